// Round 1
// baseline (1437.035 us; speedup 1.0000x reference)
//
#include <hip/hip_runtime.h>
#include <hip/hip_bf16.h>
#include <stdint.h>

// Problem constants (match reference)
#define N_USERC  50000
#define N_MERCHC 50000
#define HIDC     128
#define D_INC    64
#define NEC      1000000   // edges per direction
#define NTC      500000    // target edges

// ---------------------------------------------------------------------------
// Weight transpose: WT[k][j] = W[j][k] for 9 matrices packed contiguously.
// Layout (float offsets):
//  0      W1_um_l^T [64][128]
//  8192   W1_um_r^T [64][128]
//  16384  W1_mu_l^T [64][128]
//  24576  W1_mu_r^T [64][128]
//  32768  W2_um_l^T [128][128]
//  49152  W2_um_r^T [128][128]
//  65536  W2_mu_l^T [128][128]
//  81920  W2_mu_r^T [128][128]
//  98304  Wc1^T     [256][128]   (total 131072)
// ---------------------------------------------------------------------------
struct TransTab { const float* src[9]; int K[9]; int off[9]; };

__global__ void k_transpose(TransTab t, float* __restrict__ wt, int total)
{
    const int idx = blockIdx.x * blockDim.x + threadIdx.x;
    if (idx >= total) return;
    int m = 0;
#pragma unroll
    for (int i = 1; i < 9; ++i) if (idx >= t.off[i]) m = i;
    const int local = idx - t.off[m];
    const int k = local >> 7;        // row of WT (K index)
    const int j = local & 127;       // col (output index)
    wt[idx] = t.src[m][j * t.K[m] + k];
}

// ---------------------------------------------------------------------------
// CSR build: count -> scan (1 block per edge type) -> place
// ---------------------------------------------------------------------------
__global__ void k_count(const int* __restrict__ col, int ne, int* __restrict__ cnt)
{
    const int e = blockIdx.x * blockDim.x + threadIdx.x;
    if (e < ne) atomicAdd(&cnt[col[e]], 1);
}

__global__ __launch_bounds__(1024) void k_scan(
    const int* __restrict__ cnt0, int* __restrict__ off0, int* __restrict__ cur0,
    const int* __restrict__ cnt1, int* __restrict__ off1, int* __restrict__ cur1,
    int n)
{
    const int* cnt = blockIdx.x ? cnt1 : cnt0;
    int* offp = blockIdx.x ? off1 : off0;
    int* curp = blockIdx.x ? cur1 : cur0;
    __shared__ int sh[1024];
    const int t = threadIdx.x;
    const int per = (n + 1023) / 1024;
    int b0 = t * per; if (b0 > n) b0 = n;
    int b1 = b0 + per; if (b1 > n) b1 = n;
    int s = 0;
    for (int i = b0; i < b1; ++i) s += cnt[i];
    sh[t] = s;
    for (int d = 1; d < 1024; d <<= 1) {
        __syncthreads();
        int v = (t >= d) ? sh[t - d] : 0;
        __syncthreads();
        sh[t] += v;
    }
    __syncthreads();
    int run = sh[t] - s;   // exclusive prefix
    for (int i = b0; i < b1; ++i) { offp[i] = run; curp[i] = run; run += cnt[i]; }
    if (t == 1023) offp[n] = sh[1023];
}

__global__ void k_place(const int* __restrict__ row, const int* __restrict__ col,
                        int ne, int* __restrict__ cur, int* __restrict__ srcs)
{
    const int e = blockIdx.x * blockDim.x + threadIdx.x;
    if (e < ne) {
        const int p = atomicAdd(&cur[col[e]], 1);
        srcs[p] = row[e];
    }
}

// ---------------------------------------------------------------------------
// Mean aggregation: one 64-lane wave per dst node, lane = feature (x2 for D=128)
// Coalesced gather of full source rows, no atomics.
// ---------------------------------------------------------------------------
template <int D>
__global__ void k_aggregate(const float* __restrict__ x, const int* __restrict__ offs,
                            const int* __restrict__ srcs, float* __restrict__ om, int ndst)
{
    const int gw = (int)((blockIdx.x * blockDim.x + threadIdx.x) >> 6);
    const int lane = threadIdx.x & 63;
    if (gw >= ndst) return;
    const int b = offs[gw], e = offs[gw + 1];
    float a0 = 0.f, a1 = 0.f;
    for (int i = b; i < e; ++i) {
        const int s = srcs[i];
        const float* xp = x + (size_t)s * D;
        a0 += xp[lane];
        if (D == 128) a1 += xp[64 + lane];
    }
    const int deg = e - b;
    const float inv = 1.0f / (float)(deg > 1 ? deg : 1);
    om[(size_t)gw * D + lane] = a0 * inv;
    if (D == 128) om[(size_t)gw * D + 64 + lane] = a1 * inv;
}

// ---------------------------------------------------------------------------
// Tiled GEMM with optional row gather and fused SAGE structure:
//   C[m][0:128] = bias + A1[g1(m)][0:K1] @ W1^T + A2[g2(m)][0:K2] @ W2^T
// WT = [K1+K2][128] (contiguous W1^T then W2^T). Optional relu.
// CLASSIFY epilogue: out[m] = bc2 + sum_j relu(C[m][j]) * wc2[j]
// Tile: 64 rows x 128 cols per 256-thread block; K staged in chunks of 64.
// ---------------------------------------------------------------------------
__device__ __forceinline__ float f4c(const float4& v, int u)
{
    return u == 0 ? v.x : u == 1 ? v.y : u == 2 ? v.z : v.w;
}

template <bool RELU, bool CLASSIFY>
__global__ __launch_bounds__(256) void k_gemm(
    const float* __restrict__ src1, const float* __restrict__ src2,
    const int* __restrict__ idx1, const int* __restrict__ idx2,
    int K1, int K2,
    const float* __restrict__ WT, const float* __restrict__ bias,
    const float* __restrict__ wc2, const float* __restrict__ bc2,
    float* __restrict__ out, int M)
{
    __shared__ __align__(16) float At[64][68];   // +4 pad keeps float4 rows, breaks pow2 stride
    __shared__ __align__(16) float Bt[64][128];

    const int tx = threadIdx.x;
    const int m0 = blockIdx.x * 64;
    const int jg = tx & 15;        // col group: cols jg*8 .. jg*8+7
    const int rg = tx >> 4;        // row group: rows rg*4 .. rg*4+3
    const int lr = tx >> 2;        // loader row 0..63
    const int ls = tx & 3;         // loader segment 0..3

    int mrow = m0 + lr; if (mrow >= M) mrow = M - 1;   // clamp; stores guarded

    float acc[4][8];
#pragma unroll
    for (int i = 0; i < 4; ++i)
#pragma unroll
        for (int j = 0; j < 8; ++j) acc[i][j] = 0.f;

    const int nch = (K1 + K2) >> 6;
    for (int c = 0; c < nch; ++c) {
        const int k0 = c << 6;
        const float* src; const int* idx; int K, kloc;
        if (k0 < K1) { src = src1; idx = idx1; K = K1; kloc = k0; }
        else         { src = src2; idx = idx2; K = K2; kloc = k0 - K1; }
        const int gi = idx ? idx[mrow] : mrow;
        const float* arow = src + (size_t)gi * K + kloc;

        __syncthreads();   // previous chunk's LDS reads done before overwrite
        // A tile: 64 rows x 64 k; 4 threads/row x 4 float4 each (contig 256B per row)
#pragma unroll
        for (int q = 0; q < 4; ++q) {
            const int colk = (ls + 4 * q) * 4;
            const float4 v = *(const float4*)(arow + colk);
            *(float4*)&At[lr][colk] = v;
        }
        // B tile: WT rows k0..k0+63, 128 cols; coalesced float4 rows
        const int bj = (tx & 31) * 4;
        const int bk0 = tx >> 5;
#pragma unroll
        for (int p = 0; p < 8; ++p) {
            const int kk = bk0 + 8 * p;
            const float4 v = *(const float4*)(WT + (size_t)(k0 + kk) * 128 + bj);
            *(float4*)&Bt[kk][bj] = v;
        }
        __syncthreads();

#pragma unroll
        for (int kk = 0; kk < 64; kk += 4) {
            float4 a4[4];
#pragma unroll
            for (int i = 0; i < 4; ++i) a4[i] = *(const float4*)&At[rg * 4 + i][kk];
#pragma unroll
            for (int u = 0; u < 4; ++u) {
                const float4 b0 = *(const float4*)&Bt[kk + u][jg * 8];
                const float4 b1 = *(const float4*)&Bt[kk + u][jg * 8 + 4];
#pragma unroll
                for (int i = 0; i < 4; ++i) {
                    const float av = f4c(a4[i], u);
                    acc[i][0] = fmaf(av, b0.x, acc[i][0]);
                    acc[i][1] = fmaf(av, b0.y, acc[i][1]);
                    acc[i][2] = fmaf(av, b0.z, acc[i][2]);
                    acc[i][3] = fmaf(av, b0.w, acc[i][3]);
                    acc[i][4] = fmaf(av, b1.x, acc[i][4]);
                    acc[i][5] = fmaf(av, b1.y, acc[i][5]);
                    acc[i][6] = fmaf(av, b1.z, acc[i][6]);
                    acc[i][7] = fmaf(av, b1.w, acc[i][7]);
                }
            }
        }
    }

    if constexpr (!CLASSIFY) {
        float bv[8];
#pragma unroll
        for (int j = 0; j < 8; ++j) bv[j] = bias[jg * 8 + j];
#pragma unroll
        for (int i = 0; i < 4; ++i) {
            const int m = m0 + rg * 4 + i;
            if (m < M) {
                float o[8];
#pragma unroll
                for (int j = 0; j < 8; ++j) {
                    float v = acc[i][j] + bv[j];
                    if (RELU) v = fmaxf(v, 0.f);
                    o[j] = v;
                }
                float4* dst = (float4*)(out + (size_t)m * 128 + jg * 8);
                dst[0] = make_float4(o[0], o[1], o[2], o[3]);
                dst[1] = make_float4(o[4], o[5], o[6], o[7]);
            }
        }
    } else {
        float bv[8], wv[8];
#pragma unroll
        for (int j = 0; j < 8; ++j) { bv[j] = bias[jg * 8 + j]; wv[j] = wc2[jg * 8 + j]; }
        const float b2v = bc2[0];
#pragma unroll
        for (int i = 0; i < 4; ++i) {
            float p = 0.f;
#pragma unroll
            for (int j = 0; j < 8; ++j)
                p = fmaf(fmaxf(acc[i][j] + bv[j], 0.f), wv[j], p);
            // reduce across the 16 jg lanes (lanes with same rg are a contiguous 16-lane group)
            p += __shfl_xor(p, 1);
            p += __shfl_xor(p, 2);
            p += __shfl_xor(p, 4);
            p += __shfl_xor(p, 8);
            if (jg == 0) {
                const int m = m0 + rg * 4 + i;
                if (m < M) out[m] = p + b2v;
            }
        }
    }
}

// ---------------------------------------------------------------------------
// Host launcher
// ---------------------------------------------------------------------------
extern "C" void kernel_launch(void* const* d_in, const int* in_sizes, int n_in,
                              void* d_out, int out_size, void* d_ws, size_t ws_size,
                              hipStream_t stream)
{
    const float* x_user  = (const float*)d_in[0];
    const float* x_merch = (const float*)d_in[1];
    const int*   e_um    = (const int*)d_in[2];   // [2][1M]: row=user, col=merchant
    const int*   e_mu    = (const int*)d_in[3];   // [2][1M]: row=merchant, col=user
    const int*   tgt     = (const int*)d_in[4];   // [2][500k]: row=user, col=merchant
    const float* W1_um_l = (const float*)d_in[5];
    const float* b1_um_l = (const float*)d_in[6];
    const float* W1_um_r = (const float*)d_in[7];
    const float* W1_mu_l = (const float*)d_in[8];
    const float* b1_mu_l = (const float*)d_in[9];
    const float* W1_mu_r = (const float*)d_in[10];
    const float* W2_um_l = (const float*)d_in[11];
    const float* b2_um_l = (const float*)d_in[12];
    const float* W2_um_r = (const float*)d_in[13];
    const float* W2_mu_l = (const float*)d_in[14];
    const float* b2_mu_l = (const float*)d_in[15];
    const float* W2_mu_r = (const float*)d_in[16];
    const float* Wc1     = (const float*)d_in[17];
    const float* bc1     = (const float*)d_in[18];
    const float* Wc2     = (const float*)d_in[19];
    const float* bc2     = (const float*)d_in[20];
    float* out = (float*)d_out;

    // ---- workspace carve-up (4-byte words, 64-word aligned) ≈ 198 MB total
    uint32_t* B = (uint32_t*)d_ws;
    size_t pos = 0;
    auto take = [&](size_t n) { size_t p = pos; pos += (n + 63) & ~(size_t)63; return p; };

    int* cnt_um = (int*)(B + take(N_MERCHC));
    int* cnt_mu = (int*)(B + take(N_USERC));
    const size_t cnt_words = pos;                 // memset range (must be zero)
    int* off_um  = (int*)(B + take(N_MERCHC + 1));
    int* cur_um  = (int*)(B + take(N_MERCHC));
    int* srcs_um = (int*)(B + take(NEC));
    int* off_mu  = (int*)(B + take(N_USERC + 1));
    int* cur_mu  = (int*)(B + take(N_USERC));
    int* srcs_mu = (int*)(B + take(NEC));
    float* WT      = (float*)(B + take(131072));
    float* mean1_m = (float*)(B + take((size_t)N_MERCHC * 64));
    float* mean1_u = (float*)(B + take((size_t)N_USERC * 64));
    float* h_m     = (float*)(B + take((size_t)N_MERCHC * 128));
    float* h_u     = (float*)(B + take((size_t)N_USERC * 128));
    float* mean2_m = (float*)(B + take((size_t)N_MERCHC * 128));
    float* mean2_u = (float*)(B + take((size_t)N_USERC * 128));
    float* z_m     = (float*)(B + take((size_t)N_MERCHC * 128));
    float* z_u     = (float*)(B + take((size_t)N_USERC * 128));
    (void)ws_size; (void)in_sizes; (void)n_in; (void)out_size;

    // 1) zero the degree counters (ws is re-poisoned 0xAA before every launch)
    hipMemsetAsync(d_ws, 0, cnt_words * sizeof(uint32_t), stream);

    // 2) transpose all weight matrices into WT
    TransTab tt;
    const float* wsrc[9] = {W1_um_l, W1_um_r, W1_mu_l, W1_mu_r,
                            W2_um_l, W2_um_r, W2_mu_l, W2_mu_r, Wc1};
    const int wk[9] = {64, 64, 64, 64, 128, 128, 128, 128, 256};
    int acc_off = 0;
    for (int i = 0; i < 9; ++i) { tt.src[i] = wsrc[i]; tt.K[i] = wk[i]; tt.off[i] = acc_off; acc_off += wk[i] * 128; }
    k_transpose<<<(131072 + 255) / 256, 256, 0, stream>>>(tt, WT, 131072);

    // 3) CSR build for both edge types (reused by both layers)
    const int egrid = (NEC + 255) / 256;
    k_count<<<egrid, 256, 0, stream>>>(e_um + NEC, NEC, cnt_um);
    k_count<<<egrid, 256, 0, stream>>>(e_mu + NEC, NEC, cnt_mu);
    k_scan<<<2, 1024, 0, stream>>>(cnt_um, off_um, cur_um, cnt_mu, off_mu, cur_mu, 50000);
    k_place<<<egrid, 256, 0, stream>>>(e_um, e_um + NEC, NEC, cur_um, srcs_um);
    k_place<<<egrid, 256, 0, stream>>>(e_mu, e_mu + NEC, NEC, cur_mu, srcs_mu);

    // 4) layer 1: aggregate (D=64) then transform (K=64+64), relu
    const int agrid = 50000 / 4;   // 1 wave per dst, 4 waves per block
    k_aggregate<64><<<agrid, 256, 0, stream>>>(x_user,  off_um, srcs_um, mean1_m, N_MERCHC);
    k_aggregate<64><<<agrid, 256, 0, stream>>>(x_merch, off_mu, srcs_mu, mean1_u, N_USERC);
    const int ngrid = (50000 + 63) / 64;
    k_gemm<true, false><<<ngrid, 256, 0, stream>>>(
        mean1_m, x_merch, nullptr, nullptr, 64, 64, WT + 0,     b1_um_l, nullptr, nullptr, h_m, N_MERCHC);
    k_gemm<true, false><<<ngrid, 256, 0, stream>>>(
        mean1_u, x_user,  nullptr, nullptr, 64, 64, WT + 16384, b1_mu_l, nullptr, nullptr, h_u, N_USERC);

    // 5) layer 2: aggregate (D=128) then transform (K=128+128), no relu
    k_aggregate<128><<<agrid, 256, 0, stream>>>(h_u, off_um, srcs_um, mean2_m, N_MERCHC);
    k_aggregate<128><<<agrid, 256, 0, stream>>>(h_m, off_mu, srcs_mu, mean2_u, N_USERC);
    k_gemm<false, false><<<ngrid, 256, 0, stream>>>(
        mean2_m, h_m, nullptr, nullptr, 128, 128, WT + 32768, b2_um_l, nullptr, nullptr, z_m, N_MERCHC);
    k_gemm<false, false><<<ngrid, 256, 0, stream>>>(
        mean2_u, h_u, nullptr, nullptr, 128, 128, WT + 65536, b2_mu_l, nullptr, nullptr, z_u, N_USERC);

    // 6) classifier: gather [z_u[row] | z_m[col]] -> relu(Wc1 x + bc1) -> dot Wc2 + bc2
    const int cgrid = (NTC + 63) / 64;
    k_gemm<true, true><<<cgrid, 256, 0, stream>>>(
        z_u, z_m, tgt, tgt + NTC, 128, 128, WT + 98304, bc1, Wc2, bc2, out, NTC);
}

// Round 2
// 957.074 us; speedup vs baseline: 1.5015x; 1.5015x over previous
//
#include <hip/hip_runtime.h>
#include <hip/hip_bf16.h>
#include <stdint.h>

#define N_USERC  50000
#define N_MERCHC 50000
#define HIDC     128
#define D_INC    64
#define NEC      1000000   // edges per direction
#define NTC      500000    // target edges

// ---------------------------------------------------------------------------
// Weight transpose: WT[k][j] = W[j][k] for 9 matrices packed contiguously.
//  0      W1_um_l^T [64][128]
//  8192   W1_um_r^T [64][128]
//  16384  W1_mu_l^T [64][128]
//  24576  W1_mu_r^T [64][128]
//  32768  W2_um_l^T [128][128]
//  49152  W2_um_r^T [128][128]
//  65536  W2_mu_l^T [128][128]
//  81920  W2_mu_r^T [128][128]
//  98304  Wc1^T     [256][128]   (rows 0..127: z_u part -> P; 128..255: z_m part -> Q)
// ---------------------------------------------------------------------------
struct TransTab { const float* src[9]; int K[9]; int off[9]; };

__global__ void k_transpose(TransTab t, float* __restrict__ wt, int total)
{
    const int idx = blockIdx.x * blockDim.x + threadIdx.x;
    if (idx >= total) return;
    int m = 0;
#pragma unroll
    for (int i = 1; i < 9; ++i) if (idx >= t.off[i]) m = i;
    const int local = idx - t.off[m];
    const int k = local >> 7;
    const int j = local & 127;
    wt[idx] = t.src[m][j * t.K[m] + k];
}

// ---------------------------------------------------------------------------
// CSR build (both edge types in one launch): count -> scan -> place
// ---------------------------------------------------------------------------
__global__ void k_count2(const int* __restrict__ colA, const int* __restrict__ colB,
                         int ne, int* __restrict__ cntA, int* __restrict__ cntB)
{
    const int e = blockIdx.x * blockDim.x + threadIdx.x;
    if (e < ne)           atomicAdd(&cntA[colA[e]], 1);
    else if (e < 2 * ne)  atomicAdd(&cntB[colB[e - ne]], 1);
}

__global__ __launch_bounds__(1024) void k_scan(
    const int* __restrict__ cnt0, int* __restrict__ off0, int* __restrict__ cur0,
    const int* __restrict__ cnt1, int* __restrict__ off1, int* __restrict__ cur1,
    int n)
{
    const int* cnt = blockIdx.x ? cnt1 : cnt0;
    int* offp = blockIdx.x ? off1 : off0;
    int* curp = blockIdx.x ? cur1 : cur0;
    __shared__ int sh[1024];
    const int t = threadIdx.x;
    const int per = (n + 1023) / 1024;
    int b0 = t * per; if (b0 > n) b0 = n;
    int b1 = b0 + per; if (b1 > n) b1 = n;
    int s = 0;
    for (int i = b0; i < b1; ++i) s += cnt[i];
    sh[t] = s;
    for (int d = 1; d < 1024; d <<= 1) {
        __syncthreads();
        int v = (t >= d) ? sh[t - d] : 0;
        __syncthreads();
        sh[t] += v;
    }
    __syncthreads();
    int run = sh[t] - s;
    for (int i = b0; i < b1; ++i) { offp[i] = run; curp[i] = run; run += cnt[i]; }
    if (t == 1023) offp[n] = sh[1023];
}

__global__ void k_place2(const int* __restrict__ rowA, const int* __restrict__ colA,
                         const int* __restrict__ rowB, const int* __restrict__ colB,
                         int ne, int* __restrict__ curA, int* __restrict__ srcsA,
                         int* __restrict__ curB, int* __restrict__ srcsB)
{
    const int e = blockIdx.x * blockDim.x + threadIdx.x;
    if (e < ne) {
        const int p = atomicAdd(&curA[colA[e]], 1);
        srcsA[p] = rowA[e];
    } else if (e < 2 * ne) {
        const int i = e - ne;
        const int p = atomicAdd(&curB[colB[i]], 1);
        srcsB[p] = rowB[i];
    }
}

// ---------------------------------------------------------------------------
// Mean aggregation, vectorized: float4 per lane, multiple edges per wave-iter.
// D=64: 16 lanes/edge, 4 edges/iter.  D=128: 32 lanes/edge, 2 edges/iter.
// ---------------------------------------------------------------------------
template <int D>
__global__ void k_aggregate(const float* __restrict__ x, const int* __restrict__ offs,
                            const int* __restrict__ srcs, float* __restrict__ om, int ndst)
{
    constexpr int LPE = D / 4;      // lanes per edge row
    constexpr int EPW = 64 / LPE;   // edges per wave-iter
    const int wid = (int)((blockIdx.x * blockDim.x + threadIdx.x) >> 6);
    if (wid >= ndst) return;
    const int lane = threadIdx.x & 63;
    const int sub  = lane / LPE;    // which edge in the group
    const int c4   = lane % LPE;    // float4 index within row

    const int b = offs[wid], e = offs[wid + 1];
    float4 acc = make_float4(0.f, 0.f, 0.f, 0.f);
    for (int i = b + sub; i < e; i += EPW) {
        const int s = srcs[i];
        const float4 v = *(const float4*)(x + (size_t)s * D + c4 * 4);
        acc.x += v.x; acc.y += v.y; acc.z += v.z; acc.w += v.w;
    }
    // combine the EPW sub-accumulators
#pragma unroll
    for (int m = LPE; m < 64; m <<= 1) {
        acc.x += __shfl_xor(acc.x, m);
        acc.y += __shfl_xor(acc.y, m);
        acc.z += __shfl_xor(acc.z, m);
        acc.w += __shfl_xor(acc.w, m);
    }
    if (sub == 0) {
        const int deg = e - b;
        const float inv = 1.0f / (float)(deg > 1 ? deg : 1);
        float4 o = make_float4(acc.x * inv, acc.y * inv, acc.z * inv, acc.w * inv);
        *(float4*)(om + (size_t)wid * D + c4 * 4) = o;
    }
}

// ---------------------------------------------------------------------------
// Tiled fp32 GEMM, fused SAGE structure:
//   C[m][0:128] = bias + A1[m][0:K1] @ W1^T + A2[m][0:K2] @ W2^T
// WT = [K1+K2][128]. bias nullable. Tile 64 rows x 128 cols, K-chunk 32.
// Per-thread columns {jg*4..+3, 64+jg*4..+3} -> B LDS reads cover all 32
// banks at 2-way (free), vs 4-way with contiguous 8-col mapping.
// ---------------------------------------------------------------------------
__device__ __forceinline__ float f4c(const float4& v, int u)
{
    return u == 0 ? v.x : u == 1 ? v.y : u == 2 ? v.z : v.w;
}

template <bool RELU>
__global__ __launch_bounds__(256) void k_gemm(
    const float* __restrict__ src1, const float* __restrict__ src2,
    int K1, int K2,
    const float* __restrict__ WT, const float* __restrict__ bias,
    float* __restrict__ out, int M)
{
    __shared__ __align__(16) float At[64][36];   // 64 rows x 32 k (+4 pad)
    __shared__ __align__(16) float Bt[32][128];  // 32 k x 128 cols

    const int tx = threadIdx.x;
    const int m0 = blockIdx.x * 64;
    const int jg = tx & 15;        // col group: cols {jg*4..+3, 64+jg*4..+3}
    const int rg = tx >> 4;        // row group: rows rg*4 .. rg*4+3
    const int lr = tx >> 2;        // loader row 0..63
    const int ls = tx & 3;         // loader segment 0..3

    int mrow = m0 + lr; if (mrow >= M) mrow = M - 1;   // clamp; stores guarded

    float acc[4][8];
#pragma unroll
    for (int i = 0; i < 4; ++i)
#pragma unroll
        for (int j = 0; j < 8; ++j) acc[i][j] = 0.f;

    const int nch = (K1 + K2) >> 5;
    for (int c = 0; c < nch; ++c) {
        const int k0 = c << 5;
        const float* src; int K, kloc;
        if (k0 < K1) { src = src1; K = K1; kloc = k0; }
        else         { src = src2; K = K2; kloc = k0 - K1; }
        const float* arow = src + (size_t)mrow * K + kloc;

        __syncthreads();
        // A tile: 64 rows x 32 k; 4 threads/row x 2 float4
#pragma unroll
        for (int q = 0; q < 2; ++q) {
            const int colk = (ls + 4 * q) * 4;
            *(float4*)&At[lr][colk] = *(const float4*)(arow + colk);
        }
        // B tile: 32 k-rows x 128 cols; 4 float4/thread, coalesced
        const int bj = (tx & 31) * 4;
        const int bk0 = tx >> 5;
#pragma unroll
        for (int p = 0; p < 4; ++p) {
            const int kk = bk0 + 8 * p;
            *(float4*)&Bt[kk][bj] = *(const float4*)(WT + (size_t)(k0 + kk) * 128 + bj);
        }
        __syncthreads();

#pragma unroll
        for (int kk = 0; kk < 32; kk += 4) {
            float4 a4[4];
#pragma unroll
            for (int i = 0; i < 4; ++i) a4[i] = *(const float4*)&At[rg * 4 + i][kk];
#pragma unroll
            for (int u = 0; u < 4; ++u) {
                const float4 b0 = *(const float4*)&Bt[kk + u][jg * 4];
                const float4 b1 = *(const float4*)&Bt[kk + u][jg * 4 + 64];
#pragma unroll
                for (int i = 0; i < 4; ++i) {
                    const float av = f4c(a4[i], u);
                    acc[i][0] = fmaf(av, b0.x, acc[i][0]);
                    acc[i][1] = fmaf(av, b0.y, acc[i][1]);
                    acc[i][2] = fmaf(av, b0.z, acc[i][2]);
                    acc[i][3] = fmaf(av, b0.w, acc[i][3]);
                    acc[i][4] = fmaf(av, b1.x, acc[i][4]);
                    acc[i][5] = fmaf(av, b1.y, acc[i][5]);
                    acc[i][6] = fmaf(av, b1.z, acc[i][6]);
                    acc[i][7] = fmaf(av, b1.w, acc[i][7]);
                }
            }
        }
    }

    float bv[8] = {0, 0, 0, 0, 0, 0, 0, 0};
    if (bias) {
#pragma unroll
        for (int j = 0; j < 4; ++j) { bv[j] = bias[jg * 4 + j]; bv[4 + j] = bias[64 + jg * 4 + j]; }
    }
#pragma unroll
    for (int i = 0; i < 4; ++i) {
        const int m = m0 + rg * 4 + i;
        if (m < M) {
            float o[8];
#pragma unroll
            for (int j = 0; j < 8; ++j) {
                float v = acc[i][j] + bv[j];
                if (RELU) v = fmaxf(v, 0.f);
                o[j] = v;
            }
            *(float4*)(out + (size_t)m * 128 + jg * 4)      = make_float4(o[0], o[1], o[2], o[3]);
            *(float4*)(out + (size_t)m * 128 + 64 + jg * 4) = make_float4(o[4], o[5], o[6], o[7]);
        }
    }
}

// ---------------------------------------------------------------------------
// Edge classifier, decomposed: out[e] = bc2 + sum_j relu(P[r][j]+Q[c][j])*wc2[j]
// (bc1 folded into P). 2 edges per wave, 32 lanes x float4 per edge row.
// ---------------------------------------------------------------------------
__global__ __launch_bounds__(256) void k_edge(
    const float* __restrict__ P, const float* __restrict__ Q,
    const int* __restrict__ er, const int* __restrict__ ec,
    const float* __restrict__ wc2, const float* __restrict__ bc2,
    float* __restrict__ out, int nt)
{
    const int lane = threadIdx.x & 63;
    const int sub = lane >> 5;       // edge within wave
    const int c4 = lane & 31;        // float4 index within row (128 floats)
    const int wid = (int)((blockIdx.x * blockDim.x + threadIdx.x) >> 6);
    const int e0 = wid * 2 + sub;
    if (e0 >= nt) return;

    const float4 w4 = ((const float4*)wc2)[c4];
    const int r = er[e0], c = ec[e0];
    const float4 p = *(const float4*)(P + (size_t)r * 128 + c4 * 4);
    const float4 q = *(const float4*)(Q + (size_t)c * 128 + c4 * 4);
    float s = fmaxf(p.x + q.x, 0.f) * w4.x
            + fmaxf(p.y + q.y, 0.f) * w4.y
            + fmaxf(p.z + q.z, 0.f) * w4.z
            + fmaxf(p.w + q.w, 0.f) * w4.w;
    s += __shfl_xor(s, 1);
    s += __shfl_xor(s, 2);
    s += __shfl_xor(s, 4);
    s += __shfl_xor(s, 8);
    s += __shfl_xor(s, 16);
    if (c4 == 0) out[e0] = s + bc2[0];
}

// ---------------------------------------------------------------------------
// Host launcher
// ---------------------------------------------------------------------------
extern "C" void kernel_launch(void* const* d_in, const int* in_sizes, int n_in,
                              void* d_out, int out_size, void* d_ws, size_t ws_size,
                              hipStream_t stream)
{
    const float* x_user  = (const float*)d_in[0];
    const float* x_merch = (const float*)d_in[1];
    const int*   e_um    = (const int*)d_in[2];
    const int*   e_mu    = (const int*)d_in[3];
    const int*   tgt     = (const int*)d_in[4];
    const float* W1_um_l = (const float*)d_in[5];
    const float* b1_um_l = (const float*)d_in[6];
    const float* W1_um_r = (const float*)d_in[7];
    const float* W1_mu_l = (const float*)d_in[8];
    const float* b1_mu_l = (const float*)d_in[9];
    const float* W1_mu_r = (const float*)d_in[10];
    const float* W2_um_l = (const float*)d_in[11];
    const float* b2_um_l = (const float*)d_in[12];
    const float* W2_um_r = (const float*)d_in[13];
    const float* W2_mu_l = (const float*)d_in[14];
    const float* b2_mu_l = (const float*)d_in[15];
    const float* W2_mu_r = (const float*)d_in[16];
    const float* Wc1     = (const float*)d_in[17];
    const float* bc1     = (const float*)d_in[18];
    const float* Wc2     = (const float*)d_in[19];
    const float* bc2     = (const float*)d_in[20];
    float* out = (float*)d_out;

    // ---- workspace carve-up (4-byte words, 64-word aligned)
    uint32_t* B = (uint32_t*)d_ws;
    size_t pos = 0;
    auto take = [&](size_t n) { size_t p = pos; pos += (n + 63) & ~(size_t)63; return p; };

    int* cnt_um = (int*)(B + take(N_MERCHC));
    int* cnt_mu = (int*)(B + take(N_USERC));
    const size_t cnt_words = pos;                 // memset range
    int* off_um  = (int*)(B + take(N_MERCHC + 1));
    int* cur_um  = (int*)(B + take(N_MERCHC));
    int* srcs_um = (int*)(B + take(NEC));
    int* off_mu  = (int*)(B + take(N_USERC + 1));
    int* cur_mu  = (int*)(B + take(N_USERC));
    int* srcs_mu = (int*)(B + take(NEC));
    float* WT      = (float*)(B + take(131072));
    float* mean1_m = (float*)(B + take((size_t)N_MERCHC * 64));
    float* mean1_u = (float*)(B + take((size_t)N_USERC * 64));
    float* h_m     = (float*)(B + take((size_t)N_MERCHC * 128));
    float* h_u     = (float*)(B + take((size_t)N_USERC * 128));
    float* mean2_m = (float*)(B + take((size_t)N_MERCHC * 128));
    float* mean2_u = (float*)(B + take((size_t)N_USERC * 128));
    float* z_m     = (float*)(B + take((size_t)N_MERCHC * 128));
    float* z_u     = (float*)(B + take((size_t)N_USERC * 128));
    // P/Q alias the dead mean2 buffers (mean2 fully consumed by layer-2 GEMMs)
    float* Pbuf = mean2_m;   // 50000 x 128, includes bc1
    float* Qbuf = mean2_u;   // 50000 x 128
    (void)ws_size; (void)in_sizes; (void)n_in; (void)out_size;

    // 1) zero degree counters
    hipMemsetAsync(d_ws, 0, cnt_words * sizeof(uint32_t), stream);

    // 2) weight transposes
    TransTab tt;
    const float* wsrc[9] = {W1_um_l, W1_um_r, W1_mu_l, W1_mu_r,
                            W2_um_l, W2_um_r, W2_mu_l, W2_mu_r, Wc1};
    const int wk[9] = {64, 64, 64, 64, 128, 128, 128, 128, 256};
    int acc_off = 0;
    for (int i = 0; i < 9; ++i) { tt.src[i] = wsrc[i]; tt.K[i] = wk[i]; tt.off[i] = acc_off; acc_off += wk[i] * 128; }
    k_transpose<<<(131072 + 255) / 256, 256, 0, stream>>>(tt, WT, 131072);

    // 3) CSR build (both edge types)
    const int egrid2 = (2 * NEC + 255) / 256;
    k_count2<<<egrid2, 256, 0, stream>>>(e_um + NEC, e_mu + NEC, NEC, cnt_um, cnt_mu);
    k_scan<<<2, 1024, 0, stream>>>(cnt_um, off_um, cur_um, cnt_mu, off_mu, cur_mu, 50000);
    k_place2<<<egrid2, 256, 0, stream>>>(e_um, e_um + NEC, e_mu, e_mu + NEC, NEC,
                                         cur_um, srcs_um, cur_mu, srcs_mu);

    // 4) layer 1
    const int agrid = 50000 / 4;   // 4 waves/block, 1 wave per dst
    k_aggregate<64><<<agrid, 256, 0, stream>>>(x_user,  off_um, srcs_um, mean1_m, N_MERCHC);
    k_aggregate<64><<<agrid, 256, 0, stream>>>(x_merch, off_mu, srcs_mu, mean1_u, N_USERC);
    const int ngrid = (50000 + 63) / 64;
    k_gemm<true><<<ngrid, 256, 0, stream>>>(
        mean1_m, x_merch, 64, 64, WT + 0,     b1_um_l, h_m, N_MERCHC);
    k_gemm<true><<<ngrid, 256, 0, stream>>>(
        mean1_u, x_user,  64, 64, WT + 16384, b1_mu_l, h_u, N_USERC);

    // 5) layer 2
    k_aggregate<128><<<agrid, 256, 0, stream>>>(h_u, off_um, srcs_um, mean2_m, N_MERCHC);
    k_aggregate<128><<<agrid, 256, 0, stream>>>(h_m, off_mu, srcs_mu, mean2_u, N_USERC);
    k_gemm<false><<<ngrid, 256, 0, stream>>>(
        mean2_m, h_m, 128, 128, WT + 32768, b2_um_l, z_m, N_MERCHC);
    k_gemm<false><<<ngrid, 256, 0, stream>>>(
        mean2_u, h_u, 128, 128, WT + 65536, b2_mu_l, z_u, N_USERC);

    // 6) classifier decomposition: P = z_u @ Wc1[:, :128]^T + bc1 ; Q = z_m @ Wc1[:, 128:]^T
    k_gemm<false><<<ngrid, 256, 0, stream>>>(
        z_u, nullptr, 128, 0, WT + 98304,  bc1,     Pbuf, N_USERC);
    k_gemm<false><<<ngrid, 256, 0, stream>>>(
        z_m, nullptr, 128, 0, WT + 114688, nullptr, Qbuf, N_MERCHC);

    // 7) per-edge: out = bc2 + relu(P[r]+Q[c]) . wc2
    const int cgrid = (NTC / 2 + 3) / 4;   // 2 edges/wave, 4 waves/block
    k_edge<<<cgrid, 256, 0, stream>>>(Pbuf, Qbuf, tgt, tgt + NTC, Wc2, bc2, out, NTC);
}

// Round 3
// 665.526 us; speedup vs baseline: 2.1592x; 1.4381x over previous
//
#include <hip/hip_runtime.h>
#include <hip/hip_bf16.h>
#include <stdint.h>

#define N_USERC  50000
#define N_MERCHC 50000
#define HIDC     128
#define D_INC    64
#define NEC      1000000   // edges per direction
#define NTC      500000    // target edges

#define NB    196          // dst buckets (256 dsts each: bucket = dst >> 8)
#define BCAP  8192         // pairs per bucket (mean 5120, sigma ~72)
#define ECHUNK 8192        // edges per pass-A block (32/thread)

// ---------------------------------------------------------------------------
// Weight transpose: WT[k][j] = W[j][k] for 9 matrices packed contiguously.
//  0      W1_um_l^T [64][128]
//  8192   W1_um_r^T [64][128]
//  16384  W1_mu_l^T [64][128]
//  24576  W1_mu_r^T [64][128]
//  32768  W2_um_l^T [128][128]
//  49152  W2_um_r^T [128][128]
//  65536  W2_mu_l^T [128][128]
//  81920  W2_mu_r^T [128][128]
//  98304  Wc1^T     [256][128]   (rows 0..127 -> P; 128..255 -> Q)
// ---------------------------------------------------------------------------
struct TransTab { const float* src[9]; int K[9]; int off[9]; };

__global__ void k_transpose(TransTab t, float* __restrict__ wt, int total)
{
    const int idx = blockIdx.x * blockDim.x + threadIdx.x;
    if (idx >= total) return;
    int m = 0;
#pragma unroll
    for (int i = 1; i < 9; ++i) if (idx >= t.off[i]) m = i;
    const int local = idx - t.off[m];
    const int k = local >> 7;
    const int j = local & 127;
    wt[idx] = t.src[m][j * t.K[m] + k];
}

// ---------------------------------------------------------------------------
// CSR build pass A: bucket the edges. Per-block LDS histogram + one global
// reservation per bucket, then append packed (ldst<<16 | src) u32s so writes
// are contiguous runs (vs 64B-line-per-4B-write scatter of the old k_place).
// ---------------------------------------------------------------------------
__global__ __launch_bounds__(256) void k_bucket(
    const int* __restrict__ rowA, const int* __restrict__ colA,
    const int* __restrict__ rowB, const int* __restrict__ colB,
    uint32_t* __restrict__ gcnt,                 // [2][NB], pre-zeroed
    uint32_t* __restrict__ bktA, uint32_t* __restrict__ bktB)
{
    __shared__ uint32_t hist[NB], base[NB], cur[NB];
    const int bpt = (NEC + ECHUNK - 1) / ECHUNK;     // 123 blocks per type
    const int type = (blockIdx.x >= bpt) ? 1 : 0;
    const int cb = blockIdx.x - type * bpt;
    const int* col = type ? colB : colA;
    const int* row = type ? rowB : rowA;
    uint32_t* bkt = type ? bktB : bktA;
    uint32_t* gc = gcnt + type * NB;

    const int e0 = cb * ECHUNK;
    const int e1 = (e0 + ECHUNK < NEC) ? e0 + ECHUNK : NEC;
    const int tx = threadIdx.x;

    for (int i = tx; i < NB; i += 256) { hist[i] = 0; cur[i] = 0; }
    __syncthreads();

    int cols[32];
#pragma unroll
    for (int q = 0; q < 32; ++q) {
        const int i = e0 + tx + q * 256;
        int c = -1;
        if (i < e1) { c = col[i]; atomicAdd(&hist[c >> 8], 1u); }
        cols[q] = c;
    }
    __syncthreads();
    for (int i = tx; i < NB; i += 256)
        base[i] = atomicAdd(&gc[i], hist[i]);
    __syncthreads();
#pragma unroll
    for (int q = 0; q < 32; ++q) {
        const int i = e0 + tx + q * 256;
        if (i < e1) {
            const int c = cols[q];
            const int b = c >> 8;
            const uint32_t p = base[b] + atomicAdd(&cur[b], 1u);
            if (p < BCAP)
                bkt[(size_t)b * BCAP + p] = ((uint32_t)(c & 255) << 16) | (uint32_t)row[i];
        }
    }
}

// ---------------------------------------------------------------------------
// Bucket-base scan (1 block): exclusive scan of gcnt per type, plus the
// off[N] sentinels (each type has exactly NEC edges).
// ---------------------------------------------------------------------------
__global__ __launch_bounds__(256) void k_bscan(
    const uint32_t* __restrict__ gcnt, uint32_t* __restrict__ bbase,
    int* __restrict__ off_um, int* __restrict__ off_mu)
{
    __shared__ uint32_t sh0[256], sh1[256];
    const int t = threadIdx.x;
    const uint32_t v0 = (t < NB) ? gcnt[t] : 0;
    const uint32_t v1 = (t < NB) ? gcnt[NB + t] : 0;
    sh0[t] = v0; sh1[t] = v1;
    for (int d = 1; d < 256; d <<= 1) {
        __syncthreads();
        const uint32_t a0 = (t >= d) ? sh0[t - d] : 0;
        const uint32_t a1 = (t >= d) ? sh1[t - d] : 0;
        __syncthreads();
        sh0[t] += a0; sh1[t] += a1;
    }
    __syncthreads();
    if (t < NB) {
        bbase[t]      = sh0[t] - v0;
        bbase[NB + t] = sh1[t] - v1;
    }
    if (t == 0) { off_um[N_MERCHC] = NEC; off_mu[N_USERC] = NEC; }
}

// ---------------------------------------------------------------------------
// CSR build pass B: one block per bucket. Count per local dst in LDS, LDS
// scan -> global off array (replaces old count+scan kernels), then place
// srcs into the bucket's contiguous CSR window (L2 absorbs the local scatter).
// ---------------------------------------------------------------------------
__global__ __launch_bounds__(256) void k_bplace(
    const uint32_t* __restrict__ gcnt, const uint32_t* __restrict__ bbase,
    const uint32_t* __restrict__ bktA, const uint32_t* __restrict__ bktB,
    int* __restrict__ off_um, int* __restrict__ srcs_um,
    int* __restrict__ off_mu, int* __restrict__ srcs_mu)
{
    __shared__ uint32_t cnt[256], loff[256], cur[256];
    const int type = (blockIdx.x >= NB) ? 1 : 0;
    const int b = blockIdx.x - type * NB;
    const uint32_t* bkt = (type ? bktB : bktA) + (size_t)b * BCAP;
    int* offp = type ? off_mu : off_um;
    int* srcs = type ? srcs_mu : srcs_um;
    const int n = (int)gcnt[type * NB + b];
    const uint32_t gbase = bbase[type * NB + b];
    const int t = threadIdx.x;

    cnt[t] = 0; cur[t] = 0;
    __syncthreads();
    for (int i = t; i < n; i += 256)
        atomicAdd(&cnt[bkt[i] >> 16], 1u);
    __syncthreads();
    loff[t] = cnt[t];
    for (int d = 1; d < 256; d <<= 1) {
        __syncthreads();
        const uint32_t a = (t >= d) ? loff[t - d] : 0;
        __syncthreads();
        loff[t] += a;
    }
    __syncthreads();
    const uint32_t excl = loff[t] - cnt[t];
    const int dst0 = b << 8;
    if (dst0 + t < N_USERC) offp[dst0 + t] = (int)(gbase + excl);
    __syncthreads();
    loff[t] = excl;
    __syncthreads();
    for (int i = t; i < n; i += 256) {
        const uint32_t v = bkt[i];
        const uint32_t ld = v >> 16;
        const uint32_t p = gbase + loff[ld] + atomicAdd(&cur[ld], 1u);
        srcs[p] = (int)(v & 0xFFFFu);
    }
}

// ---------------------------------------------------------------------------
// Mean aggregation, vectorized: float4 per lane, multiple edges per wave-iter.
// ---------------------------------------------------------------------------
template <int D>
__global__ void k_aggregate(const float* __restrict__ x, const int* __restrict__ offs,
                            const int* __restrict__ srcs, float* __restrict__ om, int ndst)
{
    constexpr int LPE = D / 4;      // lanes per edge row
    constexpr int EPW = 64 / LPE;   // edges per wave-iter
    const int wid = (int)((blockIdx.x * blockDim.x + threadIdx.x) >> 6);
    if (wid >= ndst) return;
    const int lane = threadIdx.x & 63;
    const int sub  = lane / LPE;
    const int c4   = lane % LPE;

    const int b = offs[wid], e = offs[wid + 1];
    float4 acc = make_float4(0.f, 0.f, 0.f, 0.f);
    for (int i = b + sub; i < e; i += EPW) {
        const int s = srcs[i];
        const float4 v = *(const float4*)(x + (size_t)s * D + c4 * 4);
        acc.x += v.x; acc.y += v.y; acc.z += v.z; acc.w += v.w;
    }
#pragma unroll
    for (int m = LPE; m < 64; m <<= 1) {
        acc.x += __shfl_xor(acc.x, m);
        acc.y += __shfl_xor(acc.y, m);
        acc.z += __shfl_xor(acc.z, m);
        acc.w += __shfl_xor(acc.w, m);
    }
    if (sub == 0) {
        const int deg = e - b;
        const float inv = 1.0f / (float)(deg > 1 ? deg : 1);
        *(float4*)(om + (size_t)wid * D + c4 * 4) =
            make_float4(acc.x * inv, acc.y * inv, acc.z * inv, acc.w * inv);
    }
}

// ---------------------------------------------------------------------------
// Tiled fp32 GEMM, fused SAGE structure:
//   C[m][0:128] = bias + A1[m][0:K1] @ W1^T + A2[m][0:K2] @ W2^T
// Per-thread cols {jg*4..+3, 64+jg*4..+3} -> 2-way LDS bank aliasing (free).
// ---------------------------------------------------------------------------
__device__ __forceinline__ float f4c(const float4& v, int u)
{
    return u == 0 ? v.x : u == 1 ? v.y : u == 2 ? v.z : v.w;
}

template <bool RELU>
__global__ __launch_bounds__(256) void k_gemm(
    const float* __restrict__ src1, const float* __restrict__ src2,
    int K1, int K2,
    const float* __restrict__ WT, const float* __restrict__ bias,
    float* __restrict__ out, int M)
{
    __shared__ __align__(16) float At[64][36];
    __shared__ __align__(16) float Bt[32][128];

    const int tx = threadIdx.x;
    const int m0 = blockIdx.x * 64;
    const int jg = tx & 15;
    const int rg = tx >> 4;
    const int lr = tx >> 2;
    const int ls = tx & 3;

    int mrow = m0 + lr; if (mrow >= M) mrow = M - 1;

    float acc[4][8];
#pragma unroll
    for (int i = 0; i < 4; ++i)
#pragma unroll
        for (int j = 0; j < 8; ++j) acc[i][j] = 0.f;

    const int nch = (K1 + K2) >> 5;
    for (int c = 0; c < nch; ++c) {
        const int k0 = c << 5;
        const float* src; int K, kloc;
        if (k0 < K1) { src = src1; K = K1; kloc = k0; }
        else         { src = src2; K = K2; kloc = k0 - K1; }
        const float* arow = src + (size_t)mrow * K + kloc;

        __syncthreads();
#pragma unroll
        for (int q = 0; q < 2; ++q) {
            const int colk = (ls + 4 * q) * 4;
            *(float4*)&At[lr][colk] = *(const float4*)(arow + colk);
        }
        const int bj = (tx & 31) * 4;
        const int bk0 = tx >> 5;
#pragma unroll
        for (int p = 0; p < 4; ++p) {
            const int kk = bk0 + 8 * p;
            *(float4*)&Bt[kk][bj] = *(const float4*)(WT + (size_t)(k0 + kk) * 128 + bj);
        }
        __syncthreads();

#pragma unroll
        for (int kk = 0; kk < 32; kk += 4) {
            float4 a4[4];
#pragma unroll
            for (int i = 0; i < 4; ++i) a4[i] = *(const float4*)&At[rg * 4 + i][kk];
#pragma unroll
            for (int u = 0; u < 4; ++u) {
                const float4 b0 = *(const float4*)&Bt[kk + u][jg * 4];
                const float4 b1 = *(const float4*)&Bt[kk + u][jg * 4 + 64];
#pragma unroll
                for (int i = 0; i < 4; ++i) {
                    const float av = f4c(a4[i], u);
                    acc[i][0] = fmaf(av, b0.x, acc[i][0]);
                    acc[i][1] = fmaf(av, b0.y, acc[i][1]);
                    acc[i][2] = fmaf(av, b0.z, acc[i][2]);
                    acc[i][3] = fmaf(av, b0.w, acc[i][3]);
                    acc[i][4] = fmaf(av, b1.x, acc[i][4]);
                    acc[i][5] = fmaf(av, b1.y, acc[i][5]);
                    acc[i][6] = fmaf(av, b1.z, acc[i][6]);
                    acc[i][7] = fmaf(av, b1.w, acc[i][7]);
                }
            }
        }
    }

    float bv[8] = {0, 0, 0, 0, 0, 0, 0, 0};
    if (bias) {
#pragma unroll
        for (int j = 0; j < 4; ++j) { bv[j] = bias[jg * 4 + j]; bv[4 + j] = bias[64 + jg * 4 + j]; }
    }
#pragma unroll
    for (int i = 0; i < 4; ++i) {
        const int m = m0 + rg * 4 + i;
        if (m < M) {
            float o[8];
#pragma unroll
            for (int j = 0; j < 8; ++j) {
                float v = acc[i][j] + bv[j];
                if (RELU) v = fmaxf(v, 0.f);
                o[j] = v;
            }
            *(float4*)(out + (size_t)m * 128 + jg * 4)      = make_float4(o[0], o[1], o[2], o[3]);
            *(float4*)(out + (size_t)m * 128 + 64 + jg * 4) = make_float4(o[4], o[5], o[6], o[7]);
        }
    }
}

// ---------------------------------------------------------------------------
// Edge classifier, decomposed: out[e] = bc2 + sum_j relu(P[r][j]+Q[c][j])*wc2[j]
// ---------------------------------------------------------------------------
__global__ __launch_bounds__(256) void k_edge(
    const float* __restrict__ P, const float* __restrict__ Q,
    const int* __restrict__ er, const int* __restrict__ ec,
    const float* __restrict__ wc2, const float* __restrict__ bc2,
    float* __restrict__ out, int nt)
{
    const int lane = threadIdx.x & 63;
    const int sub = lane >> 5;
    const int c4 = lane & 31;
    const int wid = (int)((blockIdx.x * blockDim.x + threadIdx.x) >> 6);
    const int e0 = wid * 2 + sub;
    if (e0 >= nt) return;

    const float4 w4 = ((const float4*)wc2)[c4];
    const int r = er[e0], c = ec[e0];
    const float4 p = *(const float4*)(P + (size_t)r * 128 + c4 * 4);
    const float4 q = *(const float4*)(Q + (size_t)c * 128 + c4 * 4);
    float s = fmaxf(p.x + q.x, 0.f) * w4.x
            + fmaxf(p.y + q.y, 0.f) * w4.y
            + fmaxf(p.z + q.z, 0.f) * w4.z
            + fmaxf(p.w + q.w, 0.f) * w4.w;
    s += __shfl_xor(s, 1);
    s += __shfl_xor(s, 2);
    s += __shfl_xor(s, 4);
    s += __shfl_xor(s, 8);
    s += __shfl_xor(s, 16);
    if (c4 == 0) out[e0] = s + bc2[0];
}

// ---------------------------------------------------------------------------
// Host launcher
// ---------------------------------------------------------------------------
extern "C" void kernel_launch(void* const* d_in, const int* in_sizes, int n_in,
                              void* d_out, int out_size, void* d_ws, size_t ws_size,
                              hipStream_t stream)
{
    const float* x_user  = (const float*)d_in[0];
    const float* x_merch = (const float*)d_in[1];
    const int*   e_um    = (const int*)d_in[2];
    const int*   e_mu    = (const int*)d_in[3];
    const int*   tgt     = (const int*)d_in[4];
    const float* W1_um_l = (const float*)d_in[5];
    const float* b1_um_l = (const float*)d_in[6];
    const float* W1_um_r = (const float*)d_in[7];
    const float* W1_mu_l = (const float*)d_in[8];
    const float* b1_mu_l = (const float*)d_in[9];
    const float* W1_mu_r = (const float*)d_in[10];
    const float* W2_um_l = (const float*)d_in[11];
    const float* b2_um_l = (const float*)d_in[12];
    const float* W2_um_r = (const float*)d_in[13];
    const float* W2_mu_l = (const float*)d_in[14];
    const float* b2_mu_l = (const float*)d_in[15];
    const float* W2_mu_r = (const float*)d_in[16];
    const float* Wc1     = (const float*)d_in[17];
    const float* bc1     = (const float*)d_in[18];
    const float* Wc2     = (const float*)d_in[19];
    const float* bc2     = (const float*)d_in[20];
    float* out = (float*)d_out;

    // ---- workspace carve-up (u32 words, 64-word aligned)
    uint32_t* B = (uint32_t*)d_ws;
    size_t pos = 0;
    auto take = [&](size_t n) { size_t p = pos; pos += (n + 63) & ~(size_t)63; return p; };

    uint32_t* gcnt = (uint32_t*)(B + take(2 * NB));     // zeroed each launch
    const size_t cnt_words = pos;
    uint32_t* bbase = (uint32_t*)(B + take(2 * NB));
    int* off_um  = (int*)(B + take(N_MERCHC + 1));
    int* srcs_um = (int*)(B + take(NEC));
    int* off_mu  = (int*)(B + take(N_USERC + 1));
    int* srcs_mu = (int*)(B + take(NEC));
    float* WT      = (float*)(B + take(131072));
    float* mean1_m = (float*)(B + take((size_t)N_MERCHC * 64));
    float* mean1_u = (float*)(B + take((size_t)N_USERC * 64));
    float* h_m     = (float*)(B + take((size_t)N_MERCHC * 128));
    float* h_u     = (float*)(B + take((size_t)N_USERC * 128));
    float* mean2_m = (float*)(B + take((size_t)N_MERCHC * 128));
    float* mean2_u = (float*)(B + take((size_t)N_USERC * 128));
    float* z_m     = (float*)(B + take((size_t)N_MERCHC * 128));
    float* z_u     = (float*)(B + take((size_t)N_USERC * 128));
    // buckets alias z_m (dead until step 5; buckets dead after CSR build)
    uint32_t* bktA = (uint32_t*)z_m;                    // NB*BCAP u32 = 6.4 MB
    uint32_t* bktB = bktA + (size_t)NB * BCAP;          // another 6.4 MB (z_m is 25.6 MB)
    // P/Q alias dead mean2 buffers
    float* Pbuf = mean2_m;
    float* Qbuf = mean2_u;
    (void)ws_size; (void)in_sizes; (void)n_in; (void)out_size;

    // 1) zero bucket counters
    hipMemsetAsync(d_ws, 0, cnt_words * sizeof(uint32_t), stream);

    // 2) weight transposes
    TransTab tt;
    const float* wsrc[9] = {W1_um_l, W1_um_r, W1_mu_l, W1_mu_r,
                            W2_um_l, W2_um_r, W2_mu_l, W2_mu_r, Wc1};
    const int wk[9] = {64, 64, 64, 64, 128, 128, 128, 128, 256};
    int acc_off = 0;
    for (int i = 0; i < 9; ++i) { tt.src[i] = wsrc[i]; tt.K[i] = wk[i]; tt.off[i] = acc_off; acc_off += wk[i] * 128; }
    k_transpose<<<(131072 + 255) / 256, 256, 0, stream>>>(tt, WT, 131072);

    // 3) CSR build: bucket -> scan -> place (also writes off arrays)
    const int bpt = (NEC + ECHUNK - 1) / ECHUNK;
    k_bucket<<<2 * bpt, 256, 0, stream>>>(e_um, e_um + NEC, e_mu, e_mu + NEC,
                                          gcnt, bktA, bktB);
    k_bscan<<<1, 256, 0, stream>>>(gcnt, bbase, off_um, off_mu);
    k_bplace<<<2 * NB, 256, 0, stream>>>(gcnt, bbase, bktA, bktB,
                                         off_um, srcs_um, off_mu, srcs_mu);

    // 4) layer 1
    const int agrid = 50000 / 4;
    k_aggregate<64><<<agrid, 256, 0, stream>>>(x_user,  off_um, srcs_um, mean1_m, N_MERCHC);
    k_aggregate<64><<<agrid, 256, 0, stream>>>(x_merch, off_mu, srcs_mu, mean1_u, N_USERC);
    const int ngrid = (50000 + 63) / 64;
    k_gemm<true><<<ngrid, 256, 0, stream>>>(
        mean1_m, x_merch, 64, 64, WT + 0,     b1_um_l, h_m, N_MERCHC);
    k_gemm<true><<<ngrid, 256, 0, stream>>>(
        mean1_u, x_user,  64, 64, WT + 16384, b1_mu_l, h_u, N_USERC);

    // 5) layer 2
    k_aggregate<128><<<agrid, 256, 0, stream>>>(h_u, off_um, srcs_um, mean2_m, N_MERCHC);
    k_aggregate<128><<<agrid, 256, 0, stream>>>(h_m, off_mu, srcs_mu, mean2_u, N_USERC);
    k_gemm<false><<<ngrid, 256, 0, stream>>>(
        mean2_m, h_m, 128, 128, WT + 32768, b2_um_l, z_m, N_MERCHC);
    k_gemm<false><<<ngrid, 256, 0, stream>>>(
        mean2_u, h_u, 128, 128, WT + 65536, b2_mu_l, z_u, N_USERC);

    // 6) classifier decomposition: P = z_u @ Wc1[:, :128]^T + bc1 ; Q = z_m @ Wc1[:, 128:]^T
    k_gemm<false><<<ngrid, 256, 0, stream>>>(
        z_u, nullptr, 128, 0, WT + 98304,  bc1,     Pbuf, N_USERC);
    k_gemm<false><<<ngrid, 256, 0, stream>>>(
        z_m, nullptr, 128, 0, WT + 114688, nullptr, Qbuf, N_MERCHC);

    // 7) per-edge: out = bc2 + relu(P[r]+Q[c]) . wc2
    const int cgrid = (NTC / 2 + 3) / 4;
    k_edge<<<cgrid, 256, 0, stream>>>(Pbuf, Qbuf, tgt, tgt + NTC, Wc2, bc2, out, NTC);
}

// Round 4
// 590.919 us; speedup vs baseline: 2.4319x; 1.1263x over previous
//
#include <hip/hip_runtime.h>
#include <hip/hip_bf16.h>
#include <stdint.h>

#define N_USERC  50000
#define N_MERCHC 50000
#define HIDC     128
#define D_INC    64
#define NEC      1000000   // edges per direction
#define NTC      500000    // target edges

#define NB    196          // dst buckets (256 dsts each: bucket = dst >> 8)
#define BCAP  8192         // pairs per bucket (mean 5120, sigma ~72)
#define ECHUNK 8192        // edges per pass-A block (32/thread)

typedef unsigned short ushortT;

__device__ __forceinline__ unsigned short f2bf(float f)
{
    const unsigned u = __float_as_uint(f);
    const unsigned r = u + 0x7fffu + ((u >> 16) & 1u);   // RNE
    return (unsigned short)(r >> 16);
}
__device__ __forceinline__ float bfhi(unsigned u) { return __uint_as_float(u & 0xffff0000u); }
__device__ __forceinline__ float bflo(unsigned u) { return __uint_as_float(u << 16); }

// ---------------------------------------------------------------------------
// Weight transpose: WT[k][j] = W[j][k] for 9 matrices packed contiguously.
//  0      W1_um_l^T [64][128]      32768  W2_um_l^T [128][128]
//  8192   W1_um_r^T [64][128]      49152  W2_um_r^T [128][128]
//  16384  W1_mu_l^T [64][128]      65536  W2_mu_l^T [128][128]
//  24576  W1_mu_r^T [64][128]      81920  W2_mu_r^T [128][128]
//  98304  Wc1^T     [256][128]   (rows 0..127 -> P; 128..255 -> Q)
// ---------------------------------------------------------------------------
struct TransTab { const float* src[9]; int K[9]; int off[9]; };

__global__ void k_transpose(TransTab t, float* __restrict__ wt, int total)
{
    const int idx = blockIdx.x * blockDim.x + threadIdx.x;
    if (idx >= total) return;
    int m = 0;
#pragma unroll
    for (int i = 1; i < 9; ++i) if (idx >= t.off[i]) m = i;
    const int local = idx - t.off[m];
    const int k = local >> 7;
    const int j = local & 127;
    wt[idx] = t.src[m][j * t.K[m] + k];
}

// ---------------------------------------------------------------------------
// fp32 -> bf16 cast for the two input feature tables (4 elems/thread)
// ---------------------------------------------------------------------------
__global__ void k_cast(const float* __restrict__ a, const float* __restrict__ b,
                       int n4a, int n4b, ushortT* __restrict__ oa, ushortT* __restrict__ ob)
{
    const int idx = blockIdx.x * blockDim.x + threadIdx.x;
    if (idx < n4a) {
        const float4 v = ((const float4*)a)[idx];
        ushort4 o; o.x = f2bf(v.x); o.y = f2bf(v.y); o.z = f2bf(v.z); o.w = f2bf(v.w);
        ((ushort4*)oa)[idx] = o;
    } else if (idx < n4a + n4b) {
        const int i = idx - n4a;
        const float4 v = ((const float4*)b)[i];
        ushort4 o; o.x = f2bf(v.x); o.y = f2bf(v.y); o.z = f2bf(v.z); o.w = f2bf(v.w);
        ((ushort4*)ob)[i] = o;
    }
}

// ---------------------------------------------------------------------------
// CSR build pass A: bucket the edges (packed (ldst<<16|src) u32 appends).
// ---------------------------------------------------------------------------
__global__ __launch_bounds__(256) void k_bucket(
    const int* __restrict__ rowA, const int* __restrict__ colA,
    const int* __restrict__ rowB, const int* __restrict__ colB,
    uint32_t* __restrict__ gcnt,                 // [2][NB], pre-zeroed
    uint32_t* __restrict__ bktA, uint32_t* __restrict__ bktB)
{
    __shared__ uint32_t hist[NB], base[NB], cur[NB];
    const int bpt = (NEC + ECHUNK - 1) / ECHUNK;
    const int type = (blockIdx.x >= bpt) ? 1 : 0;
    const int cb = blockIdx.x - type * bpt;
    const int* col = type ? colB : colA;
    const int* row = type ? rowB : rowA;
    uint32_t* bkt = type ? bktB : bktA;
    uint32_t* gc = gcnt + type * NB;

    const int e0 = cb * ECHUNK;
    const int e1 = (e0 + ECHUNK < NEC) ? e0 + ECHUNK : NEC;
    const int tx = threadIdx.x;

    for (int i = tx; i < NB; i += 256) { hist[i] = 0; cur[i] = 0; }
    __syncthreads();

    int cols[32];
#pragma unroll
    for (int q = 0; q < 32; ++q) {
        const int i = e0 + tx + q * 256;
        int c = -1;
        if (i < e1) { c = col[i]; atomicAdd(&hist[c >> 8], 1u); }
        cols[q] = c;
    }
    __syncthreads();
    for (int i = tx; i < NB; i += 256)
        base[i] = atomicAdd(&gc[i], hist[i]);
    __syncthreads();
#pragma unroll
    for (int q = 0; q < 32; ++q) {
        const int i = e0 + tx + q * 256;
        if (i < e1) {
            const int c = cols[q];
            const int b = c >> 8;
            const uint32_t p = base[b] + atomicAdd(&cur[b], 1u);
            if (p < BCAP)
                bkt[(size_t)b * BCAP + p] = ((uint32_t)(c & 255) << 16) | (uint32_t)row[i];
        }
    }
}

__global__ __launch_bounds__(256) void k_bscan(
    const uint32_t* __restrict__ gcnt, uint32_t* __restrict__ bbase,
    int* __restrict__ off_um, int* __restrict__ off_mu)
{
    __shared__ uint32_t sh0[256], sh1[256];
    const int t = threadIdx.x;
    const uint32_t v0 = (t < NB) ? gcnt[t] : 0;
    const uint32_t v1 = (t < NB) ? gcnt[NB + t] : 0;
    sh0[t] = v0; sh1[t] = v1;
    for (int d = 1; d < 256; d <<= 1) {
        __syncthreads();
        const uint32_t a0 = (t >= d) ? sh0[t - d] : 0;
        const uint32_t a1 = (t >= d) ? sh1[t - d] : 0;
        __syncthreads();
        sh0[t] += a0; sh1[t] += a1;
    }
    __syncthreads();
    if (t < NB) {
        bbase[t]      = sh0[t] - v0;
        bbase[NB + t] = sh1[t] - v1;
    }
    if (t == 0) { off_um[N_MERCHC] = NEC; off_mu[N_USERC] = NEC; }
}

__global__ __launch_bounds__(256) void k_bplace(
    const uint32_t* __restrict__ gcnt, const uint32_t* __restrict__ bbase,
    const uint32_t* __restrict__ bktA, const uint32_t* __restrict__ bktB,
    int* __restrict__ off_um, int* __restrict__ srcs_um,
    int* __restrict__ off_mu, int* __restrict__ srcs_mu)
{
    __shared__ uint32_t cnt[256], loff[256], cur[256];
    const int type = (blockIdx.x >= NB) ? 1 : 0;
    const int b = blockIdx.x - type * NB;
    const uint32_t* bkt = (type ? bktB : bktA) + (size_t)b * BCAP;
    int* offp = type ? off_mu : off_um;
    int* srcs = type ? srcs_mu : srcs_um;
    const int n = (int)gcnt[type * NB + b];
    const uint32_t gbase = bbase[type * NB + b];
    const int t = threadIdx.x;

    cnt[t] = 0; cur[t] = 0;
    __syncthreads();
    for (int i = t; i < n; i += 256)
        atomicAdd(&cnt[bkt[i] >> 16], 1u);
    __syncthreads();
    loff[t] = cnt[t];
    for (int d = 1; d < 256; d <<= 1) {
        __syncthreads();
        const uint32_t a = (t >= d) ? loff[t - d] : 0;
        __syncthreads();
        loff[t] += a;
    }
    __syncthreads();
    const uint32_t excl = loff[t] - cnt[t];
    const int dst0 = b << 8;
    if (dst0 + t < N_USERC) offp[dst0 + t] = (int)(gbase + excl);
    __syncthreads();
    loff[t] = excl;
    __syncthreads();
    for (int i = t; i < n; i += 256) {
        const uint32_t v = bkt[i];
        const uint32_t ld = v >> 16;
        const uint32_t p = gbase + loff[ld] + atomicAdd(&cur[ld], 1u);
        srcs[p] = (int)(v & 0xFFFFu);
    }
}

// ---------------------------------------------------------------------------
// Mean aggregation from bf16 table, both directions in one launch.
// 16 B/lane (8 bf16), fp32 accumulate. D=64: 8 lanes/edge, 8 edges/iter.
// D=128: 16 lanes/edge, 4 edges/iter.
// ---------------------------------------------------------------------------
template <int D>
__global__ __launch_bounds__(256) void k_aggregate_bf(
    const ushortT* __restrict__ xA, const int* __restrict__ offsA,
    const int* __restrict__ srcsA, float* __restrict__ omA,
    const ushortT* __restrict__ xB, const int* __restrict__ offsB,
    const int* __restrict__ srcsB, float* __restrict__ omB, int ndst)
{
    constexpr int LPE = D / 8;      // lanes per edge row
    constexpr int EPW = 64 / LPE;   // edges per wave-iter
    const int half = gridDim.x >> 1;
    const int type = (blockIdx.x >= half) ? 1 : 0;
    const int cb = blockIdx.x - type * half;
    const ushortT* x = type ? xB : xA;
    const int* offs  = type ? offsB : offsA;
    const int* srcs  = type ? srcsB : srcsA;
    float* om        = type ? omB : omA;

    const int wid = cb * 4 + (threadIdx.x >> 6);
    if (wid >= ndst) return;
    const int lane = threadIdx.x & 63;
    const int sub  = lane / LPE;
    const int c4   = lane % LPE;

    const int b = offs[wid], e = offs[wid + 1];
    float a[8];
#pragma unroll
    for (int j = 0; j < 8; ++j) a[j] = 0.f;

    for (int i = b + sub; i < e; i += EPW) {
        const int s = srcs[i];
        const uint4 v = *(const uint4*)(x + (size_t)s * D + c4 * 8);
        a[0] += bflo(v.x); a[1] += bfhi(v.x);
        a[2] += bflo(v.y); a[3] += bfhi(v.y);
        a[4] += bflo(v.z); a[5] += bfhi(v.z);
        a[6] += bflo(v.w); a[7] += bfhi(v.w);
    }
#pragma unroll
    for (int m = LPE; m < 64; m <<= 1) {
#pragma unroll
        for (int j = 0; j < 8; ++j) a[j] += __shfl_xor(a[j], m);
    }
    if (sub == 0) {
        const int deg = e - b;
        const float inv = 1.0f / (float)(deg > 1 ? deg : 1);
        float* dst = om + (size_t)wid * D + c4 * 8;
        *(float4*)dst       = make_float4(a[0] * inv, a[1] * inv, a[2] * inv, a[3] * inv);
        *(float4*)(dst + 4) = make_float4(a[4] * inv, a[5] * inv, a[6] * inv, a[7] * inv);
    }
}

// ---------------------------------------------------------------------------
// Tiled fp32 GEMM, fused SAGE structure:
//   C[m][0:128] = bias + A1[m][0:K1] @ W1^T + A2[m][0:K2] @ W2^T
// Optional extra bf16 copy of the output (for the next layer's gather).
// ---------------------------------------------------------------------------
__device__ __forceinline__ float f4c(const float4& v, int u)
{
    return u == 0 ? v.x : u == 1 ? v.y : u == 2 ? v.z : v.w;
}

template <bool RELU>
__global__ __launch_bounds__(256) void k_gemm(
    const float* __restrict__ src1, const float* __restrict__ src2,
    int K1, int K2,
    const float* __restrict__ WT, const float* __restrict__ bias,
    float* __restrict__ out, ushortT* __restrict__ obf, int M)
{
    __shared__ __align__(16) float At[64][36];
    __shared__ __align__(16) float Bt[32][128];

    const int tx = threadIdx.x;
    const int m0 = blockIdx.x * 64;
    const int jg = tx & 15;
    const int rg = tx >> 4;
    const int lr = tx >> 2;
    const int ls = tx & 3;

    int mrow = m0 + lr; if (mrow >= M) mrow = M - 1;

    float acc[4][8];
#pragma unroll
    for (int i = 0; i < 4; ++i)
#pragma unroll
        for (int j = 0; j < 8; ++j) acc[i][j] = 0.f;

    const int nch = (K1 + K2) >> 5;
    for (int c = 0; c < nch; ++c) {
        const int k0 = c << 5;
        const float* src; int K, kloc;
        if (k0 < K1) { src = src1; K = K1; kloc = k0; }
        else         { src = src2; K = K2; kloc = k0 - K1; }
        const float* arow = src + (size_t)mrow * K + kloc;

        __syncthreads();
#pragma unroll
        for (int q = 0; q < 2; ++q) {
            const int colk = (ls + 4 * q) * 4;
            *(float4*)&At[lr][colk] = *(const float4*)(arow + colk);
        }
        const int bj = (tx & 31) * 4;
        const int bk0 = tx >> 5;
#pragma unroll
        for (int p = 0; p < 4; ++p) {
            const int kk = bk0 + 8 * p;
            *(float4*)&Bt[kk][bj] = *(const float4*)(WT + (size_t)(k0 + kk) * 128 + bj);
        }
        __syncthreads();

#pragma unroll
        for (int kk = 0; kk < 32; kk += 4) {
            float4 a4[4];
#pragma unroll
            for (int i = 0; i < 4; ++i) a4[i] = *(const float4*)&At[rg * 4 + i][kk];
#pragma unroll
            for (int u = 0; u < 4; ++u) {
                const float4 b0 = *(const float4*)&Bt[kk + u][jg * 4];
                const float4 b1 = *(const float4*)&Bt[kk + u][jg * 4 + 64];
#pragma unroll
                for (int i = 0; i < 4; ++i) {
                    const float av = f4c(a4[i], u);
                    acc[i][0] = fmaf(av, b0.x, acc[i][0]);
                    acc[i][1] = fmaf(av, b0.y, acc[i][1]);
                    acc[i][2] = fmaf(av, b0.z, acc[i][2]);
                    acc[i][3] = fmaf(av, b0.w, acc[i][3]);
                    acc[i][4] = fmaf(av, b1.x, acc[i][4]);
                    acc[i][5] = fmaf(av, b1.y, acc[i][5]);
                    acc[i][6] = fmaf(av, b1.z, acc[i][6]);
                    acc[i][7] = fmaf(av, b1.w, acc[i][7]);
                }
            }
        }
    }

    float bv[8] = {0, 0, 0, 0, 0, 0, 0, 0};
    if (bias) {
#pragma unroll
        for (int j = 0; j < 4; ++j) { bv[j] = bias[jg * 4 + j]; bv[4 + j] = bias[64 + jg * 4 + j]; }
    }
#pragma unroll
    for (int i = 0; i < 4; ++i) {
        const int m = m0 + rg * 4 + i;
        if (m < M) {
            float o[8];
#pragma unroll
            for (int j = 0; j < 8; ++j) {
                float v = acc[i][j] + bv[j];
                if (RELU) v = fmaxf(v, 0.f);
                o[j] = v;
            }
            *(float4*)(out + (size_t)m * 128 + jg * 4)      = make_float4(o[0], o[1], o[2], o[3]);
            *(float4*)(out + (size_t)m * 128 + 64 + jg * 4) = make_float4(o[4], o[5], o[6], o[7]);
            if (obf) {
                ushort4 p0; p0.x = f2bf(o[0]); p0.y = f2bf(o[1]); p0.z = f2bf(o[2]); p0.w = f2bf(o[3]);
                ushort4 p1; p1.x = f2bf(o[4]); p1.y = f2bf(o[5]); p1.z = f2bf(o[6]); p1.w = f2bf(o[7]);
                *(ushort4*)(obf + (size_t)m * 128 + jg * 4)      = p0;
                *(ushort4*)(obf + (size_t)m * 128 + 64 + jg * 4) = p1;
            }
        }
    }
}

// ---------------------------------------------------------------------------
// Edge classifier, decomposed: out[e] = bc2 + sum_j relu(P[r][j]+Q[c][j])*wc2[j]
// ---------------------------------------------------------------------------
__global__ __launch_bounds__(256) void k_edge(
    const float* __restrict__ P, const float* __restrict__ Q,
    const int* __restrict__ er, const int* __restrict__ ec,
    const float* __restrict__ wc2, const float* __restrict__ bc2,
    float* __restrict__ out, int nt)
{
    const int lane = threadIdx.x & 63;
    const int sub = lane >> 5;
    const int c4 = lane & 31;
    const int wid = (int)((blockIdx.x * blockDim.x + threadIdx.x) >> 6);
    const int e0 = wid * 2 + sub;
    if (e0 >= nt) return;

    const float4 w4 = ((const float4*)wc2)[c4];
    const int r = er[e0], c = ec[e0];
    const float4 p = *(const float4*)(P + (size_t)r * 128 + c4 * 4);
    const float4 q = *(const float4*)(Q + (size_t)c * 128 + c4 * 4);
    float s = fmaxf(p.x + q.x, 0.f) * w4.x
            + fmaxf(p.y + q.y, 0.f) * w4.y
            + fmaxf(p.z + q.z, 0.f) * w4.z
            + fmaxf(p.w + q.w, 0.f) * w4.w;
    s += __shfl_xor(s, 1);
    s += __shfl_xor(s, 2);
    s += __shfl_xor(s, 4);
    s += __shfl_xor(s, 8);
    s += __shfl_xor(s, 16);
    if (c4 == 0) out[e0] = s + bc2[0];
}

// ---------------------------------------------------------------------------
// Host launcher
// ---------------------------------------------------------------------------
extern "C" void kernel_launch(void* const* d_in, const int* in_sizes, int n_in,
                              void* d_out, int out_size, void* d_ws, size_t ws_size,
                              hipStream_t stream)
{
    const float* x_user  = (const float*)d_in[0];
    const float* x_merch = (const float*)d_in[1];
    const int*   e_um    = (const int*)d_in[2];
    const int*   e_mu    = (const int*)d_in[3];
    const int*   tgt     = (const int*)d_in[4];
    const float* W1_um_l = (const float*)d_in[5];
    const float* b1_um_l = (const float*)d_in[6];
    const float* W1_um_r = (const float*)d_in[7];
    const float* W1_mu_l = (const float*)d_in[8];
    const float* b1_mu_l = (const float*)d_in[9];
    const float* W1_mu_r = (const float*)d_in[10];
    const float* W2_um_l = (const float*)d_in[11];
    const float* b2_um_l = (const float*)d_in[12];
    const float* W2_um_r = (const float*)d_in[13];
    const float* W2_mu_l = (const float*)d_in[14];
    const float* b2_mu_l = (const float*)d_in[15];
    const float* W2_mu_r = (const float*)d_in[16];
    const float* Wc1     = (const float*)d_in[17];
    const float* bc1     = (const float*)d_in[18];
    const float* Wc2     = (const float*)d_in[19];
    const float* bc2     = (const float*)d_in[20];
    float* out = (float*)d_out;

    // ---- workspace carve-up (u32 words, 64-word aligned)
    uint32_t* B = (uint32_t*)d_ws;
    size_t pos = 0;
    auto take = [&](size_t n) { size_t p = pos; pos += (n + 63) & ~(size_t)63; return p; };

    uint32_t* gcnt = (uint32_t*)(B + take(2 * NB));     // zeroed each launch
    const size_t cnt_words = pos;
    uint32_t* bbase = (uint32_t*)(B + take(2 * NB));
    int* off_um  = (int*)(B + take(N_MERCHC + 1));
    int* srcs_um = (int*)(B + take(NEC));
    int* off_mu  = (int*)(B + take(N_USERC + 1));
    int* srcs_mu = (int*)(B + take(NEC));
    float* WT      = (float*)(B + take(131072));
    float* mean1_m = (float*)(B + take((size_t)N_MERCHC * 64));
    float* mean1_u = (float*)(B + take((size_t)N_USERC * 64));
    float* h_m     = (float*)(B + take((size_t)N_MERCHC * 128));
    float* h_u     = (float*)(B + take((size_t)N_USERC * 128));
    float* mean2_m = (float*)(B + take((size_t)N_MERCHC * 128));
    float* mean2_u = (float*)(B + take((size_t)N_USERC * 128));
    float* z_m     = (float*)(B + take((size_t)N_MERCHC * 128));
    float* z_u     = (float*)(B + take((size_t)N_USERC * 128));

    // ---- aliases into dead regions (lifetimes commented at each use)
    // buckets live only during CSR build; mean2_m not written until layer-2 agg
    uint32_t* bktA = (uint32_t*)mean2_m;                // 1.6M words
    uint32_t* bktB = bktA + (size_t)NB * BCAP;          // 1.6M words (3.2M <= 6.4M)
    // bf16 input tables: consumed by layer-1 aggregates; z_u written last
    ushortT* xu_bf = (ushortT*)z_u;                     // 3.2M bf16 = 1.6M words
    ushortT* xm_bf = xu_bf + (size_t)N_USERC * 64;      // next 1.6M words
    // bf16 h tables: written by layer-1 GEMMs, consumed by layer-2 aggregates
    ushortT* hm_bf = (ushortT*)(z_u + (size_t)3200000); // z_u words 3.2M..6.4M
    ushortT* hu_bf = (ushortT*)z_m;                     // z_m written after agg2 consumed it
    // P/Q alias dead mean2 buffers (read by GEMM3/4 before GEMM5/6 write)
    float* Pbuf = mean2_m;
    float* Qbuf = mean2_u;
    (void)ws_size; (void)in_sizes; (void)n_in; (void)out_size;

    // 1) zero bucket counters
    hipMemsetAsync(d_ws, 0, cnt_words * sizeof(uint32_t), stream);

    // 2) bf16 casts + weight transposes
    const int n4 = N_USERC * 64 / 4;   // 800k per table
    k_cast<<<(2 * n4 + 255) / 256, 256, 0, stream>>>(x_user, x_merch, n4, n4, xu_bf, xm_bf);
    TransTab tt;
    const float* wsrc[9] = {W1_um_l, W1_um_r, W1_mu_l, W1_mu_r,
                            W2_um_l, W2_um_r, W2_mu_l, W2_mu_r, Wc1};
    const int wk[9] = {64, 64, 64, 64, 128, 128, 128, 128, 256};
    int acc_off = 0;
    for (int i = 0; i < 9; ++i) { tt.src[i] = wsrc[i]; tt.K[i] = wk[i]; tt.off[i] = acc_off; acc_off += wk[i] * 128; }
    k_transpose<<<(131072 + 255) / 256, 256, 0, stream>>>(tt, WT, 131072);

    // 3) CSR build: bucket -> scan -> place (also writes off arrays)
    const int bpt = (NEC + ECHUNK - 1) / ECHUNK;
    k_bucket<<<2 * bpt, 256, 0, stream>>>(e_um, e_um + NEC, e_mu, e_mu + NEC,
                                          gcnt, bktA, bktB);
    k_bscan<<<1, 256, 0, stream>>>(gcnt, bbase, off_um, off_mu);
    k_bplace<<<2 * NB, 256, 0, stream>>>(gcnt, bbase, bktA, bktB,
                                         off_um, srcs_um, off_mu, srcs_mu);

    // 4) layer 1: both aggregates in one launch, then two GEMMs (+bf16 h copy)
    const int agrid = 50000 / 4;       // blocks per direction (4 waves/block)
    k_aggregate_bf<64><<<2 * agrid, 256, 0, stream>>>(
        xu_bf, off_um, srcs_um, mean1_m,
        xm_bf, off_mu, srcs_mu, mean1_u, N_MERCHC);
    const int ngrid = (50000 + 63) / 64;
    k_gemm<true><<<ngrid, 256, 0, stream>>>(
        mean1_m, x_merch, 64, 64, WT + 0,     b1_um_l, h_m, hm_bf, N_MERCHC);
    k_gemm<true><<<ngrid, 256, 0, stream>>>(
        mean1_u, x_user,  64, 64, WT + 16384, b1_mu_l, h_u, hu_bf, N_USERC);

    // 5) layer 2: aggregates gather bf16 h, GEMMs on fp32
    k_aggregate_bf<128><<<2 * agrid, 256, 0, stream>>>(
        hu_bf, off_um, srcs_um, mean2_m,    // overwrites dead buckets
        hm_bf, off_mu, srcs_mu, mean2_u, N_MERCHC);
    k_gemm<false><<<ngrid, 256, 0, stream>>>(
        mean2_m, h_m, 128, 128, WT + 32768, b2_um_l, z_m, nullptr, N_MERCHC);  // kills hu_bf (dead)
    k_gemm<false><<<ngrid, 256, 0, stream>>>(
        mean2_u, h_u, 128, 128, WT + 65536, b2_mu_l, z_u, nullptr, N_USERC);   // kills x*_bf/hm_bf (dead)

    // 6) classifier decomposition: P = z_u @ Wc1[:, :128]^T + bc1 ; Q = z_m @ Wc1[:, 128:]^T
    k_gemm<false><<<ngrid, 256, 0, stream>>>(
        z_u, nullptr, 128, 0, WT + 98304,  bc1,     Pbuf, nullptr, N_USERC);
    k_gemm<false><<<ngrid, 256, 0, stream>>>(
        z_m, nullptr, 128, 0, WT + 114688, nullptr, Qbuf, nullptr, N_MERCHC);

    // 7) per-edge: out = bc2 + relu(P[r]+Q[c]) . wc2
    const int cgrid = (NTC / 2 + 3) / 4;
    k_edge<<<cgrid, 256, 0, stream>>>(Pbuf, Qbuf, tgt, tgt + NTC, Wc2, bc2, out, NTC);
}

// Round 5
// 498.553 us; speedup vs baseline: 2.8824x; 1.1853x over previous
//
#include <hip/hip_runtime.h>
#include <hip/hip_bf16.h>
#include <stdint.h>

#define N_USERC  50000
#define N_MERCHC 50000
#define HIDC     128
#define D_INC    64
#define NEC      1000000   // edges per direction
#define NTC      500000    // target edges

#define NB    196          // dst buckets (256 dsts each: bucket = dst >> 8)
#define BCAP  8192         // pairs per bucket (mean 5120, sigma ~72)
#define ECHUNK 8192        // edges per pass-A block (32/thread)

typedef unsigned short ushortT;

__device__ __forceinline__ unsigned short f2bf(float f)
{
    const unsigned u = __float_as_uint(f);
    const unsigned r = u + 0x7fffu + ((u >> 16) & 1u);   // RNE
    return (unsigned short)(r >> 16);
}
__device__ __forceinline__ float bfhi(unsigned u) { return __uint_as_float(u & 0xffff0000u); }
__device__ __forceinline__ float bflo(unsigned u) { return __uint_as_float(u << 16); }

// ---------------------------------------------------------------------------
// Weight transpose: WT[k][j] = W[j][k] for the 5 matrices still used directly.
//  0      W1_um_l^T [64][128]
//  8192   W1_um_r^T [64][128]
//  16384  W1_mu_l^T [64][128]
//  24576  W1_mu_r^T [64][128]     (total 32768 words)
// ---------------------------------------------------------------------------
struct TransTab { const float* src[4]; int K[4]; int off[4]; };

__global__ void k_transpose(TransTab t, float* __restrict__ wt, int total)
{
    const int idx = blockIdx.x * blockDim.x + threadIdx.x;
    if (idx >= total) return;
    int m = 0;
#pragma unroll
    for (int i = 1; i < 4; ++i) if (idx >= t.off[i]) m = i;
    const int local = idx - t.off[m];
    const int k = local >> 7;
    const int j = local & 127;
    wt[idx] = t.src[m][j * t.K[m] + k];
}

// ---------------------------------------------------------------------------
// Classifier-layer weight fusion (z never materialized):
//   P = mean2_u @ (Wc1a@W2_mu_l)^T + h_u @ (Wc1a@W2_mu_r)^T + bP
//   Q = mean2_m @ (Wc1b@W2_um_l)^T + h_m @ (Wc1b@W2_um_r)^T + bQ
// WC layout: [q][k][j], q=0:P q=1:Q, k=0..255 (K index), j=0..127. Already
// transposed for the GEMM's B-tile loader. bPQ = [2][128].
// ---------------------------------------------------------------------------
__global__ void k_wcombine(const float* __restrict__ Wc1,
                           const float* __restrict__ W2_mu_l, const float* __restrict__ W2_mu_r,
                           const float* __restrict__ W2_um_l, const float* __restrict__ W2_um_r,
                           const float* __restrict__ bc1,
                           const float* __restrict__ b2_mu_l, const float* __restrict__ b2_um_l,
                           float* __restrict__ WC, float* __restrict__ bPQ)
{
    const int idx = blockIdx.x * blockDim.x + threadIdx.x;
    if (idx < 65536) {
        const int q = idx >> 15;
        const int k = (idx >> 7) & 255;
        const int j = idx & 127;
        const int kk = k & 127;
        const float* W2 = q ? (k < 128 ? W2_um_l : W2_um_r)
                            : (k < 128 ? W2_mu_l : W2_mu_r);
        const float* wrow = Wc1 + (size_t)j * 256 + q * 128;
        float s = 0.f;
        for (int i = 0; i < 128; ++i)
            s = fmaf(wrow[i], W2[(size_t)i * 128 + kk], s);
        WC[idx] = s;
    } else if (idx < 65536 + 256) {
        const int r = idx - 65536;
        const int q = r >> 7, j = r & 127;
        const float* wrow = Wc1 + (size_t)j * 256 + q * 128;
        const float* b2 = q ? b2_um_l : b2_mu_l;
        float s = (q == 0) ? bc1[j] : 0.f;
        for (int i = 0; i < 128; ++i) s = fmaf(wrow[i], b2[i], s);
        bPQ[r] = s;
    }
}

// ---------------------------------------------------------------------------
// fp32 -> bf16 cast for the two input feature tables (4 elems/thread)
// ---------------------------------------------------------------------------
__global__ void k_cast(const float* __restrict__ a, const float* __restrict__ b,
                       int n4a, int n4b, ushortT* __restrict__ oa, ushortT* __restrict__ ob)
{
    const int idx = blockIdx.x * blockDim.x + threadIdx.x;
    if (idx < n4a) {
        const float4 v = ((const float4*)a)[idx];
        ushort4 o; o.x = f2bf(v.x); o.y = f2bf(v.y); o.z = f2bf(v.z); o.w = f2bf(v.w);
        ((ushort4*)oa)[idx] = o;
    } else if (idx < n4a + n4b) {
        const int i = idx - n4a;
        const float4 v = ((const float4*)b)[i];
        ushort4 o; o.x = f2bf(v.x); o.y = f2bf(v.y); o.z = f2bf(v.z); o.w = f2bf(v.w);
        ((ushort4*)ob)[i] = o;
    }
}

// ---------------------------------------------------------------------------
// CSR build pass A: bucket the edges (packed (ldst<<16|src) u32 appends).
// ---------------------------------------------------------------------------
__global__ __launch_bounds__(256) void k_bucket(
    const int* __restrict__ rowA, const int* __restrict__ colA,
    const int* __restrict__ rowB, const int* __restrict__ colB,
    uint32_t* __restrict__ gcnt,                 // [2][NB], pre-zeroed
    uint32_t* __restrict__ bktA, uint32_t* __restrict__ bktB)
{
    __shared__ uint32_t hist[NB], base[NB], cur[NB];
    const int bpt = (NEC + ECHUNK - 1) / ECHUNK;
    const int type = (blockIdx.x >= bpt) ? 1 : 0;
    const int cb = blockIdx.x - type * bpt;
    const int* col = type ? colB : colA;
    const int* row = type ? rowB : rowA;
    uint32_t* bkt = type ? bktB : bktA;
    uint32_t* gc = gcnt + type * NB;

    const int e0 = cb * ECHUNK;
    const int e1 = (e0 + ECHUNK < NEC) ? e0 + ECHUNK : NEC;
    const int tx = threadIdx.x;

    for (int i = tx; i < NB; i += 256) { hist[i] = 0; cur[i] = 0; }
    __syncthreads();

    int cols[32];
#pragma unroll
    for (int q = 0; q < 32; ++q) {
        const int i = e0 + tx + q * 256;
        int c = -1;
        if (i < e1) { c = col[i]; atomicAdd(&hist[c >> 8], 1u); }
        cols[q] = c;
    }
    __syncthreads();
    for (int i = tx; i < NB; i += 256)
        base[i] = atomicAdd(&gc[i], hist[i]);
    __syncthreads();
#pragma unroll
    for (int q = 0; q < 32; ++q) {
        const int i = e0 + tx + q * 256;
        if (i < e1) {
            const int c = cols[q];
            const int b = c >> 8;
            const uint32_t p = base[b] + atomicAdd(&cur[b], 1u);
            if (p < BCAP)
                bkt[(size_t)b * BCAP + p] = ((uint32_t)(c & 255) << 16) | (uint32_t)row[i];
        }
    }
}

__global__ __launch_bounds__(256) void k_bscan(
    const uint32_t* __restrict__ gcnt, uint32_t* __restrict__ bbase,
    int* __restrict__ off_um, int* __restrict__ off_mu)
{
    __shared__ uint32_t sh0[256], sh1[256];
    const int t = threadIdx.x;
    const uint32_t v0 = (t < NB) ? gcnt[t] : 0;
    const uint32_t v1 = (t < NB) ? gcnt[NB + t] : 0;
    sh0[t] = v0; sh1[t] = v1;
    for (int d = 1; d < 256; d <<= 1) {
        __syncthreads();
        const uint32_t a0 = (t >= d) ? sh0[t - d] : 0;
        const uint32_t a1 = (t >= d) ? sh1[t - d] : 0;
        __syncthreads();
        sh0[t] += a0; sh1[t] += a1;
    }
    __syncthreads();
    if (t < NB) {
        bbase[t]      = sh0[t] - v0;
        bbase[NB + t] = sh1[t] - v1;
    }
    if (t == 0) { off_um[N_MERCHC] = NEC; off_mu[N_USERC] = NEC; }
}

__global__ __launch_bounds__(256) void k_bplace(
    const uint32_t* __restrict__ gcnt, const uint32_t* __restrict__ bbase,
    const uint32_t* __restrict__ bktA, const uint32_t* __restrict__ bktB,
    int* __restrict__ off_um, int* __restrict__ srcs_um,
    int* __restrict__ off_mu, int* __restrict__ srcs_mu)
{
    __shared__ uint32_t cnt[256], loff[256], cur[256];
    const int type = (blockIdx.x >= NB) ? 1 : 0;
    const int b = blockIdx.x - type * NB;
    const uint32_t* bkt = (type ? bktB : bktA) + (size_t)b * BCAP;
    int* offp = type ? off_mu : off_um;
    int* srcs = type ? srcs_mu : srcs_um;
    const int n = (int)gcnt[type * NB + b];
    const uint32_t gbase = bbase[type * NB + b];
    const int t = threadIdx.x;

    cnt[t] = 0; cur[t] = 0;
    __syncthreads();
    for (int i = t; i < n; i += 256)
        atomicAdd(&cnt[bkt[i] >> 16], 1u);
    __syncthreads();
    loff[t] = cnt[t];
    for (int d = 1; d < 256; d <<= 1) {
        __syncthreads();
        const uint32_t a = (t >= d) ? loff[t - d] : 0;
        __syncthreads();
        loff[t] += a;
    }
    __syncthreads();
    const uint32_t excl = loff[t] - cnt[t];
    const int dst0 = b << 8;
    if (dst0 + t < N_USERC) offp[dst0 + t] = (int)(gbase + excl);
    __syncthreads();
    loff[t] = excl;
    __syncthreads();
    for (int i = t; i < n; i += 256) {
        const uint32_t v = bkt[i];
        const uint32_t ld = v >> 16;
        const uint32_t p = gbase + loff[ld] + atomicAdd(&cur[ld], 1u);
        srcs[p] = (int)(v & 0xFFFFu);
    }
}

// ---------------------------------------------------------------------------
// Mean aggregation from bf16 table, both directions in one launch.
// 16 B/lane (8 bf16), fp32 accumulate.
// ---------------------------------------------------------------------------
template <int D>
__global__ __launch_bounds__(256) void k_aggregate_bf(
    const ushortT* __restrict__ xA, const int* __restrict__ offsA,
    const int* __restrict__ srcsA, float* __restrict__ omA,
    const ushortT* __restrict__ xB, const int* __restrict__ offsB,
    const int* __restrict__ srcsB, float* __restrict__ omB, int ndst)
{
    constexpr int LPE = D / 8;      // lanes per edge row
    constexpr int EPW = 64 / LPE;   // edges per wave-iter
    const int half = gridDim.x >> 1;
    const int type = (blockIdx.x >= half) ? 1 : 0;
    const int cb = blockIdx.x - type * half;
    const ushortT* x = type ? xB : xA;
    const int* offs  = type ? offsB : offsA;
    const int* srcs  = type ? srcsB : srcsA;
    float* om        = type ? omB : omA;

    const int wid = cb * 4 + (threadIdx.x >> 6);
    if (wid >= ndst) return;
    const int lane = threadIdx.x & 63;
    const int sub  = lane / LPE;
    const int c4   = lane % LPE;

    const int b = offs[wid], e = offs[wid + 1];
    float a[8];
#pragma unroll
    for (int j = 0; j < 8; ++j) a[j] = 0.f;

    for (int i = b + sub; i < e; i += EPW) {
        const int s = srcs[i];
        const uint4 v = *(const uint4*)(x + (size_t)s * D + c4 * 8);
        a[0] += bflo(v.x); a[1] += bfhi(v.x);
        a[2] += bflo(v.y); a[3] += bfhi(v.y);
        a[4] += bflo(v.z); a[5] += bfhi(v.z);
        a[6] += bflo(v.w); a[7] += bfhi(v.w);
    }
#pragma unroll
    for (int m = LPE; m < 64; m <<= 1) {
#pragma unroll
        for (int j = 0; j < 8; ++j) a[j] += __shfl_xor(a[j], m);
    }
    if (sub == 0) {
        const int deg = e - b;
        const float inv = 1.0f / (float)(deg > 1 ? deg : 1);
        float* dst = om + (size_t)wid * D + c4 * 8;
        *(float4*)dst       = make_float4(a[0] * inv, a[1] * inv, a[2] * inv, a[3] * inv);
        *(float4*)(dst + 4) = make_float4(a[4] * inv, a[5] * inv, a[6] * inv, a[7] * inv);
    }
}

// ---------------------------------------------------------------------------
// Tiled fp32 GEMM, fused SAGE structure:
//   C[m][0:128] = bias + A1[m][0:K1] @ W1^T + A2[m][0:K2] @ W2^T
// out (fp32) and obf (bf16) independently nullable.
// ---------------------------------------------------------------------------
__device__ __forceinline__ float f4c(const float4& v, int u)
{
    return u == 0 ? v.x : u == 1 ? v.y : u == 2 ? v.z : v.w;
}

template <bool RELU>
__global__ __launch_bounds__(256) void k_gemm(
    const float* __restrict__ src1, const float* __restrict__ src2,
    int K1, int K2,
    const float* __restrict__ WT, const float* __restrict__ bias,
    float* __restrict__ out, ushortT* __restrict__ obf, int M)
{
    __shared__ __align__(16) float At[64][36];
    __shared__ __align__(16) float Bt[32][128];

    const int tx = threadIdx.x;
    const int m0 = blockIdx.x * 64;
    const int jg = tx & 15;
    const int rg = tx >> 4;
    const int lr = tx >> 2;
    const int ls = tx & 3;

    int mrow = m0 + lr; if (mrow >= M) mrow = M - 1;

    float acc[4][8];
#pragma unroll
    for (int i = 0; i < 4; ++i)
#pragma unroll
        for (int j = 0; j < 8; ++j) acc[i][j] = 0.f;

    const int nch = (K1 + K2) >> 5;
    for (int c = 0; c < nch; ++c) {
        const int k0 = c << 5;
        const float* src; int K, kloc;
        if (k0 < K1) { src = src1; K = K1; kloc = k0; }
        else         { src = src2; K = K2; kloc = k0 - K1; }
        const float* arow = src + (size_t)mrow * K + kloc;

        __syncthreads();
#pragma unroll
        for (int q = 0; q < 2; ++q) {
            const int colk = (ls + 4 * q) * 4;
            *(float4*)&At[lr][colk] = *(const float4*)(arow + colk);
        }
        const int bj = (tx & 31) * 4;
        const int bk0 = tx >> 5;
#pragma unroll
        for (int p = 0; p < 4; ++p) {
            const int kk = bk0 + 8 * p;
            *(float4*)&Bt[kk][bj] = *(const float4*)(WT + (size_t)(k0 + kk) * 128 + bj);
        }
        __syncthreads();

#pragma unroll
        for (int kk = 0; kk < 32; kk += 4) {
            float4 a4[4];
#pragma unroll
            for (int i = 0; i < 4; ++i) a4[i] = *(const float4*)&At[rg * 4 + i][kk];
#pragma unroll
            for (int u = 0; u < 4; ++u) {
                const float4 b0 = *(const float4*)&Bt[kk + u][jg * 4];
                const float4 b1 = *(const float4*)&Bt[kk + u][jg * 4 + 64];
#pragma unroll
                for (int i = 0; i < 4; ++i) {
                    const float av = f4c(a4[i], u);
                    acc[i][0] = fmaf(av, b0.x, acc[i][0]);
                    acc[i][1] = fmaf(av, b0.y, acc[i][1]);
                    acc[i][2] = fmaf(av, b0.z, acc[i][2]);
                    acc[i][3] = fmaf(av, b0.w, acc[i][3]);
                    acc[i][4] = fmaf(av, b1.x, acc[i][4]);
                    acc[i][5] = fmaf(av, b1.y, acc[i][5]);
                    acc[i][6] = fmaf(av, b1.z, acc[i][6]);
                    acc[i][7] = fmaf(av, b1.w, acc[i][7]);
                }
            }
        }
    }

    float bv[8] = {0, 0, 0, 0, 0, 0, 0, 0};
    if (bias) {
#pragma unroll
        for (int j = 0; j < 4; ++j) { bv[j] = bias[jg * 4 + j]; bv[4 + j] = bias[64 + jg * 4 + j]; }
    }
#pragma unroll
    for (int i = 0; i < 4; ++i) {
        const int m = m0 + rg * 4 + i;
        if (m < M) {
            float o[8];
#pragma unroll
            for (int j = 0; j < 8; ++j) {
                float v = acc[i][j] + bv[j];
                if (RELU) v = fmaxf(v, 0.f);
                o[j] = v;
            }
            if (out) {
                *(float4*)(out + (size_t)m * 128 + jg * 4)      = make_float4(o[0], o[1], o[2], o[3]);
                *(float4*)(out + (size_t)m * 128 + 64 + jg * 4) = make_float4(o[4], o[5], o[6], o[7]);
            }
            if (obf) {
                ushort4 p0; p0.x = f2bf(o[0]); p0.y = f2bf(o[1]); p0.z = f2bf(o[2]); p0.w = f2bf(o[3]);
                ushort4 p1; p1.x = f2bf(o[4]); p1.y = f2bf(o[5]); p1.z = f2bf(o[6]); p1.w = f2bf(o[7]);
                *(ushort4*)(obf + (size_t)m * 128 + jg * 4)      = p0;
                *(ushort4*)(obf + (size_t)m * 128 + 64 + jg * 4) = p1;
            }
        }
    }
}

// ---------------------------------------------------------------------------
// Edge classifier on bf16 P/Q: out[e] = bc2 + sum_j relu(P[r][j]+Q[c][j])*wc2[j]
// 4 edges per wave, 16 lanes x 8 bf16 (16 B) per edge row.
// ---------------------------------------------------------------------------
__global__ __launch_bounds__(256) void k_edge_bf(
    const ushortT* __restrict__ P, const ushortT* __restrict__ Q,
    const int* __restrict__ er, const int* __restrict__ ec,
    const float* __restrict__ wc2, const float* __restrict__ bc2,
    float* __restrict__ out, int nt)
{
    const int lane = threadIdx.x & 63;
    const int sub = lane >> 4;       // edge within wave (4)
    const int c8 = lane & 15;        // 8-elem group within row
    const int wid = (int)((blockIdx.x * blockDim.x + threadIdx.x) >> 6);
    const int e0 = wid * 4 + sub;
    if (e0 >= nt) return;

    const float4 w0 = ((const float4*)wc2)[c8 * 2];
    const float4 w1 = ((const float4*)wc2)[c8 * 2 + 1];
    const int r = er[e0], c = ec[e0];
    const uint4 pv = *(const uint4*)(P + (size_t)r * 128 + c8 * 8);
    const uint4 qv = *(const uint4*)(Q + (size_t)c * 128 + c8 * 8);
    float s = fmaxf(bflo(pv.x) + bflo(qv.x), 0.f) * w0.x
            + fmaxf(bfhi(pv.x) + bfhi(qv.x), 0.f) * w0.y
            + fmaxf(bflo(pv.y) + bflo(qv.y), 0.f) * w0.z
            + fmaxf(bfhi(pv.y) + bfhi(qv.y), 0.f) * w0.w
            + fmaxf(bflo(pv.z) + bflo(qv.z), 0.f) * w1.x
            + fmaxf(bfhi(pv.z) + bfhi(qv.z), 0.f) * w1.y
            + fmaxf(bflo(pv.w) + bflo(qv.w), 0.f) * w1.z
            + fmaxf(bfhi(pv.w) + bfhi(qv.w), 0.f) * w1.w;
    s += __shfl_xor(s, 1);
    s += __shfl_xor(s, 2);
    s += __shfl_xor(s, 4);
    s += __shfl_xor(s, 8);
    if (c8 == 0) out[e0] = s + bc2[0];
}

// ---------------------------------------------------------------------------
// Host launcher
// ---------------------------------------------------------------------------
extern "C" void kernel_launch(void* const* d_in, const int* in_sizes, int n_in,
                              void* d_out, int out_size, void* d_ws, size_t ws_size,
                              hipStream_t stream)
{
    const float* x_user  = (const float*)d_in[0];
    const float* x_merch = (const float*)d_in[1];
    const int*   e_um    = (const int*)d_in[2];
    const int*   e_mu    = (const int*)d_in[3];
    const int*   tgt     = (const int*)d_in[4];
    const float* W1_um_l = (const float*)d_in[5];
    const float* b1_um_l = (const float*)d_in[6];
    const float* W1_um_r = (const float*)d_in[7];
    const float* W1_mu_l = (const float*)d_in[8];
    const float* b1_mu_l = (const float*)d_in[9];
    const float* W1_mu_r = (const float*)d_in[10];
    const float* W2_um_l = (const float*)d_in[11];
    const float* b2_um_l = (const float*)d_in[12];
    const float* W2_um_r = (const float*)d_in[13];
    const float* W2_mu_l = (const float*)d_in[14];
    const float* b2_mu_l = (const float*)d_in[15];
    const float* W2_mu_r = (const float*)d_in[16];
    const float* Wc1     = (const float*)d_in[17];
    const float* bc1     = (const float*)d_in[18];
    const float* Wc2     = (const float*)d_in[19];
    const float* bc2     = (const float*)d_in[20];
    float* out = (float*)d_out;

    // ---- workspace carve-up (u32 words, 64-word aligned), ~176 MB total
    uint32_t* B = (uint32_t*)d_ws;
    size_t pos = 0;
    auto take = [&](size_t n) { size_t p = pos; pos += (n + 63) & ~(size_t)63; return p; };

    uint32_t* gcnt = (uint32_t*)(B + take(2 * NB));     // zeroed each launch
    const size_t cnt_words = pos;
    uint32_t* bbase = (uint32_t*)(B + take(2 * NB));
    int* off_um  = (int*)(B + take(N_MERCHC + 1));
    int* srcs_um = (int*)(B + take(NEC));
    int* off_mu  = (int*)(B + take(N_USERC + 1));
    int* srcs_mu = (int*)(B + take(NEC));
    float* WT   = (float*)(B + take(32768));            // layer-1 weight transposes
    float* WC   = (float*)(B + take(65536));            // fused P/Q weights [2][256][128]
    float* bPQ  = (float*)(B + take(256));              // fused biases [2][128]
    float* mean1_m = (float*)(B + take((size_t)N_MERCHC * 64));
    float* mean1_u = (float*)(B + take((size_t)N_USERC * 64));
    float* h_m     = (float*)(B + take((size_t)N_MERCHC * 128));
    float* h_u     = (float*)(B + take((size_t)N_USERC * 128));
    float* mean2_m = (float*)(B + take((size_t)N_MERCHC * 128));
    float* mean2_u = (float*)(B + take((size_t)N_USERC * 128));
    uint32_t* arenaA = B + take((size_t)2 * N_USERC * 64 / 2);   // 3.2M words: bf16 x tables
    uint32_t* arenaB = B + take((size_t)2 * N_USERC * 128 / 2);  // 6.4M words: bf16 h, then P/Q

    // ---- aliases (lifetimes):
    // buckets: CSR build only; mean2_m not written until layer-2 aggregate
    uint32_t* bktA = (uint32_t*)mean2_m;
    uint32_t* bktB = bktA + (size_t)NB * BCAP;          // 3.2M words total <= 6.4M
    // bf16 input tables: cast -> layer-1 aggregate
    ushortT* xu_bf = (ushortT*)arenaA;
    ushortT* xm_bf = xu_bf + (size_t)N_USERC * 64;
    // bf16 h tables: layer-1 GEMM epilogue -> layer-2 aggregate
    ushortT* hm_bf = (ushortT*)arenaB;
    ushortT* hu_bf = hm_bf + (size_t)N_MERCHC * 128;
    // bf16 P/Q: P/Q GEMM epilogue -> edge kernel (h_bf dead by then)
    ushortT* Pbf = (ushortT*)arenaB;
    ushortT* Qbf = Pbf + (size_t)N_USERC * 128;
    (void)ws_size; (void)in_sizes; (void)n_in; (void)out_size;

    // 1) zero bucket counters
    hipMemsetAsync(d_ws, 0, cnt_words * sizeof(uint32_t), stream);

    // 2) prep: bf16 casts, layer-1 weight transposes, fused classifier weights
    const int n4 = N_USERC * 64 / 4;
    k_cast<<<(2 * n4 + 255) / 256, 256, 0, stream>>>(x_user, x_merch, n4, n4, xu_bf, xm_bf);
    TransTab tt;
    const float* wsrc[4] = {W1_um_l, W1_um_r, W1_mu_l, W1_mu_r};
    const int wk[4] = {64, 64, 64, 64};
    int acc_off = 0;
    for (int i = 0; i < 4; ++i) { tt.src[i] = wsrc[i]; tt.K[i] = wk[i]; tt.off[i] = acc_off; acc_off += wk[i] * 128; }
    k_transpose<<<(32768 + 255) / 256, 256, 0, stream>>>(tt, WT, 32768);
    k_wcombine<<<(65536 + 256 + 255) / 256, 256, 0, stream>>>(
        Wc1, W2_mu_l, W2_mu_r, W2_um_l, W2_um_r, bc1, b2_mu_l, b2_um_l, WC, bPQ);

    // 3) CSR build: bucket -> scan -> place (also writes off arrays)
    const int bpt = (NEC + ECHUNK - 1) / ECHUNK;
    k_bucket<<<2 * bpt, 256, 0, stream>>>(e_um, e_um + NEC, e_mu, e_mu + NEC,
                                          gcnt, bktA, bktB);
    k_bscan<<<1, 256, 0, stream>>>(gcnt, bbase, off_um, off_mu);
    k_bplace<<<2 * NB, 256, 0, stream>>>(gcnt, bbase, bktA, bktB,
                                         off_um, srcs_um, off_mu, srcs_mu);

    // 4) layer 1: fused aggregate pair, then two GEMMs (fp32 h + bf16 h copy)
    const int agrid = 50000 / 4;
    k_aggregate_bf<64><<<2 * agrid, 256, 0, stream>>>(
        xu_bf, off_um, srcs_um, mean1_m,
        xm_bf, off_mu, srcs_mu, mean1_u, N_MERCHC);
    const int ngrid = (50000 + 63) / 64;
    k_gemm<true><<<ngrid, 256, 0, stream>>>(
        mean1_m, x_merch, 64, 64, WT + 0,     b1_um_l, h_m, hm_bf, N_MERCHC);
    k_gemm<true><<<ngrid, 256, 0, stream>>>(
        mean1_u, x_user,  64, 64, WT + 16384, b1_mu_l, h_u, hu_bf, N_USERC);

    // 5) layer 2 aggregates (gather bf16 h; overwrites dead buckets in mean2_m)
    k_aggregate_bf<128><<<2 * agrid, 256, 0, stream>>>(
        hu_bf, off_um, srcs_um, mean2_m,
        hm_bf, off_mu, srcs_mu, mean2_u, N_MERCHC);

    // 6) fused classifier GEMMs (z never materialized), bf16-only output:
    //    P = mean2_u @ WCp^T + h_u @ ... + bP ; Q = mean2_m @ WCq^T + h_m @ ... + bQ
    k_gemm<false><<<ngrid, 256, 0, stream>>>(
        mean2_u, h_u, 128, 128, WC,         bPQ,       nullptr, Pbf, N_USERC);
    k_gemm<false><<<ngrid, 256, 0, stream>>>(
        mean2_m, h_m, 128, 128, WC + 32768, bPQ + 128, nullptr, Qbf, N_MERCHC);

    // 7) per-edge: out = bc2 + relu(P[r]+Q[c]) . wc2  (bf16 gathers)
    const int cgrid = (NTC + 15) / 16;   // 4 edges/wave, 4 waves/block
    k_edge_bf<<<cgrid, 256, 0, stream>>>(Pbf, Qbf, tgt, tgt + NTC, Wc2, bc2, out, NTC);
}

// Round 6
// 439.828 us; speedup vs baseline: 3.2673x; 1.1335x over previous
//
#include <hip/hip_runtime.h>
#include <hip/hip_bf16.h>
#include <stdint.h>

#define N_USERC  50000
#define N_MERCHC 50000
#define NEC      1000000   // edges per direction
#define NTC      500000    // target edges

#define NB    196          // dst buckets (256 dsts each: bucket = dst >> 8)
#define BCAP  8192         // pairs per bucket (mean 5120, sigma ~72)
#define ECHUNK 8192        // edges per pass-A block (32/thread)

typedef unsigned short ushortT;
typedef __attribute__((ext_vector_type(8))) short short8;     // 8 bf16 = 4 VGPRs (MFMA frag)
typedef __attribute__((ext_vector_type(8))) unsigned short ushort8;
typedef __attribute__((ext_vector_type(4))) float f32x4;

__device__ __forceinline__ unsigned short f2bf(float f)
{
    const unsigned u = __float_as_uint(f);
    const unsigned r = u + 0x7fffu + ((u >> 16) & 1u);   // RNE
    return (unsigned short)(r >> 16);
}
__device__ __forceinline__ float bfhi(unsigned u) { return __uint_as_float(u & 0xffff0000u); }
__device__ __forceinline__ float bflo(unsigned u) { return __uint_as_float(u << 16); }

// ---------------------------------------------------------------------------
// Cast x tables into the interleaved A1 layout: A1[row] = [mean1(64) | x(64)]
// (mean part filled later by the aggregate). 8 elems/thread.
// ---------------------------------------------------------------------------
__global__ void k_cast_x(const float* __restrict__ xu, const float* __restrict__ xm,
                         ushortT* __restrict__ A1u, ushortT* __restrict__ A1m)
{
    const int idx = blockIdx.x * blockDim.x + threadIdx.x;   // 800000 threads
    if (idx >= 800000) return;
    const int which = idx / 400000;
    const int rem = idx - which * 400000;
    const int row = rem >> 3;
    const int c8 = rem & 7;
    const float* x = which ? xm : xu;
    ushortT* A = which ? A1m : A1u;
    const float4 v0 = *(const float4*)(x + (size_t)row * 64 + c8 * 8);
    const float4 v1 = *(const float4*)(x + (size_t)row * 64 + c8 * 8 + 4);
    ushort8 o;
    o[0] = f2bf(v0.x); o[1] = f2bf(v0.y); o[2] = f2bf(v0.z); o[3] = f2bf(v0.w);
    o[4] = f2bf(v1.x); o[5] = f2bf(v1.y); o[6] = f2bf(v1.z); o[7] = f2bf(v1.w);
    *(ushort8*)(A + (size_t)row * 128 + 64 + c8 * 8) = o;
}

// ---------------------------------------------------------------------------
// Layer-1 weights to bf16, concatenated along K: B1[n][k] = k<64 ? Wl[n][k]
// : Wr[n][k-64]. Row-major [128][128] — already MFMA-B-fragment friendly.
// ---------------------------------------------------------------------------
__global__ void k_cast_w1(const float* __restrict__ W1um_l, const float* __restrict__ W1um_r,
                          const float* __restrict__ W1mu_l, const float* __restrict__ W1mu_r,
                          ushortT* __restrict__ B1m, ushortT* __restrict__ B1u)
{
    const int idx = blockIdx.x * blockDim.x + threadIdx.x;   // 4096 threads
    if (idx >= 4096) return;
    const int which = idx >> 11;          // 0: um -> B1m, 1: mu -> B1u
    const int rem = idx & 2047;
    const int n = rem >> 4;
    const int k0 = (rem & 15) * 8;
    const float* Wl = which ? W1mu_l : W1um_l;
    const float* Wr = which ? W1mu_r : W1um_r;
    const float* src = (k0 < 64) ? Wl + (size_t)n * 64 + k0 : Wr + (size_t)n * 64 + (k0 - 64);
    const float4 v0 = *(const float4*)src;
    const float4 v1 = *(const float4*)(src + 4);
    ushort8 o;
    o[0] = f2bf(v0.x); o[1] = f2bf(v0.y); o[2] = f2bf(v0.z); o[3] = f2bf(v0.w);
    o[4] = f2bf(v1.x); o[5] = f2bf(v1.y); o[6] = f2bf(v1.z); o[7] = f2bf(v1.w);
    ushortT* O = which ? B1u : B1m;
    *(ushort8*)(O + (size_t)n * 128 + k0) = o;
}

// ---------------------------------------------------------------------------
// Fused classifier weights (z never materialized), bf16 row-major [q][j][k]:
//   WP[j][k] = sum_i Wc1[j][i] * (k<128 ? W2_mu_l : W2_mu_r)[i][k%128]   (q=0)
//   WQ[j][k] = sum_i Wc1[j][128+i] * (k<128 ? W2_um_l : W2_um_r)[i][k%128]
// bPQ fp32 [2][128]: bP = bc1 + Wc1a@b2_mu_l ; bQ = Wc1b@b2_um_l
// ---------------------------------------------------------------------------
__global__ void k_wcombine(const float* __restrict__ Wc1,
                           const float* __restrict__ W2_mu_l, const float* __restrict__ W2_mu_r,
                           const float* __restrict__ W2_um_l, const float* __restrict__ W2_um_r,
                           const float* __restrict__ bc1,
                           const float* __restrict__ b2_mu_l, const float* __restrict__ b2_um_l,
                           ushortT* __restrict__ WPQ, float* __restrict__ bPQ)
{
    const int idx = blockIdx.x * blockDim.x + threadIdx.x;
    if (idx < 65536) {
        const int q = idx >> 15;
        const int j = (idx >> 8) & 127;
        const int k = idx & 255;
        const int kk = k & 127;
        const float* W2 = q ? (k < 128 ? W2_um_l : W2_um_r)
                            : (k < 128 ? W2_mu_l : W2_mu_r);
        const float* wrow = Wc1 + (size_t)j * 256 + q * 128;
        float s = 0.f;
        for (int i = 0; i < 128; ++i)
            s = fmaf(wrow[i], W2[(size_t)i * 128 + kk], s);
        WPQ[idx] = f2bf(s);
    } else if (idx < 65536 + 256) {
        const int r = idx - 65536;
        const int q = r >> 7, j = r & 127;
        const float* wrow = Wc1 + (size_t)j * 256 + q * 128;
        const float* b2 = q ? b2_um_l : b2_mu_l;
        float s = (q == 0) ? bc1[j] : 0.f;
        for (int i = 0; i < 128; ++i) s = fmaf(wrow[i], b2[i], s);
        bPQ[r] = s;
    }
}

// ---------------------------------------------------------------------------
// CSR build pass A: bucket the edges (packed (ldst<<16|src) u32 appends).
// ---------------------------------------------------------------------------
__global__ __launch_bounds__(256) void k_bucket(
    const int* __restrict__ rowA, const int* __restrict__ colA,
    const int* __restrict__ rowB, const int* __restrict__ colB,
    uint32_t* __restrict__ gcnt,                 // [2][NB], pre-zeroed
    uint32_t* __restrict__ bktA, uint32_t* __restrict__ bktB)
{
    __shared__ uint32_t hist[NB], base[NB], cur[NB];
    const int bpt = (NEC + ECHUNK - 1) / ECHUNK;
    const int type = (blockIdx.x >= bpt) ? 1 : 0;
    const int cb = blockIdx.x - type * bpt;
    const int* col = type ? colB : colA;
    const int* row = type ? rowB : rowA;
    uint32_t* bkt = type ? bktB : bktA;
    uint32_t* gc = gcnt + type * NB;

    const int e0 = cb * ECHUNK;
    const int e1 = (e0 + ECHUNK < NEC) ? e0 + ECHUNK : NEC;
    const int tx = threadIdx.x;

    for (int i = tx; i < NB; i += 256) { hist[i] = 0; cur[i] = 0; }
    __syncthreads();

    int cols[32];
#pragma unroll
    for (int q = 0; q < 32; ++q) {
        const int i = e0 + tx + q * 256;
        int c = -1;
        if (i < e1) { c = col[i]; atomicAdd(&hist[c >> 8], 1u); }
        cols[q] = c;
    }
    __syncthreads();
    for (int i = tx; i < NB; i += 256)
        base[i] = atomicAdd(&gc[i], hist[i]);
    __syncthreads();
#pragma unroll
    for (int q = 0; q < 32; ++q) {
        const int i = e0 + tx + q * 256;
        if (i < e1) {
            const int c = cols[q];
            const int b = c >> 8;
            const uint32_t p = base[b] + atomicAdd(&cur[b], 1u);
            if (p < BCAP)
                bkt[(size_t)b * BCAP + p] = ((uint32_t)(c & 255) << 16) | (uint32_t)row[i];
        }
    }
}

__global__ __launch_bounds__(256) void k_bscan(
    const uint32_t* __restrict__ gcnt, uint32_t* __restrict__ bbase,
    int* __restrict__ off_um, int* __restrict__ off_mu)
{
    __shared__ uint32_t sh0[256], sh1[256];
    const int t = threadIdx.x;
    const uint32_t v0 = (t < NB) ? gcnt[t] : 0;
    const uint32_t v1 = (t < NB) ? gcnt[NB + t] : 0;
    sh0[t] = v0; sh1[t] = v1;
    for (int d = 1; d < 256; d <<= 1) {
        __syncthreads();
        const uint32_t a0 = (t >= d) ? sh0[t - d] : 0;
        const uint32_t a1 = (t >= d) ? sh1[t - d] : 0;
        __syncthreads();
        sh0[t] += a0; sh1[t] += a1;
    }
    __syncthreads();
    if (t < NB) {
        bbase[t]      = sh0[t] - v0;
        bbase[NB + t] = sh1[t] - v1;
    }
    if (t == 0) { off_um[N_MERCHC] = NEC; off_mu[N_USERC] = NEC; }
}

__global__ __launch_bounds__(256) void k_bplace(
    const uint32_t* __restrict__ gcnt, const uint32_t* __restrict__ bbase,
    const uint32_t* __restrict__ bktA, const uint32_t* __restrict__ bktB,
    int* __restrict__ off_um, int* __restrict__ srcs_um,
    int* __restrict__ off_mu, int* __restrict__ srcs_mu)
{
    __shared__ uint32_t cnt[256], loff[256], cur[256];
    const int type = (blockIdx.x >= NB) ? 1 : 0;
    const int b = blockIdx.x - type * NB;
    const uint32_t* bkt = (type ? bktB : bktA) + (size_t)b * BCAP;
    int* offp = type ? off_mu : off_um;
    int* srcs = type ? srcs_mu : srcs_um;
    const int n = (int)gcnt[type * NB + b];
    const uint32_t gbase = bbase[type * NB + b];
    const int t = threadIdx.x;

    cnt[t] = 0; cur[t] = 0;
    __syncthreads();
    for (int i = t; i < n; i += 256)
        atomicAdd(&cnt[bkt[i] >> 16], 1u);
    __syncthreads();
    loff[t] = cnt[t];
    for (int d = 1; d < 256; d <<= 1) {
        __syncthreads();
        const uint32_t a = (t >= d) ? loff[t - d] : 0;
        __syncthreads();
        loff[t] += a;
    }
    __syncthreads();
    const uint32_t excl = loff[t] - cnt[t];
    const int dst0 = b << 8;
    if (dst0 + t < N_USERC) offp[dst0 + t] = (int)(gbase + excl);
    __syncthreads();
    loff[t] = excl;
    __syncthreads();
    for (int i = t; i < n; i += 256) {
        const uint32_t v = bkt[i];
        const uint32_t ld = v >> 16;
        const uint32_t p = gbase + loff[ld] + atomicAdd(&cur[ld], 1u);
        srcs[p] = (int)(v & 0xFFFFu);
    }
}

// ---------------------------------------------------------------------------
// Mean aggregation over the interleaved bf16 tables, both directions in one
// launch. Gathers the x/h sub-row at column offset D (rows stride 2D), writes
// the bf16 mean into column 0 of the destination table. fp32 accumulate.
// ---------------------------------------------------------------------------
template <int D>
__global__ __launch_bounds__(256) void k_agg(
    const ushortT* __restrict__ gA, const int* __restrict__ offsA,
    const int* __restrict__ srcsA, ushortT* __restrict__ oA,
    const ushortT* __restrict__ gB, const int* __restrict__ offsB,
    const int* __restrict__ srcsB, ushortT* __restrict__ oB, int ndst)
{
    constexpr int LPE = D / 8;      // lanes per edge row
    constexpr int EPW = 64 / LPE;   // edges per wave-iter
    constexpr int STR = 2 * D;      // interleaved row stride
    const int half = gridDim.x >> 1;
    const int type = (blockIdx.x >= half) ? 1 : 0;
    const int cb = blockIdx.x - type * half;
    const ushortT* g = type ? gB : gA;
    const int* offs  = type ? offsB : offsA;
    const int* srcs  = type ? srcsB : srcsA;
    ushortT* om      = type ? oB : oA;

    const int wid = cb * 4 + (threadIdx.x >> 6);
    if (wid >= ndst) return;
    const int lane = threadIdx.x & 63;
    const int sub  = lane / LPE;
    const int c4   = lane % LPE;

    const int b = offs[wid], e = offs[wid + 1];
    float a[8];
#pragma unroll
    for (int j = 0; j < 8; ++j) a[j] = 0.f;

    for (int i = b + sub; i < e; i += EPW) {
        const int s = srcs[i];
        const uint4 v = *(const uint4*)(g + (size_t)s * STR + D + c4 * 8);
        a[0] += bflo(v.x); a[1] += bfhi(v.x);
        a[2] += bflo(v.y); a[3] += bfhi(v.y);
        a[4] += bflo(v.z); a[5] += bfhi(v.z);
        a[6] += bflo(v.w); a[7] += bfhi(v.w);
    }
#pragma unroll
    for (int m = LPE; m < 64; m <<= 1) {
#pragma unroll
        for (int j = 0; j < 8; ++j) a[j] += __shfl_xor(a[j], m);
    }
    if (sub == 0) {
        const int deg = e - b;
        const float inv = 1.0f / (float)(deg > 1 ? deg : 1);
        ushort8 o;
#pragma unroll
        for (int j = 0; j < 8; ++j) o[j] = f2bf(a[j] * inv);
        *(ushort8*)(om + (size_t)wid * STR + c4 * 8) = o;
    }
}

// ---------------------------------------------------------------------------
// MFMA bf16 GEMM: Out[m][0:128] = act(A[m][0:K] @ W^T + bias), bf16 out.
// A: [M][K] bf16 row-major. W: [128][K] bf16 row-major (= B-fragment native:
// lane holds W[n=lane&15][k=quad*8+j], contiguous 16B). A-fragment: lane holds
// A[m=lane&15][k=quad*8+j], contiguous 16B. C/D: col=lane&15, row=quad*4+reg.
// Wave tile 16x128 (8 acc), block = 4 waves = 64 rows. Epilogue repacks
// through a per-wave LDS tile into 16B bf16 stores at Obf + m*OS + OO.
// ---------------------------------------------------------------------------
template <int K, bool RELU>
__global__ __launch_bounds__(256) void k_mfma_gemm(
    const ushortT* __restrict__ A, const ushortT* __restrict__ Bw,
    const float* __restrict__ bias,
    ushortT* __restrict__ Obf, int OS, int OO, int M)
{
    __shared__ float lds[4][16][132];   // per-wave 16x128 f32 tile (+4 pad)
    const int tx = threadIdx.x;
    const int wid = tx >> 6;
    const int lane = tx & 63;
    const int ln = lane & 15;
    const int quad = lane >> 4;
    const int m0 = blockIdx.x * 64 + wid * 16;
    int arow = m0 + ln; if (arow >= M) arow = M - 1;
    const ushortT* ap = A + (size_t)arow * K + quad * 8;

    f32x4 acc[8];
#pragma unroll
    for (int i = 0; i < 8; ++i) acc[i] = (f32x4){0.f, 0.f, 0.f, 0.f};

#pragma unroll
    for (int kc = 0; kc < K / 32; ++kc) {
        const short8 a = *(const short8*)(ap + kc * 32);
#pragma unroll
        for (int nt = 0; nt < 8; ++nt) {
            const short8 b = *(const short8*)(Bw + (size_t)(nt * 16 + ln) * K + kc * 32 + quad * 8);
            acc[nt] = __builtin_amdgcn_mfma_f32_16x16x32_bf16(a, b, acc[nt], 0, 0, 0);
        }
    }

    // bias + act into the wave's LDS tile
    float (*t)[132] = lds[wid];
#pragma unroll
    for (int nt = 0; nt < 8; ++nt) {
        const float bv = bias[nt * 16 + ln];
#pragma unroll
        for (int r = 0; r < 4; ++r) {
            float v = acc[nt][r] + bv;
            if (RELU) v = fmaxf(v, 0.f);
            t[quad * 4 + r][nt * 16 + ln] = v;
        }
    }
    // repack: each lane stores 8 consecutive cols of one row as 16B bf16
#pragma unroll
    for (int p = 0; p < 4; ++p) {
        const int row = p * 4 + quad;
        const int gr = m0 + row;
        if (gr < M) {
            const float4 v0 = *(const float4*)&t[row][ln * 8];
            const float4 v1 = *(const float4*)&t[row][ln * 8 + 4];
            ushort8 o;
            o[0] = f2bf(v0.x); o[1] = f2bf(v0.y); o[2] = f2bf(v0.z); o[3] = f2bf(v0.w);
            o[4] = f2bf(v1.x); o[5] = f2bf(v1.y); o[6] = f2bf(v1.z); o[7] = f2bf(v1.w);
            *(ushort8*)(Obf + (size_t)gr * OS + OO + ln * 8) = o;
        }
    }
}

// ---------------------------------------------------------------------------
// Edge classifier on bf16 P/Q: out[e] = bc2 + sum_j relu(P[r][j]+Q[c][j])*wc2[j]
// ---------------------------------------------------------------------------
__global__ __launch_bounds__(256) void k_edge_bf(
    const ushortT* __restrict__ P, const ushortT* __restrict__ Q,
    const int* __restrict__ er, const int* __restrict__ ec,
    const float* __restrict__ wc2, const float* __restrict__ bc2,
    float* __restrict__ out, int nt)
{
    const int lane = threadIdx.x & 63;
    const int sub = lane >> 4;       // edge within wave (4)
    const int c8 = lane & 15;        // 8-elem group within row
    const int wid = (int)((blockIdx.x * blockDim.x + threadIdx.x) >> 6);
    const int e0 = wid * 4 + sub;
    if (e0 >= nt) return;

    const float4 w0 = ((const float4*)wc2)[c8 * 2];
    const float4 w1 = ((const float4*)wc2)[c8 * 2 + 1];
    const int r = er[e0], c = ec[e0];
    const uint4 pv = *(const uint4*)(P + (size_t)r * 128 + c8 * 8);
    const uint4 qv = *(const uint4*)(Q + (size_t)c * 128 + c8 * 8);
    float s = fmaxf(bflo(pv.x) + bflo(qv.x), 0.f) * w0.x
            + fmaxf(bfhi(pv.x) + bfhi(qv.x), 0.f) * w0.y
            + fmaxf(bflo(pv.y) + bflo(qv.y), 0.f) * w0.z
            + fmaxf(bfhi(pv.y) + bfhi(qv.y), 0.f) * w0.w
            + fmaxf(bflo(pv.z) + bflo(qv.z), 0.f) * w1.x
            + fmaxf(bfhi(pv.z) + bfhi(qv.z), 0.f) * w1.y
            + fmaxf(bflo(pv.w) + bflo(qv.w), 0.f) * w1.z
            + fmaxf(bfhi(pv.w) + bfhi(qv.w), 0.f) * w1.w;
    s += __shfl_xor(s, 1);
    s += __shfl_xor(s, 2);
    s += __shfl_xor(s, 4);
    s += __shfl_xor(s, 8);
    if (c8 == 0) out[e0] = s + bc2[0];
}

// ---------------------------------------------------------------------------
// Host launcher
// ---------------------------------------------------------------------------
extern "C" void kernel_launch(void* const* d_in, const int* in_sizes, int n_in,
                              void* d_out, int out_size, void* d_ws, size_t ws_size,
                              hipStream_t stream)
{
    const float* x_user  = (const float*)d_in[0];
    const float* x_merch = (const float*)d_in[1];
    const int*   e_um    = (const int*)d_in[2];
    const int*   e_mu    = (const int*)d_in[3];
    const int*   tgt     = (const int*)d_in[4];
    const float* W1_um_l = (const float*)d_in[5];
    const float* b1_um_l = (const float*)d_in[6];
    const float* W1_um_r = (const float*)d_in[7];
    const float* W1_mu_l = (const float*)d_in[8];
    const float* b1_mu_l = (const float*)d_in[9];
    const float* W1_mu_r = (const float*)d_in[10];
    const float* W2_um_l = (const float*)d_in[11];
    const float* b2_um_l = (const float*)d_in[12];
    const float* W2_um_r = (const float*)d_in[13];
    const float* W2_mu_l = (const float*)d_in[14];
    const float* b2_mu_l = (const float*)d_in[15];
    const float* W2_mu_r = (const float*)d_in[16];
    const float* Wc1     = (const float*)d_in[17];
    const float* bc1     = (const float*)d_in[18];
    const float* Wc2     = (const float*)d_in[19];
    const float* bc2     = (const float*)d_in[20];
    float* out = (float*)d_out;

    // ---- workspace carve-up (u32 words, 64-word aligned), ~86 MB
    uint32_t* B = (uint32_t*)d_ws;
    size_t pos = 0;
    auto take = [&](size_t n) { size_t p = pos; pos += (n + 63) & ~(size_t)63; return p; };

    uint32_t* gcnt = (uint32_t*)(B + take(2 * NB));     // zeroed each launch
    const size_t cnt_words = pos;
    uint32_t* bbase = (uint32_t*)(B + take(2 * NB));
    int* off_um  = (int*)(B + take(N_MERCHC + 1));
    int* srcs_um = (int*)(B + take(NEC));
    int* off_mu  = (int*)(B + take(N_USERC + 1));
    int* srcs_mu = (int*)(B + take(NEC));
    ushortT* A1u = (ushortT*)(B + take((size_t)N_USERC  * 128 / 2));  // [mean1_u | x_u]
    ushortT* A1m = (ushortT*)(B + take((size_t)N_MERCHC * 128 / 2));  // [mean1_m | x_m]
    ushortT* A2u = (ushortT*)(B + take((size_t)N_USERC  * 256 / 2));  // [mean2_u | h_u]
    ushortT* A2m = (ushortT*)(B + take((size_t)N_MERCHC * 256 / 2));  // [mean2_m | h_m]
    ushortT* B1m = (ushortT*)(B + take(8192));          // [W1_um_l | W1_um_r] bf16 [128][128]
    ushortT* B1u = (ushortT*)(B + take(8192));          // [W1_mu_l | W1_mu_r]
    ushortT* WPQ = (ushortT*)(B + take(32768));         // fused [2][128][256] bf16
    float*   bPQ = (float*)(B + take(256));             // fused biases [2][128] fp32

    // ---- aliases (lifetimes):
    // buckets: CSR build only; A2m's h/mean parts written later (GEMM1/agg2)
    uint32_t* bktA = (uint32_t*)A2m;
    uint32_t* bktB = bktA + (size_t)NB * BCAP;          // 3.2M words <= 6.4M
    // P/Q: written by GEMM2 (A1 dead after GEMM1), read by edge kernel
    ushortT* Pbf = A1u;
    ushortT* Qbf = A1m;
    (void)ws_size; (void)in_sizes; (void)n_in; (void)out_size;

    // 1) zero bucket counters
    hipMemsetAsync(d_ws, 0, cnt_words * sizeof(uint32_t), stream);

    // 2) prep: x casts into A1, layer-1 weight casts, fused classifier weights
    k_cast_x<<<(800000 + 255) / 256, 256, 0, stream>>>(x_user, x_merch, A1u, A1m);
    k_cast_w1<<<16, 256, 0, stream>>>(W1_um_l, W1_um_r, W1_mu_l, W1_mu_r, B1m, B1u);
    k_wcombine<<<(65536 + 256 + 255) / 256, 256, 0, stream>>>(
        Wc1, W2_mu_l, W2_mu_r, W2_um_l, W2_um_r, bc1, b2_mu_l, b2_um_l, WPQ, bPQ);

    // 3) CSR build: bucket -> scan -> place (also writes off arrays)
    const int bpt = (NEC + ECHUNK - 1) / ECHUNK;
    k_bucket<<<2 * bpt, 256, 0, stream>>>(e_um, e_um + NEC, e_mu, e_mu + NEC,
                                          gcnt, bktA, bktB);
    k_bscan<<<1, 256, 0, stream>>>(gcnt, bbase, off_um, off_mu);
    k_bplace<<<2 * NB, 256, 0, stream>>>(gcnt, bbase, bktA, bktB,
                                         off_um, srcs_um, off_mu, srcs_mu);

    // 4) layer-1 aggregates: gather x parts, write mean1 parts (bf16)
    const int agrid = 50000 / 4;
    k_agg<64><<<2 * agrid, 256, 0, stream>>>(
        A1u, off_um, srcs_um, A1m,
        A1m, off_mu, srcs_mu, A1u, N_MERCHC);

    // 5) layer-1 MFMA GEMMs: h = relu(A1 @ B1^T + b1) -> A2 cols 128..255
    const int ggrid = (50000 + 63) / 64;
    k_mfma_gemm<128, true><<<ggrid, 256, 0, stream>>>(A1m, B1m, b1_um_l, A2m, 256, 128, N_MERCHC);
    k_mfma_gemm<128, true><<<ggrid, 256, 0, stream>>>(A1u, B1u, b1_mu_l, A2u, 256, 128, N_USERC);

    // 6) layer-2 aggregates: gather h parts, write mean2 parts (bf16)
    k_agg<128><<<2 * agrid, 256, 0, stream>>>(
        A2u, off_um, srcs_um, A2m,
        A2m, off_mu, srcs_mu, A2u, N_MERCHC);

    // 7) fused classifier MFMA GEMMs: P = A2u @ WP^T + bP ; Q = A2m @ WQ^T + bQ
    k_mfma_gemm<256, false><<<ggrid, 256, 0, stream>>>(A2u, WPQ,         bPQ,       Pbf, 128, 0, N_USERC);
    k_mfma_gemm<256, false><<<ggrid, 256, 0, stream>>>(A2m, WPQ + 32768, bPQ + 128, Qbf, 128, 0, N_MERCHC);

    // 8) per-edge: out = bc2 + relu(P[r]+Q[c]) . wc2  (bf16 gathers)
    const int cgrid = (NTC + 15) / 16;   // 4 edges/wave, 4 waves/block
    k_edge_bf<<<cgrid, 256, 0, stream>>>(Pbf, Qbf, tgt, tgt + NTC, Wc2, bc2, out, NTC);
}

// Round 8
// 430.562 us; speedup vs baseline: 3.3376x; 1.0215x over previous
//
#include <hip/hip_runtime.h>
#include <hip/hip_bf16.h>
#include <stdint.h>

#define N_USERC  50000
#define N_MERCHC 50000
#define NEC      1000000   // edges per direction
#define NTC      500000    // target edges

#define NB    196          // dst buckets (256 dsts each: bucket = dst >> 8)
#define BCAP  8192         // pairs per bucket (mean 5120, sigma ~72, +43 sigma cap)
#define ECHUNK 8192        // edges per bucket-pass block (32/thread)
#define BPT   123          // bucket-pass blocks per edge type = ceil(NEC/ECHUNK)

// k_prep fused-grid offsets
#define PREP_CASTX  3125   // 800000/256
#define PREP_CASTW  (PREP_CASTX + 16)
#define PREP_WC     (PREP_CASTW + 257)
#define PREP_BKT    (PREP_WC + 2 * BPT)     // total grid

typedef unsigned short ushortT;
typedef __attribute__((ext_vector_type(8))) short short8;     // 8 bf16 (MFMA frag)
typedef __attribute__((ext_vector_type(8))) unsigned short ushort8;
typedef __attribute__((ext_vector_type(4))) float f32x4;

__device__ __forceinline__ unsigned short f2bf(float f)
{
    const unsigned u = __float_as_uint(f);
    const unsigned r = u + 0x7fffu + ((u >> 16) & 1u);   // RNE
    return (unsigned short)(r >> 16);
}
__device__ __forceinline__ float bfhi(unsigned u) { return __uint_as_float(u & 0xffff0000u); }
__device__ __forceinline__ float bflo(unsigned u) { return __uint_as_float(u << 16); }

// ---------------------------------------------------------------------------
// Fused prep kernel: blockIdx ranges dispatch 4 independent jobs.
//  [0, 3125)      cast x tables -> interleaved A1 ([mean1 | x], bf16)
//  [3125, 3141)   cast layer-1 weights -> B1 ([Wl | Wr] along K, bf16 row-major)
//  [3141, 3398)   fused classifier weights WPQ/bPQ (z never materialized)
//  [3398, 3644)   CSR bucket pass (packed (ldst<<16|src) appends)
// ---------------------------------------------------------------------------
__global__ __launch_bounds__(256) void k_prep(
    const float* __restrict__ xu, const float* __restrict__ xm,
    ushortT* __restrict__ A1u, ushortT* __restrict__ A1m,
    const float* __restrict__ W1um_l, const float* __restrict__ W1um_r,
    const float* __restrict__ W1mu_l, const float* __restrict__ W1mu_r,
    ushortT* __restrict__ B1m, ushortT* __restrict__ B1u,
    const float* __restrict__ Wc1,
    const float* __restrict__ W2mu_l, const float* __restrict__ W2mu_r,
    const float* __restrict__ W2um_l, const float* __restrict__ W2um_r,
    const float* __restrict__ bc1,
    const float* __restrict__ b2mu_l, const float* __restrict__ b2um_l,
    ushortT* __restrict__ WPQ, float* __restrict__ bPQ,
    const int* __restrict__ rowA, const int* __restrict__ colA,
    const int* __restrict__ rowB, const int* __restrict__ colB,
    uint32_t* __restrict__ gcnt, uint32_t* __restrict__ bktA, uint32_t* __restrict__ bktB)
{
    __shared__ uint32_t hist[NB], base[NB], cur[NB];
    const int bid = blockIdx.x;
    const int tx = threadIdx.x;

    if (bid < PREP_CASTX) {
        // ---- cast_x: A1[row] = [ (mean later) | bf16(x[row]) ]
        const int idx = bid * 256 + tx;
        if (idx >= 800000) return;
        const int which = idx / 400000;
        const int rem = idx - which * 400000;
        const int row = rem >> 3;
        const int c8 = rem & 7;
        const float* x = which ? xm : xu;
        ushortT* A = which ? A1m : A1u;
        const float4 v0 = *(const float4*)(x + (size_t)row * 64 + c8 * 8);
        const float4 v1 = *(const float4*)(x + (size_t)row * 64 + c8 * 8 + 4);
        ushort8 o;
        o[0] = f2bf(v0.x); o[1] = f2bf(v0.y); o[2] = f2bf(v0.z); o[3] = f2bf(v0.w);
        o[4] = f2bf(v1.x); o[5] = f2bf(v1.y); o[6] = f2bf(v1.z); o[7] = f2bf(v1.w);
        *(ushort8*)(A + (size_t)row * 128 + 64 + c8 * 8) = o;
    } else if (bid < PREP_CASTW) {
        // ---- cast_w1: B1[n][k] = k<64 ? Wl[n][k] : Wr[n][k-64]
        const int idx = (bid - PREP_CASTX) * 256 + tx;
        if (idx >= 4096) return;
        const int which = idx >> 11;
        const int rem = idx & 2047;
        const int n = rem >> 4;
        const int k0 = (rem & 15) * 8;
        const float* Wl = which ? W1mu_l : W1um_l;
        const float* Wr = which ? W1mu_r : W1um_r;
        const float* src = (k0 < 64) ? Wl + (size_t)n * 64 + k0
                                     : Wr + (size_t)n * 64 + (k0 - 64);
        const float4 v0 = *(const float4*)src;
        const float4 v1 = *(const float4*)(src + 4);
        ushort8 o;
        o[0] = f2bf(v0.x); o[1] = f2bf(v0.y); o[2] = f2bf(v0.z); o[3] = f2bf(v0.w);
        o[4] = f2bf(v1.x); o[5] = f2bf(v1.y); o[6] = f2bf(v1.z); o[7] = f2bf(v1.w);
        ushortT* O = which ? B1u : B1m;
        *(ushort8*)(O + (size_t)n * 128 + k0) = o;
    } else if (bid < PREP_WC) {
        // ---- wcombine: WP[j][k] = Wc1a[j,:] @ W2_mu_{l|r}[:,k] etc., bf16
        const int idx = (bid - PREP_CASTW) * 256 + tx;
        if (idx < 65536) {
            const int q = idx >> 15;
            const int j = (idx >> 8) & 127;
            const int k = idx & 255;
            const int kk = k & 127;
            const float* W2 = q ? (k < 128 ? W2um_l : W2um_r)
                                : (k < 128 ? W2mu_l : W2mu_r);
            const float* wrow = Wc1 + (size_t)j * 256 + q * 128;
            float s = 0.f;
            for (int i = 0; i < 128; ++i)
                s = fmaf(wrow[i], W2[(size_t)i * 128 + kk], s);
            WPQ[idx] = f2bf(s);
        } else if (idx < 65536 + 256) {
            const int r = idx - 65536;
            const int q = r >> 7, j = r & 127;
            const float* wrow = Wc1 + (size_t)j * 256 + q * 128;
            const float* b2 = q ? b2um_l : b2mu_l;
            float s = (q == 0) ? bc1[j] : 0.f;
            for (int i = 0; i < 128; ++i) s = fmaf(wrow[i], b2[i], s);
            bPQ[r] = s;
        }
    } else {
        // ---- CSR bucket pass
        const int cb2 = bid - PREP_WC;
        const int type = (cb2 >= BPT) ? 1 : 0;
        const int cb = cb2 - type * BPT;
        const int* col = type ? colB : colA;
        const int* row = type ? rowB : rowA;
        uint32_t* bkt = type ? bktB : bktA;
        uint32_t* gc = gcnt + type * NB;

        const int e0 = cb * ECHUNK;
        const int e1 = (e0 + ECHUNK < NEC) ? e0 + ECHUNK : NEC;

        for (int i = tx; i < NB; i += 256) { hist[i] = 0; cur[i] = 0; }
        __syncthreads();

        int cols[32];
#pragma unroll
        for (int q = 0; q < 32; ++q) {
            const int i = e0 + tx + q * 256;
            int c = -1;
            if (i < e1) { c = col[i]; atomicAdd(&hist[c >> 8], 1u); }
            cols[q] = c;
        }
        __syncthreads();
        for (int i = tx; i < NB; i += 256)
            base[i] = atomicAdd(&gc[i], hist[i]);
        __syncthreads();
#pragma unroll
        for (int q = 0; q < 32; ++q) {
            const int i = e0 + tx + q * 256;
            if (i < e1) {
                const int c = cols[q];
                const int b = c >> 8;
                const uint32_t p = base[b] + atomicAdd(&cur[b], 1u);
                if (p < BCAP)
                    bkt[(size_t)b * BCAP + p] = ((uint32_t)(c & 255) << 16) | (uint32_t)row[i];
            }
        }
    }
}

// ---------------------------------------------------------------------------
// CSR place pass with inline bucket-base scan: each block scans its type's
// 196 bucket counts in LDS, then counts per local dst, scans, writes the off
// array, and places srcs into the bucket's contiguous CSR window.
// ---------------------------------------------------------------------------
__global__ __launch_bounds__(256) void k_bplace(
    const uint32_t* __restrict__ gcnt,
    const uint32_t* __restrict__ bktA, const uint32_t* __restrict__ bktB,
    int* __restrict__ off_um, int* __restrict__ srcs_um,
    int* __restrict__ off_mu, int* __restrict__ srcs_mu)
{
    __shared__ uint32_t sb[256], cnt[256], loff[256], cur[256];
    const int type = (blockIdx.x >= NB) ? 1 : 0;
    const int b = blockIdx.x - type * NB;
    const uint32_t* bkt = (type ? bktB : bktA) + (size_t)b * BCAP;
    int* offp = type ? off_mu : off_um;
    int* srcs = type ? srcs_mu : srcs_um;
    const int t = threadIdx.x;

    // inline exclusive scan of this type's bucket counts
    const uint32_t gv = (t < NB) ? gcnt[type * NB + t] : 0;
    sb[t] = gv;
    for (int d = 1; d < 256; d <<= 1) {
        __syncthreads();
        const uint32_t a = (t >= d) ? sb[t - d] : 0;
        __syncthreads();
        sb[t] += a;
    }
    __syncthreads();
    const int n = (int)gcnt[type * NB + b];
    const uint32_t gbase = sb[b] - (uint32_t)n;   // exclusive prefix at b
    if (blockIdx.x == 0 && t == 0)  off_um[N_MERCHC] = NEC;
    if (blockIdx.x == NB && t == 0) off_mu[N_USERC] = NEC;
    __syncthreads();

    cnt[t] = 0; cur[t] = 0;
    __syncthreads();
    for (int i = t; i < n; i += 256)
        atomicAdd(&cnt[bkt[i] >> 16], 1u);
    __syncthreads();
    loff[t] = cnt[t];
    for (int d = 1; d < 256; d <<= 1) {
        __syncthreads();
        const uint32_t a = (t >= d) ? loff[t - d] : 0;
        __syncthreads();
        loff[t] += a;
    }
    __syncthreads();
    const uint32_t excl = loff[t] - cnt[t];
    const int dst0 = b << 8;
    if (dst0 + t < N_USERC) offp[dst0 + t] = (int)(gbase + excl);
    __syncthreads();
    loff[t] = excl;
    __syncthreads();
    for (int i = t; i < n; i += 256) {
        const uint32_t v = bkt[i];
        const uint32_t ld = v >> 16;
        const uint32_t p = gbase + loff[ld] + atomicAdd(&cur[ld], 1u);
        srcs[p] = (int)(v & 0xFFFFu);
    }
}

// ---------------------------------------------------------------------------
// Mean aggregation over interleaved bf16 tables, both directions per launch.
// (R6-proven version: direct per-iteration srcs load, single accumulator.)
// ---------------------------------------------------------------------------
template <int D>
__global__ __launch_bounds__(256) void k_agg(
    const ushortT* __restrict__ gA, const int* __restrict__ offsA,
    const int* __restrict__ srcsA, ushortT* __restrict__ oA,
    const ushortT* __restrict__ gB, const int* __restrict__ offsB,
    const int* __restrict__ srcsB, ushortT* __restrict__ oB, int ndst)
{
    constexpr int LPE = D / 8;      // lanes per edge row
    constexpr int EPW = 64 / LPE;   // edges per wave-iter
    constexpr int STR = 2 * D;      // interleaved row stride (elems)
    const int half = gridDim.x >> 1;
    const int type = (blockIdx.x >= half) ? 1 : 0;
    const int cb = blockIdx.x - type * half;
    const ushortT* g = type ? gB : gA;
    const int* offs  = type ? offsB : offsA;
    const int* srcs  = type ? srcsB : srcsA;
    ushortT* om      = type ? oB : oA;

    const int wid = cb * 4 + (threadIdx.x >> 6);
    if (wid >= ndst) return;
    const int lane = threadIdx.x & 63;
    const int sub  = lane / LPE;
    const int c4   = lane % LPE;

    const int b = offs[wid], e = offs[wid + 1];
    float a[8];
#pragma unroll
    for (int j = 0; j < 8; ++j) a[j] = 0.f;

    for (int i = b + sub; i < e; i += EPW) {
        const int s = srcs[i];
        const uint4 v = *(const uint4*)(g + (size_t)s * STR + D + c4 * 8);
        a[0] += bflo(v.x); a[1] += bfhi(v.x);
        a[2] += bflo(v.y); a[3] += bfhi(v.y);
        a[4] += bflo(v.z); a[5] += bfhi(v.z);
        a[6] += bflo(v.w); a[7] += bfhi(v.w);
    }
#pragma unroll
    for (int m = LPE; m < 64; m <<= 1) {
#pragma unroll
        for (int j = 0; j < 8; ++j) a[j] += __shfl_xor(a[j], m);
    }
    if (sub == 0) {
        const int deg = e - b;
        const float inv = 1.0f / (float)(deg > 1 ? deg : 1);
        ushort8 o;
#pragma unroll
        for (int j = 0; j < 8; ++j) o[j] = f2bf(a[j] * inv);
        *(ushort8*)(om + (size_t)wid * STR + c4 * 8) = o;
    }
}

// ---------------------------------------------------------------------------
// MFMA bf16 GEMM pair (two independent problems in one launch):
//   Out[m][0:128] = act(A[m][0:K] @ W^T + bias), bf16 out at Obf + m*OS + OO.
// A row-major = A-fragment native; W [128][K] row-major = B-fragment native.
// C/D: col=lane&15, row=quad*4+reg. Wave tile 16x128, block 4 waves.
// ---------------------------------------------------------------------------
template <int K, bool RELU>
__device__ __forceinline__ void mfma_gemm_body(
    int cb, float (*lds)[16][132],
    const ushortT* __restrict__ A, const ushortT* __restrict__ Bw,
    const float* __restrict__ bias,
    ushortT* __restrict__ Obf, int OS, int OO, int M)
{
    const int tx = threadIdx.x;
    const int wid = tx >> 6;
    const int lane = tx & 63;
    const int ln = lane & 15;
    const int quad = lane >> 4;
    const int m0 = cb * 64 + wid * 16;
    int arow = m0 + ln; if (arow >= M) arow = M - 1;
    const ushortT* ap = A + (size_t)arow * K + quad * 8;

    f32x4 acc[8];
#pragma unroll
    for (int i = 0; i < 8; ++i) acc[i] = (f32x4){0.f, 0.f, 0.f, 0.f};

#pragma unroll
    for (int kc = 0; kc < K / 32; ++kc) {
        const short8 a = *(const short8*)(ap + kc * 32);
#pragma unroll
        for (int nt = 0; nt < 8; ++nt) {
            const short8 b = *(const short8*)(Bw + (size_t)(nt * 16 + ln) * K + kc * 32 + quad * 8);
            acc[nt] = __builtin_amdgcn_mfma_f32_16x16x32_bf16(a, b, acc[nt], 0, 0, 0);
        }
    }

    float (*t)[132] = lds[wid];
#pragma unroll
    for (int nt = 0; nt < 8; ++nt) {
        const float bv = bias[nt * 16 + ln];
#pragma unroll
        for (int r = 0; r < 4; ++r) {
            float v = acc[nt][r] + bv;
            if (RELU) v = fmaxf(v, 0.f);
            t[quad * 4 + r][nt * 16 + ln] = v;
        }
    }
#pragma unroll
    for (int p = 0; p < 4; ++p) {
        const int row = p * 4 + quad;
        const int gr = m0 + row;
        if (gr < M) {
            const float4 v0 = *(const float4*)&t[row][ln * 8];
            const float4 v1 = *(const float4*)&t[row][ln * 8 + 4];
            ushort8 o;
            o[0] = f2bf(v0.x); o[1] = f2bf(v0.y); o[2] = f2bf(v0.z); o[3] = f2bf(v0.w);
            o[4] = f2bf(v1.x); o[5] = f2bf(v1.y); o[6] = f2bf(v1.z); o[7] = f2bf(v1.w);
            *(ushort8*)(Obf + (size_t)gr * OS + OO + ln * 8) = o;
        }
    }
}

template <int K, bool RELU>
__global__ __launch_bounds__(256) void k_mfma_gemm2(
    const ushortT* __restrict__ Aa, const ushortT* __restrict__ Bwa,
    const float* __restrict__ biasa, ushortT* __restrict__ Oa, int OSa, int OOa, int Ma,
    const ushortT* __restrict__ Ab, const ushortT* __restrict__ Bwb,
    const float* __restrict__ biasb, ushortT* __restrict__ Ob, int OSb, int OOb, int Mb,
    int gridA)
{
    __shared__ float lds[4][16][132];
    if ((int)blockIdx.x < gridA)
        mfma_gemm_body<K, RELU>(blockIdx.x, lds, Aa, Bwa, biasa, Oa, OSa, OOa, Ma);
    else
        mfma_gemm_body<K, RELU>(blockIdx.x - gridA, lds, Ab, Bwb, biasb, Ob, OSb, OOb, Mb);
}

// ---------------------------------------------------------------------------
// Edge classifier on bf16 P/Q: out[e] = bc2 + sum_j relu(P[r][j]+Q[c][j])*wc2[j]
// ---------------------------------------------------------------------------
__global__ __launch_bounds__(256) void k_edge_bf(
    const ushortT* __restrict__ P, const ushortT* __restrict__ Q,
    const int* __restrict__ er, const int* __restrict__ ec,
    const float* __restrict__ wc2, const float* __restrict__ bc2,
    float* __restrict__ out, int nt)
{
    const int lane = threadIdx.x & 63;
    const int sub = lane >> 4;       // edge within wave (4)
    const int c8 = lane & 15;        // 8-elem group within row
    const int wid = (int)((blockIdx.x * blockDim.x + threadIdx.x) >> 6);
    const int e0 = wid * 4 + sub;
    if (e0 >= nt) return;

    const float4 w0 = ((const float4*)wc2)[c8 * 2];
    const float4 w1 = ((const float4*)wc2)[c8 * 2 + 1];
    const int r = er[e0], c = ec[e0];
    const uint4 pv = *(const uint4*)(P + (size_t)r * 128 + c8 * 8);
    const uint4 qv = *(const uint4*)(Q + (size_t)c * 128 + c8 * 8);
    float s = fmaxf(bflo(pv.x) + bflo(qv.x), 0.f) * w0.x
            + fmaxf(bfhi(pv.x) + bfhi(qv.x), 0.f) * w0.y
            + fmaxf(bflo(pv.y) + bflo(qv.y), 0.f) * w0.z
            + fmaxf(bfhi(pv.y) + bfhi(qv.y), 0.f) * w0.w
            + fmaxf(bflo(pv.z) + bflo(qv.z), 0.f) * w1.x
            + fmaxf(bfhi(pv.z) + bfhi(qv.z), 0.f) * w1.y
            + fmaxf(bflo(pv.w) + bflo(qv.w), 0.f) * w1.z
            + fmaxf(bfhi(pv.w) + bfhi(qv.w), 0.f) * w1.w;
    s += __shfl_xor(s, 1);
    s += __shfl_xor(s, 2);
    s += __shfl_xor(s, 4);
    s += __shfl_xor(s, 8);
    if (c8 == 0) out[e0] = s + bc2[0];
}

// ---------------------------------------------------------------------------
// Host launcher
// ---------------------------------------------------------------------------
extern "C" void kernel_launch(void* const* d_in, const int* in_sizes, int n_in,
                              void* d_out, int out_size, void* d_ws, size_t ws_size,
                              hipStream_t stream)
{
    const float* x_user  = (const float*)d_in[0];
    const float* x_merch = (const float*)d_in[1];
    const int*   e_um    = (const int*)d_in[2];
    const int*   e_mu    = (const int*)d_in[3];
    const int*   tgt     = (const int*)d_in[4];
    const float* W1_um_l = (const float*)d_in[5];
    const float* b1_um_l = (const float*)d_in[6];
    const float* W1_um_r = (const float*)d_in[7];
    const float* W1_mu_l = (const float*)d_in[8];
    const float* b1_mu_l = (const float*)d_in[9];
    const float* W1_mu_r = (const float*)d_in[10];
    const float* W2_um_l = (const float*)d_in[11];
    const float* b2_um_l = (const float*)d_in[12];
    const float* W2_um_r = (const float*)d_in[13];
    const float* W2_mu_l = (const float*)d_in[14];
    const float* b2_mu_l = (const float*)d_in[15];
    const float* W2_mu_r = (const float*)d_in[16];
    const float* Wc1     = (const float*)d_in[17];
    const float* bc1     = (const float*)d_in[18];
    const float* Wc2     = (const float*)d_in[19];
    const float* bc2     = (const float*)d_in[20];
    float* out = (float*)d_out;

    // ---- workspace carve-up (u32 words, 64-word aligned)
    uint32_t* B = (uint32_t*)d_ws;
    size_t pos = 0;
    auto take = [&](size_t n) { size_t p = pos; pos += (n + 63) & ~(size_t)63; return p; };

    uint32_t* gcnt = (uint32_t*)(B + take(2 * NB));     // zeroed each launch
    const size_t cnt_words = pos;
    int* off_um  = (int*)(B + take(N_MERCHC + 1));
    int* srcs_um = (int*)(B + take(NEC));
    int* off_mu  = (int*)(B + take(N_USERC + 1));
    int* srcs_mu = (int*)(B + take(NEC));
    ushortT* A1u = (ushortT*)(B + take((size_t)N_USERC  * 128 / 2));  // [mean1_u | x_u]
    ushortT* A1m = (ushortT*)(B + take((size_t)N_MERCHC * 128 / 2));  // [mean1_m | x_m]
    ushortT* A2u = (ushortT*)(B + take((size_t)N_USERC  * 256 / 2));  // [mean2_u | h_u]
    ushortT* A2m = (ushortT*)(B + take((size_t)N_MERCHC * 256 / 2));  // [mean2_m | h_m]
    ushortT* B1m = (ushortT*)(B + take(8192));          // [W1_um_l | W1_um_r] bf16
    ushortT* B1u = (ushortT*)(B + take(8192));          // [W1_mu_l | W1_mu_r]
    ushortT* WPQ = (ushortT*)(B + take(32768));         // fused [2][128][256] bf16
    float*   bPQ = (float*)(B + take(256));             // fused biases [2][128] fp32

    // ---- aliases (lifetimes):
    // buckets: CSR build only; A2m's halves are written later (GEMM1 / agg2)
    uint32_t* bktA = (uint32_t*)A2m;
    uint32_t* bktB = bktA + (size_t)NB * BCAP;          // 3.2M words <= 6.4M
    // P/Q: written by classifier GEMMs (A1 dead after GEMM1), read by k_edge
    ushortT* Pbf = A1u;
    ushortT* Qbf = A1m;
    (void)ws_size; (void)in_sizes; (void)n_in; (void)out_size;

    // 1) zero bucket counters
    hipMemsetAsync(d_ws, 0, cnt_words * sizeof(uint32_t), stream);

    // 2) fused prep: x casts + weight casts + classifier weight fusion + CSR bucket
    k_prep<<<PREP_BKT, 256, 0, stream>>>(
        x_user, x_merch, A1u, A1m,
        W1_um_l, W1_um_r, W1_mu_l, W1_mu_r, B1m, B1u,
        Wc1, W2_mu_l, W2_mu_r, W2_um_l, W2_um_r, bc1, b2_mu_l, b2_um_l, WPQ, bPQ,
        e_um, e_um + NEC, e_mu, e_mu + NEC, gcnt, bktA, bktB);

    // 3) CSR place (inline bucket-base scan; writes off arrays + srcs)
    k_bplace<<<2 * NB, 256, 0, stream>>>(gcnt, bktA, bktB,
                                         off_um, srcs_um, off_mu, srcs_mu);

    // 4) layer-1 aggregates: gather x halves, write mean1 halves (bf16)
    const int agrid = 50000 / 4;
    k_agg<64><<<2 * agrid, 256, 0, stream>>>(
        A1u, off_um, srcs_um, A1m,
        A1m, off_mu, srcs_mu, A1u, N_MERCHC);

    // 5) layer-1 MFMA GEMM pair: h = relu(A1 @ B1^T + b1) -> A2 cols 128..255
    const int ggrid = (50000 + 63) / 64;
    k_mfma_gemm2<128, true><<<2 * ggrid, 256, 0, stream>>>(
        A1m, B1m, b1_um_l, A2m, 256, 128, N_MERCHC,
        A1u, B1u, b1_mu_l, A2u, 256, 128, N_USERC, ggrid);

    // 6) layer-2 aggregates: gather h halves, write mean2 halves (bf16)
    k_agg<128><<<2 * agrid, 256, 0, stream>>>(
        A2u, off_um, srcs_um, A2m,
        A2m, off_mu, srcs_mu, A2u, N_MERCHC);

    // 7) fused classifier MFMA GEMM pair: P = A2u @ WP^T + bP ; Q = A2m @ WQ^T + bQ
    k_mfma_gemm2<256, false><<<2 * ggrid, 256, 0, stream>>>(
        A2u, WPQ,         bPQ,       Pbf, 128, 0, N_USERC,
        A2m, WPQ + 32768, bPQ + 128, Qbf, 128, 0, N_MERCHC, ggrid);

    // 8) per-edge: out = bc2 + relu(P[r]+Q[c]) . wc2  (bf16 gathers)
    const int cgrid = (NTC + 15) / 16;   // 4 edges/wave, 4 waves/block
    k_edge_bf<<<cgrid, 256, 0, stream>>>(Pbf, Qbf, tgt, tgt + NTC, Wc2, bc2, out, NTC);
}

// Round 9
// 404.299 us; speedup vs baseline: 3.5544x; 1.0650x over previous
//
#include <hip/hip_runtime.h>
#include <hip/hip_bf16.h>
#include <stdint.h>

#define N_USERC  50000
#define N_MERCHC 50000
#define NEC      1000000   // edges per direction
#define NTC      500000    // target edges

#define NB    196          // dst buckets (256 dsts each: bucket = dst >> 8)
#define BCAP  8192         // pairs per bucket (mean 5120, sigma ~72, +43 sigma cap)
#define ECHUNK 8192        // edges per bucket-pass block (32/thread)
#define BPT   123          // bucket-pass blocks per edge type = ceil(NEC/ECHUNK)

// k_prep fused-grid offsets
#define PREP_CASTX  3125   // 800000/256
#define PREP_CASTW  (PREP_CASTX + 16)
#define PREP_WC     (PREP_CASTW + 257)
#define PREP_BKT    (PREP_WC + 2 * BPT)     // total grid

typedef unsigned short ushortT;
typedef __attribute__((ext_vector_type(8))) short short8;     // 8 bf16 (MFMA frag)
typedef __attribute__((ext_vector_type(8))) unsigned short ushort8;
typedef __attribute__((ext_vector_type(4))) float f32x4;

__device__ __forceinline__ unsigned short f2bf(float f)
{
    const unsigned u = __float_as_uint(f);
    const unsigned r = u + 0x7fffu + ((u >> 16) & 1u);   // RNE
    return (unsigned short)(r >> 16);
}
__device__ __forceinline__ float bfhi(unsigned u) { return __uint_as_float(u & 0xffff0000u); }
__device__ __forceinline__ float bflo(unsigned u) { return __uint_as_float(u << 16); }

__device__ __forceinline__ void acc8(float* a, const uint4 v)
{
    a[0] += bflo(v.x); a[1] += bfhi(v.x);
    a[2] += bflo(v.y); a[3] += bfhi(v.y);
    a[4] += bflo(v.z); a[5] += bfhi(v.z);
    a[6] += bflo(v.w); a[7] += bfhi(v.w);
}

// ---------------------------------------------------------------------------
// Fused prep kernel: blockIdx ranges dispatch 4 independent jobs.
//  [0, 3125)      cast x tables -> interleaved A1 ([mean1 | x], bf16)
//  [3125, 3141)   cast layer-1 weights -> B1 ([Wl | Wr] along K, bf16 row-major)
//  [3141, 3398)   fused classifier weights WPQ/bPQ (z never materialized)
//  [3398, 3644)   CSR bucket pass (packed (ldst<<16|src) appends)
// ---------------------------------------------------------------------------
__global__ __launch_bounds__(256) void k_prep(
    const float* __restrict__ xu, const float* __restrict__ xm,
    ushortT* __restrict__ A1u, ushortT* __restrict__ A1m,
    const float* __restrict__ W1um_l, const float* __restrict__ W1um_r,
    const float* __restrict__ W1mu_l, const float* __restrict__ W1mu_r,
    ushortT* __restrict__ B1m, ushortT* __restrict__ B1u,
    const float* __restrict__ Wc1,
    const float* __restrict__ W2mu_l, const float* __restrict__ W2mu_r,
    const float* __restrict__ W2um_l, const float* __restrict__ W2um_r,
    const float* __restrict__ bc1,
    const float* __restrict__ b2mu_l, const float* __restrict__ b2um_l,
    ushortT* __restrict__ WPQ, float* __restrict__ bPQ,
    const int* __restrict__ rowA, const int* __restrict__ colA,
    const int* __restrict__ rowB, const int* __restrict__ colB,
    uint32_t* __restrict__ gcnt, uint32_t* __restrict__ bktA, uint32_t* __restrict__ bktB)
{
    __shared__ uint32_t hist[NB], base[NB], cur[NB];
    const int bid = blockIdx.x;
    const int tx = threadIdx.x;

    if (bid < PREP_CASTX) {
        // ---- cast_x: A1[row] = [ (mean later) | bf16(x[row]) ]
        const int idx = bid * 256 + tx;
        if (idx >= 800000) return;
        const int which = idx / 400000;
        const int rem = idx - which * 400000;
        const int row = rem >> 3;
        const int c8 = rem & 7;
        const float* x = which ? xm : xu;
        ushortT* A = which ? A1m : A1u;
        const float4 v0 = *(const float4*)(x + (size_t)row * 64 + c8 * 8);
        const float4 v1 = *(const float4*)(x + (size_t)row * 64 + c8 * 8 + 4);
        ushort8 o;
        o[0] = f2bf(v0.x); o[1] = f2bf(v0.y); o[2] = f2bf(v0.z); o[3] = f2bf(v0.w);
        o[4] = f2bf(v1.x); o[5] = f2bf(v1.y); o[6] = f2bf(v1.z); o[7] = f2bf(v1.w);
        *(ushort8*)(A + (size_t)row * 128 + 64 + c8 * 8) = o;
    } else if (bid < PREP_CASTW) {
        // ---- cast_w1: B1[n][k] = k<64 ? Wl[n][k] : Wr[n][k-64]
        const int idx = (bid - PREP_CASTX) * 256 + tx;
        if (idx >= 4096) return;
        const int which = idx >> 11;
        const int rem = idx & 2047;
        const int n = rem >> 4;
        const int k0 = (rem & 15) * 8;
        const float* Wl = which ? W1mu_l : W1um_l;
        const float* Wr = which ? W1mu_r : W1um_r;
        const float* src = (k0 < 64) ? Wl + (size_t)n * 64 + k0
                                     : Wr + (size_t)n * 64 + (k0 - 64);
        const float4 v0 = *(const float4*)src;
        const float4 v1 = *(const float4*)(src + 4);
        ushort8 o;
        o[0] = f2bf(v0.x); o[1] = f2bf(v0.y); o[2] = f2bf(v0.z); o[3] = f2bf(v0.w);
        o[4] = f2bf(v1.x); o[5] = f2bf(v1.y); o[6] = f2bf(v1.z); o[7] = f2bf(v1.w);
        ushortT* O = which ? B1u : B1m;
        *(ushort8*)(O + (size_t)n * 128 + k0) = o;
    } else if (bid < PREP_WC) {
        // ---- wcombine: WP[j][k] = Wc1a[j,:] @ W2_mu_{l|r}[:,k] etc., bf16
        const int idx = (bid - PREP_CASTW) * 256 + tx;
        if (idx < 65536) {
            const int q = idx >> 15;
            const int j = (idx >> 8) & 127;
            const int k = idx & 255;
            const int kk = k & 127;
            const float* W2 = q ? (k < 128 ? W2um_l : W2um_r)
                                : (k < 128 ? W2mu_l : W2mu_r);
            const float* wrow = Wc1 + (size_t)j * 256 + q * 128;
            float s = 0.f;
            for (int i = 0; i < 128; ++i)
                s = fmaf(wrow[i], W2[(size_t)i * 128 + kk], s);
            WPQ[idx] = f2bf(s);
        } else if (idx < 65536 + 256) {
            const int r = idx - 65536;
            const int q = r >> 7, j = r & 127;
            const float* wrow = Wc1 + (size_t)j * 256 + q * 128;
            const float* b2 = q ? b2um_l : b2mu_l;
            float s = (q == 0) ? bc1[j] : 0.f;
            for (int i = 0; i < 128; ++i) s = fmaf(wrow[i], b2[i], s);
            bPQ[r] = s;
        }
    } else {
        // ---- CSR bucket pass
        const int cb2 = bid - PREP_WC;
        const int type = (cb2 >= BPT) ? 1 : 0;
        const int cb = cb2 - type * BPT;
        const int* col = type ? colB : colA;
        const int* row = type ? rowB : rowA;
        uint32_t* bkt = type ? bktB : bktA;
        uint32_t* gc = gcnt + type * NB;

        const int e0 = cb * ECHUNK;
        const int e1 = (e0 + ECHUNK < NEC) ? e0 + ECHUNK : NEC;

        for (int i = tx; i < NB; i += 256) { hist[i] = 0; cur[i] = 0; }
        __syncthreads();

        int cols[32];
#pragma unroll
        for (int q = 0; q < 32; ++q) {
            const int i = e0 + tx + q * 256;
            int c = -1;
            if (i < e1) { c = col[i]; atomicAdd(&hist[c >> 8], 1u); }
            cols[q] = c;
        }
        __syncthreads();
        for (int i = tx; i < NB; i += 256)
            base[i] = atomicAdd(&gc[i], hist[i]);
        __syncthreads();
#pragma unroll
        for (int q = 0; q < 32; ++q) {
            const int i = e0 + tx + q * 256;
            if (i < e1) {
                const int c = cols[q];
                const int b = c >> 8;
                const uint32_t p = base[b] + atomicAdd(&cur[b], 1u);
                if (p < BCAP)
                    bkt[(size_t)b * BCAP + p] = ((uint32_t)(c & 255) << 16) | (uint32_t)row[i];
            }
        }
    }
}

// ---------------------------------------------------------------------------
// CSR place pass with inline bucket-base scan: each block scans its type's
// 196 bucket counts in LDS, then counts per local dst, scans, writes the off
// array, and places srcs into the bucket's contiguous CSR window.
// ---------------------------------------------------------------------------
__global__ __launch_bounds__(256) void k_bplace(
    const uint32_t* __restrict__ gcnt,
    const uint32_t* __restrict__ bktA, const uint32_t* __restrict__ bktB,
    int* __restrict__ off_um, int* __restrict__ srcs_um,
    int* __restrict__ off_mu, int* __restrict__ srcs_mu)
{
    __shared__ uint32_t sb[256], cnt[256], loff[256], cur[256];
    const int type = (blockIdx.x >= NB) ? 1 : 0;
    const int b = blockIdx.x - type * NB;
    const uint32_t* bkt = (type ? bktB : bktA) + (size_t)b * BCAP;
    int* offp = type ? off_mu : off_um;
    int* srcs = type ? srcs_mu : srcs_um;
    const int t = threadIdx.x;

    // inline exclusive scan of this type's bucket counts
    const uint32_t gv = (t < NB) ? gcnt[type * NB + t] : 0;
    sb[t] = gv;
    for (int d = 1; d < 256; d <<= 1) {
        __syncthreads();
        const uint32_t a = (t >= d) ? sb[t - d] : 0;
        __syncthreads();
        sb[t] += a;
    }
    __syncthreads();
    const int n = (int)gcnt[type * NB + b];
    const uint32_t gbase = sb[b] - (uint32_t)n;   // exclusive prefix at b
    if (blockIdx.x == 0 && t == 0)  off_um[N_MERCHC] = NEC;
    if (blockIdx.x == NB && t == 0) off_mu[N_USERC] = NEC;
    __syncthreads();

    cnt[t] = 0; cur[t] = 0;
    __syncthreads();
    for (int i = t; i < n; i += 256)
        atomicAdd(&cnt[bkt[i] >> 16], 1u);
    __syncthreads();
    loff[t] = cnt[t];
    for (int d = 1; d < 256; d <<= 1) {
        __syncthreads();
        const uint32_t a = (t >= d) ? loff[t - d] : 0;
        __syncthreads();
        loff[t] += a;
    }
    __syncthreads();
    const uint32_t excl = loff[t] - cnt[t];
    const int dst0 = b << 8;
    if (dst0 + t < N_USERC) offp[dst0 + t] = (int)(gbase + excl);
    __syncthreads();
    loff[t] = excl;
    __syncthreads();
    for (int i = t; i < n; i += 256) {
        const uint32_t v = bkt[i];
        const uint32_t ld = v >> 16;
        const uint32_t p = gbase + loff[ld] + atomicAdd(&cur[ld], 1u);
        srcs[p] = (int)(v & 0xFFFFu);
    }
}

// ---------------------------------------------------------------------------
// Mean aggregation over interleaved bf16 tables, both directions per launch.
// 2x unrolled with dual accumulators: two independent 16B gathers in flight
// per iteration (direct srcs loads — uniform within each 16-lane group).
// ---------------------------------------------------------------------------
template <int D>
__global__ __launch_bounds__(256) void k_agg(
    const ushortT* __restrict__ gA, const int* __restrict__ offsA,
    const int* __restrict__ srcsA, ushortT* __restrict__ oA,
    const ushortT* __restrict__ gB, const int* __restrict__ offsB,
    const int* __restrict__ srcsB, ushortT* __restrict__ oB, int ndst)
{
    constexpr int LPE = D / 8;      // lanes per edge row
    constexpr int EPW = 64 / LPE;   // edges per wave-iter
    constexpr int STR = 2 * D;      // interleaved row stride (elems)
    const int half = gridDim.x >> 1;
    const int type = (blockIdx.x >= half) ? 1 : 0;
    const int cb = blockIdx.x - type * half;
    const ushortT* g = type ? gB : gA;
    const int* offs  = type ? offsB : offsA;
    const int* srcs  = type ? srcsB : srcsA;
    ushortT* om      = type ? oB : oA;

    const int wid = cb * 4 + (threadIdx.x >> 6);
    if (wid >= ndst) return;
    const int lane = threadIdx.x & 63;
    const int sub  = lane / LPE;
    const int c4   = lane % LPE;

    const int b = offs[wid], e = offs[wid + 1];
    float a0[8], a1[8];
#pragma unroll
    for (int j = 0; j < 8; ++j) { a0[j] = 0.f; a1[j] = 0.f; }

    int i = b + sub;
    for (; i + EPW < e; i += 2 * EPW) {
        const int s0 = srcs[i];
        const int s1 = srcs[i + EPW];
        const uint4 v0 = *(const uint4*)(g + (size_t)s0 * STR + D + c4 * 8);
        const uint4 v1 = *(const uint4*)(g + (size_t)s1 * STR + D + c4 * 8);
        acc8(a0, v0);
        acc8(a1, v1);
    }
    if (i < e) {
        const int s0 = srcs[i];
        const uint4 v0 = *(const uint4*)(g + (size_t)s0 * STR + D + c4 * 8);
        acc8(a0, v0);
    }
#pragma unroll
    for (int j = 0; j < 8; ++j) a0[j] += a1[j];
#pragma unroll
    for (int m = LPE; m < 64; m <<= 1) {
#pragma unroll
        for (int j = 0; j < 8; ++j) a0[j] += __shfl_xor(a0[j], m);
    }
    if (sub == 0) {
        const int deg = e - b;
        const float inv = 1.0f / (float)(deg > 1 ? deg : 1);
        ushort8 o;
#pragma unroll
        for (int j = 0; j < 8; ++j) o[j] = f2bf(a0[j] * inv);
        *(ushort8*)(om + (size_t)wid * STR + c4 * 8) = o;
    }
}

// ---------------------------------------------------------------------------
// MFMA bf16 GEMM pair (two independent problems in one launch):
//   Out[m][0:128] = act(A[m][0:K] @ W^T + bias), bf16 out at Obf + m*OS + OO.
// A row-major = A-fragment native; W [128][K] row-major = B-fragment native.
// C/D: col=lane&15, row=quad*4+reg. Wave tile 16x128, block 4 waves.
// ---------------------------------------------------------------------------
template <int K, bool RELU>
__device__ __forceinline__ void mfma_gemm_body(
    int cb, float (*lds)[16][132],
    const ushortT* __restrict__ A, const ushortT* __restrict__ Bw,
    const float* __restrict__ bias,
    ushortT* __restrict__ Obf, int OS, int OO, int M)
{
    const int tx = threadIdx.x;
    const int wid = tx >> 6;
    const int lane = tx & 63;
    const int ln = lane & 15;
    const int quad = lane >> 4;
    const int m0 = cb * 64 + wid * 16;
    int arow = m0 + ln; if (arow >= M) arow = M - 1;
    const ushortT* ap = A + (size_t)arow * K + quad * 8;

    f32x4 acc[8];
#pragma unroll
    for (int i = 0; i < 8; ++i) acc[i] = (f32x4){0.f, 0.f, 0.f, 0.f};

#pragma unroll
    for (int kc = 0; kc < K / 32; ++kc) {
        const short8 a = *(const short8*)(ap + kc * 32);
#pragma unroll
        for (int nt = 0; nt < 8; ++nt) {
            const short8 b = *(const short8*)(Bw + (size_t)(nt * 16 + ln) * K + kc * 32 + quad * 8);
            acc[nt] = __builtin_amdgcn_mfma_f32_16x16x32_bf16(a, b, acc[nt], 0, 0, 0);
        }
    }

    float (*t)[132] = lds[wid];
#pragma unroll
    for (int nt = 0; nt < 8; ++nt) {
        const float bv = bias[nt * 16 + ln];
#pragma unroll
        for (int r = 0; r < 4; ++r) {
            float v = acc[nt][r] + bv;
            if (RELU) v = fmaxf(v, 0.f);
            t[quad * 4 + r][nt * 16 + ln] = v;
        }
    }
#pragma unroll
    for (int p = 0; p < 4; ++p) {
        const int row = p * 4 + quad;
        const int gr = m0 + row;
        if (gr < M) {
            const float4 v0 = *(const float4*)&t[row][ln * 8];
            const float4 v1 = *(const float4*)&t[row][ln * 8 + 4];
            ushort8 o;
            o[0] = f2bf(v0.x); o[1] = f2bf(v0.y); o[2] = f2bf(v0.z); o[3] = f2bf(v0.w);
            o[4] = f2bf(v1.x); o[5] = f2bf(v1.y); o[6] = f2bf(v1.z); o[7] = f2bf(v1.w);
            *(ushort8*)(Obf + (size_t)gr * OS + OO + ln * 8) = o;
        }
    }
}

template <int K, bool RELU>
__global__ __launch_bounds__(256) void k_mfma_gemm2(
    const ushortT* __restrict__ Aa, const ushortT* __restrict__ Bwa,
    const float* __restrict__ biasa, ushortT* __restrict__ Oa, int OSa, int OOa, int Ma,
    const ushortT* __restrict__ Ab, const ushortT* __restrict__ Bwb,
    const float* __restrict__ biasb, ushortT* __restrict__ Ob, int OSb, int OOb, int Mb,
    int gridA)
{
    __shared__ float lds[4][16][132];
    if ((int)blockIdx.x < gridA)
        mfma_gemm_body<K, RELU>(blockIdx.x, lds, Aa, Bwa, biasa, Oa, OSa, OOa, Ma);
    else
        mfma_gemm_body<K, RELU>(blockIdx.x - gridA, lds, Ab, Bwb, biasb, Ob, OSb, OOb, Mb);
}

// ---------------------------------------------------------------------------
// Edge classifier on bf16 P/Q: out[e] = bc2 + sum_j relu(P[r][j]+Q[c][j])*wc2[j]
// ---------------------------------------------------------------------------
__global__ __launch_bounds__(256) void k_edge_bf(
    const ushortT* __restrict__ P, const ushortT* __restrict__ Q,
    const int* __restrict__ er, const int* __restrict__ ec,
    const float* __restrict__ wc2, const float* __restrict__ bc2,
    float* __restrict__ out, int nt)
{
    const int lane = threadIdx.x & 63;
    const int sub = lane >> 4;       // edge within wave (4)
    const int c8 = lane & 15;        // 8-elem group within row
    const int wid = (int)((blockIdx.x * blockDim.x + threadIdx.x) >> 6);
    const int e0 = wid * 4 + sub;
    if (e0 >= nt) return;

    const float4 w0 = ((const float4*)wc2)[c8 * 2];
    const float4 w1 = ((const float4*)wc2)[c8 * 2 + 1];
    const int r = er[e0], c = ec[e0];
    const uint4 pv = *(const uint4*)(P + (size_t)r * 128 + c8 * 8);
    const uint4 qv = *(const uint4*)(Q + (size_t)c * 128 + c8 * 8);
    float s = fmaxf(bflo(pv.x) + bflo(qv.x), 0.f) * w0.x
            + fmaxf(bfhi(pv.x) + bfhi(qv.x), 0.f) * w0.y
            + fmaxf(bflo(pv.y) + bflo(qv.y), 0.f) * w0.z
            + fmaxf(bfhi(pv.y) + bfhi(qv.y), 0.f) * w0.w
            + fmaxf(bflo(pv.z) + bflo(qv.z), 0.f) * w1.x
            + fmaxf(bfhi(pv.z) + bfhi(qv.z), 0.f) * w1.y
            + fmaxf(bflo(pv.w) + bflo(qv.w), 0.f) * w1.z
            + fmaxf(bfhi(pv.w) + bfhi(qv.w), 0.f) * w1.w;
    s += __shfl_xor(s, 1);
    s += __shfl_xor(s, 2);
    s += __shfl_xor(s, 4);
    s += __shfl_xor(s, 8);
    if (c8 == 0) out[e0] = s + bc2[0];
}

// ---------------------------------------------------------------------------
// Host launcher
// ---------------------------------------------------------------------------
extern "C" void kernel_launch(void* const* d_in, const int* in_sizes, int n_in,
                              void* d_out, int out_size, void* d_ws, size_t ws_size,
                              hipStream_t stream)
{
    const float* x_user  = (const float*)d_in[0];
    const float* x_merch = (const float*)d_in[1];
    const int*   e_um    = (const int*)d_in[2];
    const int*   e_mu    = (const int*)d_in[3];
    const int*   tgt     = (const int*)d_in[4];
    const float* W1_um_l = (const float*)d_in[5];
    const float* b1_um_l = (const float*)d_in[6];
    const float* W1_um_r = (const float*)d_in[7];
    const float* W1_mu_l = (const float*)d_in[8];
    const float* b1_mu_l = (const float*)d_in[9];
    const float* W1_mu_r = (const float*)d_in[10];
    const float* W2_um_l = (const float*)d_in[11];
    const float* b2_um_l = (const float*)d_in[12];
    const float* W2_um_r = (const float*)d_in[13];
    const float* W2_mu_l = (const float*)d_in[14];
    const float* b2_mu_l = (const float*)d_in[15];
    const float* W2_mu_r = (const float*)d_in[16];
    const float* Wc1     = (const float*)d_in[17];
    const float* bc1     = (const float*)d_in[18];
    const float* Wc2     = (const float*)d_in[19];
    const float* bc2     = (const float*)d_in[20];
    float* out = (float*)d_out;

    // ---- workspace carve-up (u32 words, 64-word aligned)
    uint32_t* B = (uint32_t*)d_ws;
    size_t pos = 0;
    auto take = [&](size_t n) { size_t p = pos; pos += (n + 63) & ~(size_t)63; return p; };

    uint32_t* gcnt = (uint32_t*)(B + take(2 * NB));     // zeroed each launch
    const size_t cnt_words = pos;
    int* off_um  = (int*)(B + take(N_MERCHC + 1));
    int* srcs_um = (int*)(B + take(NEC));
    int* off_mu  = (int*)(B + take(N_USERC + 1));
    int* srcs_mu = (int*)(B + take(NEC));
    ushortT* A1u = (ushortT*)(B + take((size_t)N_USERC  * 128 / 2));  // [mean1_u | x_u]
    ushortT* A1m = (ushortT*)(B + take((size_t)N_MERCHC * 128 / 2));  // [mean1_m | x_m]
    ushortT* A2u = (ushortT*)(B + take((size_t)N_USERC  * 256 / 2));  // [mean2_u | h_u]
    ushortT* A2m = (ushortT*)(B + take((size_t)N_MERCHC * 256 / 2));  // [mean2_m | h_m]
    ushortT* B1m = (ushortT*)(B + take(8192));          // [W1_um_l | W1_um_r] bf16
    ushortT* B1u = (ushortT*)(B + take(8192));          // [W1_mu_l | W1_mu_r]
    ushortT* WPQ = (ushortT*)(B + take(32768));         // fused [2][128][256] bf16
    float*   bPQ = (float*)(B + take(256));             // fused biases [2][128] fp32

    // ---- aliases (lifetimes):
    // buckets: CSR build only; A2m's halves are written later (GEMM1 / agg2)
    uint32_t* bktA = (uint32_t*)A2m;
    uint32_t* bktB = bktA + (size_t)NB * BCAP;          // 3.2M words <= 6.4M
    // P/Q: written by classifier GEMMs (A1 dead after GEMM1), read by k_edge
    ushortT* Pbf = A1u;
    ushortT* Qbf = A1m;
    (void)ws_size; (void)in_sizes; (void)n_in; (void)out_size;

    // 1) zero bucket counters
    hipMemsetAsync(d_ws, 0, cnt_words * sizeof(uint32_t), stream);

    // 2) fused prep: x casts + weight casts + classifier weight fusion + CSR bucket
    k_prep<<<PREP_BKT, 256, 0, stream>>>(
        x_user, x_merch, A1u, A1m,
        W1_um_l, W1_um_r, W1_mu_l, W1_mu_r, B1m, B1u,
        Wc1, W2_mu_l, W2_mu_r, W2_um_l, W2_um_r, bc1, b2_mu_l, b2_um_l, WPQ, bPQ,
        e_um, e_um + NEC, e_mu, e_mu + NEC, gcnt, bktA, bktB);

    // 3) CSR place (inline bucket-base scan; writes off arrays + srcs)
    k_bplace<<<2 * NB, 256, 0, stream>>>(gcnt, bktA, bktB,
                                         off_um, srcs_um, off_mu, srcs_mu);

    // 4) layer-1 aggregates: gather x halves, write mean1 halves (bf16)
    const int agrid = 50000 / 4;
    k_agg<64><<<2 * agrid, 256, 0, stream>>>(
        A1u, off_um, srcs_um, A1m,
        A1m, off_mu, srcs_mu, A1u, N_MERCHC);

    // 5) layer-1 MFMA GEMM pair: h = relu(A1 @ B1^T + b1) -> A2 cols 128..255
    const int ggrid = (50000 + 63) / 64;
    k_mfma_gemm2<128, true><<<2 * ggrid, 256, 0, stream>>>(
        A1m, B1m, b1_um_l, A2m, 256, 128, N_MERCHC,
        A1u, B1u, b1_mu_l, A2u, 256, 128, N_USERC, ggrid);

    // 6) layer-2 aggregates: gather h halves, write mean2 halves (bf16)
    k_agg<128><<<2 * agrid, 256, 0, stream>>>(
        A2u, off_um, srcs_um, A2m,
        A2m, off_mu, srcs_mu, A2u, N_MERCHC);

    // 7) fused classifier MFMA GEMM pair: P = A2u @ WP^T + bP ; Q = A2m @ WQ^T + bQ
    k_mfma_gemm2<256, false><<<2 * ggrid, 256, 0, stream>>>(
        A2u, WPQ,         bPQ,       Pbf, 128, 0, N_USERC,
        A2m, WPQ + 32768, bPQ + 128, Qbf, 128, 0, N_MERCHC, ggrid);

    // 8) per-edge: out = bc2 + relu(P[r]+Q[c]) . wc2  (bf16 gathers)
    const int cgrid = (NTC + 15) / 16;   // 4 edges/wave, 4 waves/block
    k_edge_bf<<<cgrid, 256, 0, stream>>>(Pbf, Qbf, tgt, tgt + NTC, Wc2, bc2, out, NTC);
}

// Round 10
// 370.380 us; speedup vs baseline: 3.8799x; 1.0916x over previous
//
#include <hip/hip_runtime.h>
#include <hip/hip_bf16.h>
#include <stdint.h>

#define N_USERC  50000
#define N_MERCHC 50000
#define NEC      1000000   // edges per direction
#define NTC      500000    // target edges

#define NB    196          // dst buckets (256 dsts each: bucket = dst >> 8)
#define BCAP  8192         // pairs per bucket (mean 5120, sigma ~72, +43 sigma cap)
#define ECHUNK 8192        // edges per bucket-pass block (32/thread)
#define BPT   123          // bucket-pass blocks per edge type = ceil(NEC/ECHUNK)

// k_prep fused-grid offsets
#define PREP_CASTX  3125   // 800000/256
#define PREP_CASTW  (PREP_CASTX + 16)
#define PREP_WC     (PREP_CASTW + 257)
#define PREP_BKT    (PREP_WC + 2 * BPT)     // total grid

typedef unsigned short ushortT;
typedef __attribute__((ext_vector_type(8))) short short8;     // 8 bf16 (MFMA frag)
typedef __attribute__((ext_vector_type(8))) unsigned short ushort8;
typedef __attribute__((ext_vector_type(4))) float f32x4;

__device__ __forceinline__ unsigned short f2bf(float f)
{
    const unsigned u = __float_as_uint(f);
    const unsigned r = u + 0x7fffu + ((u >> 16) & 1u);   // RNE
    return (unsigned short)(r >> 16);
}
__device__ __forceinline__ float bfhi(unsigned u) { return __uint_as_float(u & 0xffff0000u); }
__device__ __forceinline__ float bflo(unsigned u) { return __uint_as_float(u << 16); }

__device__ __forceinline__ void acc8(float* a, const uint4 v)
{
    a[0] += bflo(v.x); a[1] += bfhi(v.x);
    a[2] += bflo(v.y); a[3] += bfhi(v.y);
    a[4] += bflo(v.z); a[5] += bfhi(v.z);
    a[6] += bflo(v.w); a[7] += bfhi(v.w);
}

// ---------------------------------------------------------------------------
// Fused prep kernel: blockIdx ranges dispatch 4 independent jobs.
//  [0, 3125)      cast x tables -> interleaved A1 ([mean1 | x], bf16)
//  [3125, 3141)   cast layer-1 weights -> B1 ([Wl | Wr] along K, bf16 row-major)
//  [3141, 3398)   fused classifier weights WPQ/bPQ (z never materialized)
//  [3398, 3644)   CSR bucket pass (packed (ldst<<16|src) appends)
// ---------------------------------------------------------------------------
__global__ __launch_bounds__(256) void k_prep(
    const float* __restrict__ xu, const float* __restrict__ xm,
    ushortT* __restrict__ A1u, ushortT* __restrict__ A1m,
    const float* __restrict__ W1um_l, const float* __restrict__ W1um_r,
    const float* __restrict__ W1mu_l, const float* __restrict__ W1mu_r,
    ushortT* __restrict__ B1m, ushortT* __restrict__ B1u,
    const float* __restrict__ Wc1,
    const float* __restrict__ W2mu_l, const float* __restrict__ W2mu_r,
    const float* __restrict__ W2um_l, const float* __restrict__ W2um_r,
    const float* __restrict__ bc1,
    const float* __restrict__ b2mu_l, const float* __restrict__ b2um_l,
    ushortT* __restrict__ WPQ, float* __restrict__ bPQ,
    const int* __restrict__ rowA, const int* __restrict__ colA,
    const int* __restrict__ rowB, const int* __restrict__ colB,
    uint32_t* __restrict__ gcnt, uint32_t* __restrict__ bktA, uint32_t* __restrict__ bktB)
{
    __shared__ uint32_t hist[NB], base[NB], cur[NB];
    const int bid = blockIdx.x;
    const int tx = threadIdx.x;

    if (bid < PREP_CASTX) {
        // ---- cast_x: A1[row] = [ (mean later) | bf16(x[row]) ]
        const int idx = bid * 256 + tx;
        if (idx >= 800000) return;
        const int which = idx / 400000;
        const int rem = idx - which * 400000;
        const int row = rem >> 3;
        const int c8 = rem & 7;
        const float* x = which ? xm : xu;
        ushortT* A = which ? A1m : A1u;
        const float4 v0 = *(const float4*)(x + (size_t)row * 64 + c8 * 8);
        const float4 v1 = *(const float4*)(x + (size_t)row * 64 + c8 * 8 + 4);
        ushort8 o;
        o[0] = f2bf(v0.x); o[1] = f2bf(v0.y); o[2] = f2bf(v0.z); o[3] = f2bf(v0.w);
        o[4] = f2bf(v1.x); o[5] = f2bf(v1.y); o[6] = f2bf(v1.z); o[7] = f2bf(v1.w);
        *(ushort8*)(A + (size_t)row * 128 + 64 + c8 * 8) = o;
    } else if (bid < PREP_CASTW) {
        // ---- cast_w1: B1[n][k] = k<64 ? Wl[n][k] : Wr[n][k-64]
        const int idx = (bid - PREP_CASTX) * 256 + tx;
        if (idx >= 4096) return;
        const int which = idx >> 11;
        const int rem = idx & 2047;
        const int n = rem >> 4;
        const int k0 = (rem & 15) * 8;
        const float* Wl = which ? W1mu_l : W1um_l;
        const float* Wr = which ? W1mu_r : W1um_r;
        const float* src = (k0 < 64) ? Wl + (size_t)n * 64 + k0
                                     : Wr + (size_t)n * 64 + (k0 - 64);
        const float4 v0 = *(const float4*)src;
        const float4 v1 = *(const float4*)(src + 4);
        ushort8 o;
        o[0] = f2bf(v0.x); o[1] = f2bf(v0.y); o[2] = f2bf(v0.z); o[3] = f2bf(v0.w);
        o[4] = f2bf(v1.x); o[5] = f2bf(v1.y); o[6] = f2bf(v1.z); o[7] = f2bf(v1.w);
        ushortT* O = which ? B1u : B1m;
        *(ushort8*)(O + (size_t)n * 128 + k0) = o;
    } else if (bid < PREP_WC) {
        // ---- wcombine: WP[j][k] = Wc1a[j,:] @ W2_mu_{l|r}[:,k] etc., bf16
        const int idx = (bid - PREP_CASTW) * 256 + tx;
        if (idx < 65536) {
            const int q = idx >> 15;
            const int j = (idx >> 8) & 127;
            const int k = idx & 255;
            const int kk = k & 127;
            const float* W2 = q ? (k < 128 ? W2um_l : W2um_r)
                                : (k < 128 ? W2mu_l : W2mu_r);
            const float* wrow = Wc1 + (size_t)j * 256 + q * 128;
            float s = 0.f;
            for (int i = 0; i < 128; ++i)
                s = fmaf(wrow[i], W2[(size_t)i * 128 + kk], s);
            WPQ[idx] = f2bf(s);
        } else if (idx < 65536 + 256) {
            const int r = idx - 65536;
            const int q = r >> 7, j = r & 127;
            const float* wrow = Wc1 + (size_t)j * 256 + q * 128;
            const float* b2 = q ? b2um_l : b2mu_l;
            float s = (q == 0) ? bc1[j] : 0.f;
            for (int i = 0; i < 128; ++i) s = fmaf(wrow[i], b2[i], s);
            bPQ[r] = s;
        }
    } else {
        // ---- CSR bucket pass
        const int cb2 = bid - PREP_WC;
        const int type = (cb2 >= BPT) ? 1 : 0;
        const int cb = cb2 - type * BPT;
        const int* col = type ? colB : colA;
        const int* row = type ? rowB : rowA;
        uint32_t* bkt = type ? bktB : bktA;
        uint32_t* gc = gcnt + type * NB;

        const int e0 = cb * ECHUNK;
        const int e1 = (e0 + ECHUNK < NEC) ? e0 + ECHUNK : NEC;

        for (int i = tx; i < NB; i += 256) { hist[i] = 0; cur[i] = 0; }
        __syncthreads();

        int cols[32];
#pragma unroll
        for (int q = 0; q < 32; ++q) {
            const int i = e0 + tx + q * 256;
            int c = -1;
            if (i < e1) { c = col[i]; atomicAdd(&hist[c >> 8], 1u); }
            cols[q] = c;
        }
        __syncthreads();
        for (int i = tx; i < NB; i += 256)
            base[i] = atomicAdd(&gc[i], hist[i]);
        __syncthreads();
#pragma unroll
        for (int q = 0; q < 32; ++q) {
            const int i = e0 + tx + q * 256;
            if (i < e1) {
                const int c = cols[q];
                const int b = c >> 8;
                const uint32_t p = base[b] + atomicAdd(&cur[b], 1u);
                if (p < BCAP)
                    bkt[(size_t)b * BCAP + p] = ((uint32_t)(c & 255) << 16) | (uint32_t)row[i];
            }
        }
    }
}

// ---------------------------------------------------------------------------
// CSR place pass with inline bucket-base scan: each block scans its type's
// 196 bucket counts in LDS, then counts per local dst, scans, writes the off
// array, and places srcs into the bucket's contiguous CSR window.
// ---------------------------------------------------------------------------
__global__ __launch_bounds__(256) void k_bplace(
    const uint32_t* __restrict__ gcnt,
    const uint32_t* __restrict__ bktA, const uint32_t* __restrict__ bktB,
    int* __restrict__ off_um, int* __restrict__ srcs_um,
    int* __restrict__ off_mu, int* __restrict__ srcs_mu)
{
    __shared__ uint32_t sb[256], cnt[256], loff[256], cur[256];
    const int type = (blockIdx.x >= NB) ? 1 : 0;
    const int b = blockIdx.x - type * NB;
    const uint32_t* bkt = (type ? bktB : bktA) + (size_t)b * BCAP;
    int* offp = type ? off_mu : off_um;
    int* srcs = type ? srcs_mu : srcs_um;
    const int t = threadIdx.x;

    // inline exclusive scan of this type's bucket counts
    const uint32_t gv = (t < NB) ? gcnt[type * NB + t] : 0;
    sb[t] = gv;
    for (int d = 1; d < 256; d <<= 1) {
        __syncthreads();
        const uint32_t a = (t >= d) ? sb[t - d] : 0;
        __syncthreads();
        sb[t] += a;
    }
    __syncthreads();
    const int n = (int)gcnt[type * NB + b];
    const uint32_t gbase = sb[b] - (uint32_t)n;   // exclusive prefix at b
    if (blockIdx.x == 0 && t == 0)  off_um[N_MERCHC] = NEC;
    if (blockIdx.x == NB && t == 0) off_mu[N_USERC] = NEC;
    __syncthreads();

    cnt[t] = 0; cur[t] = 0;
    __syncthreads();
    for (int i = t; i < n; i += 256)
        atomicAdd(&cnt[bkt[i] >> 16], 1u);
    __syncthreads();
    loff[t] = cnt[t];
    for (int d = 1; d < 256; d <<= 1) {
        __syncthreads();
        const uint32_t a = (t >= d) ? loff[t - d] : 0;
        __syncthreads();
        loff[t] += a;
    }
    __syncthreads();
    const uint32_t excl = loff[t] - cnt[t];
    const int dst0 = b << 8;
    if (dst0 + t < N_USERC) offp[dst0 + t] = (int)(gbase + excl);
    __syncthreads();
    loff[t] = excl;
    __syncthreads();
    for (int i = t; i < n; i += 256) {
        const uint32_t v = bkt[i];
        const uint32_t ld = v >> 16;
        const uint32_t p = gbase + loff[ld] + atomicAdd(&cur[ld], 1u);
        srcs[p] = (int)(v & 0xFFFFu);
    }
}

// ---------------------------------------------------------------------------
// Mean aggregation over interleaved bf16 tables, both directions per launch.
// 2x unrolled with dual accumulators (R9-proven).
// ---------------------------------------------------------------------------
template <int D>
__global__ __launch_bounds__(256) void k_agg(
    const ushortT* __restrict__ gA, const int* __restrict__ offsA,
    const int* __restrict__ srcsA, ushortT* __restrict__ oA,
    const ushortT* __restrict__ gB, const int* __restrict__ offsB,
    const int* __restrict__ srcsB, ushortT* __restrict__ oB, int ndst)
{
    constexpr int LPE = D / 8;      // lanes per edge row
    constexpr int EPW = 64 / LPE;   // edges per wave-iter
    constexpr int STR = 2 * D;      // interleaved row stride (elems)
    const int half = gridDim.x >> 1;
    const int type = (blockIdx.x >= half) ? 1 : 0;
    const int cb = blockIdx.x - type * half;
    const ushortT* g = type ? gB : gA;
    const int* offs  = type ? offsB : offsA;
    const int* srcs  = type ? srcsB : srcsA;
    ushortT* om      = type ? oB : oA;

    const int wid = cb * 4 + (threadIdx.x >> 6);
    if (wid >= ndst) return;
    const int lane = threadIdx.x & 63;
    const int sub  = lane / LPE;
    const int c4   = lane % LPE;

    const int b = offs[wid], e = offs[wid + 1];
    float a0[8], a1[8];
#pragma unroll
    for (int j = 0; j < 8; ++j) { a0[j] = 0.f; a1[j] = 0.f; }

    int i = b + sub;
    for (; i + EPW < e; i += 2 * EPW) {
        const int s0 = srcs[i];
        const int s1 = srcs[i + EPW];
        const uint4 v0 = *(const uint4*)(g + (size_t)s0 * STR + D + c4 * 8);
        const uint4 v1 = *(const uint4*)(g + (size_t)s1 * STR + D + c4 * 8);
        acc8(a0, v0);
        acc8(a1, v1);
    }
    if (i < e) {
        const int s0 = srcs[i];
        const uint4 v0 = *(const uint4*)(g + (size_t)s0 * STR + D + c4 * 8);
        acc8(a0, v0);
    }
#pragma unroll
    for (int j = 0; j < 8; ++j) a0[j] += a1[j];
#pragma unroll
    for (int m = LPE; m < 64; m <<= 1) {
#pragma unroll
        for (int j = 0; j < 8; ++j) a0[j] += __shfl_xor(a0[j], m);
    }
    if (sub == 0) {
        const int deg = e - b;
        const float inv = 1.0f / (float)(deg > 1 ? deg : 1);
        ushort8 o;
#pragma unroll
        for (int j = 0; j < 8; ++j) o[j] = f2bf(a0[j] * inv);
        *(ushort8*)(om + (size_t)wid * STR + c4 * 8) = o;
    }
}

// ---------------------------------------------------------------------------
// MFMA bf16 GEMM: Out[m][0:128] = act(A[m][0:K] @ W^T + bias), bf16 out.
// 64 A-rows per wave (4 A-frags): each B-fragment load feeds 4 MFMAs,
// MFMA:load = 32:12 per K-chunk — latency hidden by ILP, not occupancy.
// Block = 4 waves = 256 rows. Epilogue reuses per-wave LDS tile 4x
// (DS ops from one wave complete in order; no barrier needed).
// ---------------------------------------------------------------------------
template <int K, bool RELU>
__device__ __forceinline__ void mfma_gemm_body(
    int cb, float (*lds)[16][132],
    const ushortT* __restrict__ A, const ushortT* __restrict__ Bw,
    const float* __restrict__ bias,
    ushortT* __restrict__ Obf, int OS, int OO, int M)
{
    const int tx = threadIdx.x;
    const int wid = tx >> 6;
    const int lane = tx & 63;
    const int ln = lane & 15;
    const int quad = lane >> 4;
    const int m0 = cb * 256 + wid * 64;

    const ushortT* ap[4];
#pragma unroll
    for (int i = 0; i < 4; ++i) {
        int arow = m0 + i * 16 + ln; if (arow >= M) arow = M - 1;
        ap[i] = A + (size_t)arow * K + quad * 8;
    }

    f32x4 acc[4][8];
#pragma unroll
    for (int i = 0; i < 4; ++i)
#pragma unroll
        for (int nt = 0; nt < 8; ++nt) acc[i][nt] = (f32x4){0.f, 0.f, 0.f, 0.f};

#pragma unroll
    for (int kc = 0; kc < K / 32; ++kc) {
        short8 a[4];
#pragma unroll
        for (int i = 0; i < 4; ++i) a[i] = *(const short8*)(ap[i] + kc * 32);
#pragma unroll
        for (int nt = 0; nt < 8; ++nt) {
            const short8 b = *(const short8*)(Bw + (size_t)(nt * 16 + ln) * K + kc * 32 + quad * 8);
#pragma unroll
            for (int i = 0; i < 4; ++i)
                acc[i][nt] = __builtin_amdgcn_mfma_f32_16x16x32_bf16(a[i], b, acc[i][nt], 0, 0, 0);
        }
    }

    float (*t)[132] = lds[wid];
#pragma unroll
    for (int i = 0; i < 4; ++i) {
#pragma unroll
        for (int nt = 0; nt < 8; ++nt) {
            const float bv = bias[nt * 16 + ln];
#pragma unroll
            for (int r = 0; r < 4; ++r) {
                float v = acc[i][nt][r] + bv;
                if (RELU) v = fmaxf(v, 0.f);
                t[quad * 4 + r][nt * 16 + ln] = v;
            }
        }
#pragma unroll
        for (int p = 0; p < 4; ++p) {
            const int row = p * 4 + quad;
            const int gr = m0 + i * 16 + row;
            if (gr < M) {
                const float4 v0 = *(const float4*)&t[row][ln * 8];
                const float4 v1 = *(const float4*)&t[row][ln * 8 + 4];
                ushort8 o;
                o[0] = f2bf(v0.x); o[1] = f2bf(v0.y); o[2] = f2bf(v0.z); o[3] = f2bf(v0.w);
                o[4] = f2bf(v1.x); o[5] = f2bf(v1.y); o[6] = f2bf(v1.z); o[7] = f2bf(v1.w);
                *(ushort8*)(Obf + (size_t)gr * OS + OO + ln * 8) = o;
            }
        }
    }
}

template <int K, bool RELU>
__global__ __launch_bounds__(256) void k_mfma_gemm2(
    const ushortT* __restrict__ Aa, const ushortT* __restrict__ Bwa,
    const float* __restrict__ biasa, ushortT* __restrict__ Oa, int OSa, int OOa, int Ma,
    const ushortT* __restrict__ Ab, const ushortT* __restrict__ Bwb,
    const float* __restrict__ biasb, ushortT* __restrict__ Ob, int OSb, int OOb, int Mb,
    int gridA)
{
    __shared__ float lds[4][16][132];
    if ((int)blockIdx.x < gridA)
        mfma_gemm_body<K, RELU>(blockIdx.x, lds, Aa, Bwa, biasa, Oa, OSa, OOa, Ma);
    else
        mfma_gemm_body<K, RELU>(blockIdx.x - gridA, lds, Ab, Bwb, biasb, Ob, OSb, OOb, Mb);
}

// ---------------------------------------------------------------------------
// Edge classifier on bf16 P/Q: out[e] = bc2 + sum_j relu(P[r][j]+Q[c][j])*wc2[j]
// ---------------------------------------------------------------------------
__global__ __launch_bounds__(256) void k_edge_bf(
    const ushortT* __restrict__ P, const ushortT* __restrict__ Q,
    const int* __restrict__ er, const int* __restrict__ ec,
    const float* __restrict__ wc2, const float* __restrict__ bc2,
    float* __restrict__ out, int nt)
{
    const int lane = threadIdx.x & 63;
    const int sub = lane >> 4;       // edge within wave (4)
    const int c8 = lane & 15;        // 8-elem group within row
    const int wid = (int)((blockIdx.x * blockDim.x + threadIdx.x) >> 6);
    const int e0 = wid * 4 + sub;
    if (e0 >= nt) return;

    const float4 w0 = ((const float4*)wc2)[c8 * 2];
    const float4 w1 = ((const float4*)wc2)[c8 * 2 + 1];
    const int r = er[e0], c = ec[e0];
    const uint4 pv = *(const uint4*)(P + (size_t)r * 128 + c8 * 8);
    const uint4 qv = *(const uint4*)(Q + (size_t)c * 128 + c8 * 8);
    float s = fmaxf(bflo(pv.x) + bflo(qv.x), 0.f) * w0.x
            + fmaxf(bfhi(pv.x) + bfhi(qv.x), 0.f) * w0.y
            + fmaxf(bflo(pv.y) + bflo(qv.y), 0.f) * w0.z
            + fmaxf(bfhi(pv.y) + bfhi(qv.y), 0.f) * w0.w
            + fmaxf(bflo(pv.z) + bflo(qv.z), 0.f) * w1.x
            + fmaxf(bfhi(pv.z) + bfhi(qv.z), 0.f) * w1.y
            + fmaxf(bflo(pv.w) + bflo(qv.w), 0.f) * w1.z
            + fmaxf(bfhi(pv.w) + bfhi(qv.w), 0.f) * w1.w;
    s += __shfl_xor(s, 1);
    s += __shfl_xor(s, 2);
    s += __shfl_xor(s, 4);
    s += __shfl_xor(s, 8);
    if (c8 == 0) out[e0] = s + bc2[0];
}

// ---------------------------------------------------------------------------
// Host launcher
// ---------------------------------------------------------------------------
extern "C" void kernel_launch(void* const* d_in, const int* in_sizes, int n_in,
                              void* d_out, int out_size, void* d_ws, size_t ws_size,
                              hipStream_t stream)
{
    const float* x_user  = (const float*)d_in[0];
    const float* x_merch = (const float*)d_in[1];
    const int*   e_um    = (const int*)d_in[2];
    const int*   e_mu    = (const int*)d_in[3];
    const int*   tgt     = (const int*)d_in[4];
    const float* W1_um_l = (const float*)d_in[5];
    const float* b1_um_l = (const float*)d_in[6];
    const float* W1_um_r = (const float*)d_in[7];
    const float* W1_mu_l = (const float*)d_in[8];
    const float* b1_mu_l = (const float*)d_in[9];
    const float* W1_mu_r = (const float*)d_in[10];
    const float* W2_um_l = (const float*)d_in[11];
    const float* b2_um_l = (const float*)d_in[12];
    const float* W2_um_r = (const float*)d_in[13];
    const float* W2_mu_l = (const float*)d_in[14];
    const float* b2_mu_l = (const float*)d_in[15];
    const float* W2_mu_r = (const float*)d_in[16];
    const float* Wc1     = (const float*)d_in[17];
    const float* bc1     = (const float*)d_in[18];
    const float* Wc2     = (const float*)d_in[19];
    const float* bc2     = (const float*)d_in[20];
    float* out = (float*)d_out;

    // ---- workspace carve-up (u32 words, 64-word aligned)
    uint32_t* B = (uint32_t*)d_ws;
    size_t pos = 0;
    auto take = [&](size_t n) { size_t p = pos; pos += (n + 63) & ~(size_t)63; return p; };

    uint32_t* gcnt = (uint32_t*)(B + take(2 * NB));     // zeroed each launch
    const size_t cnt_words = pos;
    int* off_um  = (int*)(B + take(N_MERCHC + 1));
    int* srcs_um = (int*)(B + take(NEC));
    int* off_mu  = (int*)(B + take(N_USERC + 1));
    int* srcs_mu = (int*)(B + take(NEC));
    ushortT* A1u = (ushortT*)(B + take((size_t)N_USERC  * 128 / 2));  // [mean1_u | x_u]
    ushortT* A1m = (ushortT*)(B + take((size_t)N_MERCHC * 128 / 2));  // [mean1_m | x_m]
    ushortT* A2u = (ushortT*)(B + take((size_t)N_USERC  * 256 / 2));  // [mean2_u | h_u]
    ushortT* A2m = (ushortT*)(B + take((size_t)N_MERCHC * 256 / 2));  // [mean2_m | h_m]
    ushortT* B1m = (ushortT*)(B + take(8192));          // [W1_um_l | W1_um_r] bf16
    ushortT* B1u = (ushortT*)(B + take(8192));          // [W1_mu_l | W1_mu_r]
    ushortT* WPQ = (ushortT*)(B + take(32768));         // fused [2][128][256] bf16
    float*   bPQ = (float*)(B + take(256));             // fused biases [2][128] fp32

    // ---- aliases (lifetimes):
    // buckets: CSR build only; A2m's halves are written later (GEMM1 / agg2)
    uint32_t* bktA = (uint32_t*)A2m;
    uint32_t* bktB = bktA + (size_t)NB * BCAP;          // 3.2M words <= 6.4M
    // P/Q: written by classifier GEMMs (A1 dead after GEMM1), read by k_edge
    ushortT* Pbf = A1u;
    ushortT* Qbf = A1m;
    (void)ws_size; (void)in_sizes; (void)n_in; (void)out_size;

    // 1) zero bucket counters
    hipMemsetAsync(d_ws, 0, cnt_words * sizeof(uint32_t), stream);

    // 2) fused prep: x casts + weight casts + classifier weight fusion + CSR bucket
    k_prep<<<PREP_BKT, 256, 0, stream>>>(
        x_user, x_merch, A1u, A1m,
        W1_um_l, W1_um_r, W1_mu_l, W1_mu_r, B1m, B1u,
        Wc1, W2_mu_l, W2_mu_r, W2_um_l, W2_um_r, bc1, b2_mu_l, b2_um_l, WPQ, bPQ,
        e_um, e_um + NEC, e_mu, e_mu + NEC, gcnt, bktA, bktB);

    // 3) CSR place (inline bucket-base scan; writes off arrays + srcs)
    k_bplace<<<2 * NB, 256, 0, stream>>>(gcnt, bktA, bktB,
                                         off_um, srcs_um, off_mu, srcs_mu);

    // 4) layer-1 aggregates: gather x halves, write mean1 halves (bf16)
    const int agrid = 50000 / 4;
    k_agg<64><<<2 * agrid, 256, 0, stream>>>(
        A1u, off_um, srcs_um, A1m,
        A1m, off_mu, srcs_mu, A1u, N_MERCHC);

    // 5) layer-1 MFMA GEMM pair: h = relu(A1 @ B1^T + b1) -> A2 cols 128..255
    const int ggrid = (50000 + 255) / 256;
    k_mfma_gemm2<128, true><<<2 * ggrid, 256, 0, stream>>>(
        A1m, B1m, b1_um_l, A2m, 256, 128, N_MERCHC,
        A1u, B1u, b1_mu_l, A2u, 256, 128, N_USERC, ggrid);

    // 6) layer-2 aggregates: gather h halves, write mean2 halves (bf16)
    k_agg<128><<<2 * agrid, 256, 0, stream>>>(
        A2u, off_um, srcs_um, A2m,
        A2m, off_mu, srcs_mu, A2u, N_MERCHC);

    // 7) fused classifier MFMA GEMM pair: P = A2u @ WP^T + bP ; Q = A2m @ WQ^T + bQ
    k_mfma_gemm2<256, false><<<2 * ggrid, 256, 0, stream>>>(
        A2u, WPQ,         bPQ,       Pbf, 128, 0, N_USERC,
        A2m, WPQ + 32768, bPQ + 128, Qbf, 128, 0, N_MERCHC, ggrid);

    // 8) per-edge: out = bc2 + relu(P[r]+Q[c]) . wc2  (bf16 gathers)
    const int cgrid = (NTC + 15) / 16;   // 4 edges/wave, 4 waves/block
    k_edge_bf<<<cgrid, 256, 0, stream>>>(Pbf, Qbf, tgt, tgt + NTC, Wc2, bc2, out, NTC);
}